// Round 1
// baseline (4591.429 us; speedup 1.0000x reference)
//
#include <hip/hip_runtime.h>
#include <hip/hip_fp16.h>
#include <math.h>

#define T_ 128
#define B_ 32
#define D_ 512
#define V_ 128
#define S_ 64
#define N_ 4
#define R_ 64
#define O_ 64

__device__ __forceinline__ float fsigm(float x) {
    return __fdividef(1.0f, 1.0f + __expf(-x));
}
__device__ __forceinline__ float ftanh(float x) {
    x = fminf(15.f, fmaxf(-15.f, x));
    float e = __expf(2.f * x);
    return 1.f - __fdividef(2.f, e + 1.f);
}

// ---------------------------------------------------------------------------
// K1: precompute (all t,b in parallel):
//   src = emb[ids]@We + be  (kept in LDS only)
//   v_all   = src@Win + b_in
//   xo_all  = src@Win2 + b_in2
//   w3_all  = softmax(src@Win3 + b_in3)
//   gIn_all = v@Wig + b_ig
// 8 rows (flat f = t*B+b) per block, 256 threads.
// ---------------------------------------------------------------------------
__global__ __launch_bounds__(256)
void k1_pre(const int* __restrict__ ids, const float* __restrict__ emb,
            const float* __restrict__ We, const float* __restrict__ be,
            const float* __restrict__ Win, const float* __restrict__ b_in,
            const float* __restrict__ Win2, const float* __restrict__ b_in2,
            const float* __restrict__ Win3, const float* __restrict__ b_in3,
            const float* __restrict__ Wig, const float* __restrict__ b_ig,
            float* __restrict__ v_all, float* __restrict__ gIn_all,
            float* __restrict__ w3_all, float* __restrict__ xo_all)
{
    __shared__ float E[8][D_];
    __shared__ float X[8][D_];
    __shared__ float vs[8][S_];
    __shared__ float sc[8][N_];
    const int tid = threadIdx.x;
    const int f0 = blockIdx.x * 8;

    for (int i = tid; i < 8 * D_; i += 256) {
        int r = i >> 9, d = i & (D_ - 1);
        int f = f0 + r;
        int t = f >> 5, b = f & 31;               // B_ = 32
        E[r][d] = emb[ids[b * T_ + t] * D_ + d];
    }
    __syncthreads();

    { // src = E @ We + be
        const int d0 = tid, d1 = tid + 256;
        float a0[8], a1[8];
        float b0 = be[d0], b1 = be[d1];
#pragma unroll
        for (int r = 0; r < 8; ++r) { a0[r] = b0; a1[r] = b1; }
        for (int k = 0; k < D_; ++k) {
            float w0 = We[k * D_ + d0], w1 = We[k * D_ + d1];
#pragma unroll
            for (int r = 0; r < 8; ++r) {
                float e = E[r][k];
                a0[r] = fmaf(e, w0, a0[r]);
                a1[r] = fmaf(e, w1, a1[r]);
            }
        }
#pragma unroll
        for (int r = 0; r < 8; ++r) { X[r][d0] = a0[r]; X[r][d1] = a1[r]; }
    }
    __syncthreads();

    { // v and xo (share X reads)
        const int j = tid & 63, r0 = tid >> 6;
#pragma unroll
        for (int ri = 0; ri < 2; ++ri) {
            int r = r0 + 4 * ri;
            float a = b_in[j], a2 = b_in2[j];
            for (int k = 0; k < D_; ++k) {
                float x = X[r][k];
                a  = fmaf(x, Win [k * S_ + j], a);
                a2 = fmaf(x, Win2[k * O_ + j], a2);
            }
            vs[r][j] = a;
            v_all [(f0 + r) * S_ + j] = a;
            xo_all[(f0 + r) * O_ + j] = a2;
        }
    }
    if (tid < 32) { // w3 raw scores
        int r = tid >> 2, n = tid & 3;
        float a = b_in3[n];
        for (int k = 0; k < D_; ++k) a = fmaf(X[r][k], Win3[k * N_ + n], a);
        sc[r][n] = a;
    }
    __syncthreads();
    if (tid < 8) { // w3 softmax
        float x0 = sc[tid][0], x1 = sc[tid][1], x2 = sc[tid][2], x3 = sc[tid][3];
        float m = fmaxf(fmaxf(x0, x1), fmaxf(x2, x3));
        float e0 = expf(x0 - m), e1 = expf(x1 - m), e2 = expf(x2 - m), e3 = expf(x3 - m);
        float inv = 1.0f / (e0 + e1 + e2 + e3);
        float* w = &w3_all[(f0 + tid) * N_];
        w[0] = e0 * inv; w[1] = e1 * inv; w[2] = e2 * inv; w[3] = e3 * inv;
    }
    { // gIn = v@Wig + b_ig
        const int c = tid & 127, r0 = tid >> 7;
#pragma unroll
        for (int ri = 0; ri < 4; ++ri) {
            int r = r0 + 2 * ri;
            float a = b_ig[c];
            for (int k = 0; k < S_; ++k) a = fmaf(vs[r][k], Wig[k * 2 * S_ + c], a);
            gIn_all[(f0 + r) * 2 * S_ + c] = a;
        }
    }
}

// ---------------------------------------------------------------------------
// K2: the sequential scan. One block (1024 threads) per batch.
// Mi in LDS (f32). Mr in global ws (L2-resident). Wmg/Wvb staged transposed
// in LDS as fp16 with 4-elem XOR swizzle for conflict-free column reads.
// Emits o_all[t*B+b][O] only; MLP is hoisted to K3.
// ---------------------------------------------------------------------------
__global__ __launch_bounds__(1024)
void k2_scan(const float* __restrict__ v_all, const float* __restrict__ gIn_all,
             const float* __restrict__ w3_all, const float* __restrict__ xo_all,
             const float* __restrict__ Wmg, const float* __restrict__ b_mg,
             const float* __restrict__ Wqkv, const float* __restrict__ b_qkv,
             const float* __restrict__ ln_g, const float* __restrict__ ln_b,
             const float* __restrict__ Wrel, const float* __restrict__ b_rel,
             const float* __restrict__ Wvb, const float* __restrict__ b_vb,
             const float* __restrict__ Wrel3, const float* __restrict__ b_rel3,
             const float* __restrict__ Mi0, const float* __restrict__ Mr0,
             const float* __restrict__ p_ib, const float* __restrict__ p_fb,
             const float* __restrict__ p_a1, const float* __restrict__ p_a2,
             float* __restrict__ Mr_g, float* __restrict__ o_all)
{
    const int tid = threadIdx.x;
    const int b = blockIdx.x;

    __shared__ __align__(16) float Mi[S_][S_];        // 16 KB
    __shared__ __align__(16) float sc1[S_][S_];       // 16 KB: tanh(Mi) then transfer
    __shared__ __align__(16) __half WmgT[2 * S_][S_]; // 16 KB, [j][k] swizzled
    __shared__ __align__(16) __half WvbT[S_][S_];     // 8 KB,  [j][r] swizzled
    __shared__ float qkvn[S_ * 12];
    __shared__ float vvs[N_][S_];
    __shared__ float wvm[N_][S_];
    __shared__ float racc[N_][R_];
    __shared__ float r3s[N_][O_];
    __shared__ float Amat[N_][N_];
    __shared__ float vt[S_];
    __shared__ float w3s[N_];
    __shared__ float red1[16], red2[16];
    __shared__ float stat[2];

    const float ib = p_ib[0], fb = p_fb[0], a1 = p_a1[0], a2v = p_a2[0];

    // ---- init: stage swizzled fp16 weights, Mi <- Mi0, Mr_g[b] <- Mr0 ----
    for (int i = tid; i < 2 * S_ * S_; i += 1024) {       // Wmg (64,128)
        int k = i >> 7, j = i & 127;
        WmgT[j][(((k >> 2) ^ (j & 15)) << 2) | (k & 3)] = __float2half(Wmg[i]);
    }
    for (int i = tid; i < S_ * S_; i += 1024) {           // Wvb (64,64)
        int r = i >> 6, j = i & 63;
        WvbT[j][(((r >> 2) ^ (j & 15)) << 2) | (r & 3)] = __float2half(Wvb[i]);
    }
    {
        float* mf = &Mi[0][0];
        for (int i = tid; i < S_ * S_; i += 1024) mf[i] = Mi0[i];
        float* mr0 = Mr_g + (size_t)b * (N_ * S_ * R_);
        for (int i = tid; i < N_ * S_ * R_; i += 1024) mr0[i] = Mr0[i];
    }
    __syncthreads();

    float* mrb = Mr_g + (size_t)b * (N_ * S_ * R_);

    for (int t = 0; t < T_; ++t) {
        const int f = t * B_ + b;

        // ---- top: per-step loads + sc1 = tanh(Mi) ----
        if (tid < S_) vt[tid] = v_all[f * S_ + tid];
        if (tid < N_) w3s[tid] = w3_all[f * N_ + tid];
        {
            const float* mf = &Mi[0][0];
            float* s1 = &sc1[0][0];
#pragma unroll
            for (int i = 0; i < 4; ++i) s1[tid + i * 1024] = ftanh(mf[tid + i * 1024]);
        }
        __syncthreads();

        // ---- B: gates = tanh(Mi)@Wmg + b_mg + gIn ; Mi = gf*Mi + gi*tanh(v v^T)
        if (tid < 512) {
            const int jj = tid & 31, s0 = tid >> 5, jsw = jj & 15;
            float acc0[4], acc1[4], acc2[4], acc3[4];
            {
                const float* gin = &gIn_all[f * 2 * S_];
                float g0 = b_mg[jj]      + gin[jj];
                float g1 = b_mg[jj + 32] + gin[jj + 32];
                float g2 = b_mg[jj + 64] + gin[jj + 64];
                float g3 = b_mg[jj + 96] + gin[jj + 96];
#pragma unroll
                for (int si = 0; si < 4; ++si) { acc0[si] = g0; acc1[si] = g1; acc2[si] = g2; acc3[si] = g3; }
            }
            for (int kk = 0; kk < 16; ++kk) {
                const int ch = ((kk ^ jsw) << 2);
                float w0[4], w1[4], w2[4], w3v[4];
                {
                    __half2 ha, hb;
                    ha = *(const __half2*)&WmgT[jj][ch];      hb = *(const __half2*)&WmgT[jj][ch + 2];
                    w0[0] = __low2float(ha); w0[1] = __high2float(ha); w0[2] = __low2float(hb); w0[3] = __high2float(hb);
                    ha = *(const __half2*)&WmgT[jj + 32][ch]; hb = *(const __half2*)&WmgT[jj + 32][ch + 2];
                    w1[0] = __low2float(ha); w1[1] = __high2float(ha); w1[2] = __low2float(hb); w1[3] = __high2float(hb);
                    ha = *(const __half2*)&WmgT[jj + 64][ch]; hb = *(const __half2*)&WmgT[jj + 64][ch + 2];
                    w2[0] = __low2float(ha); w2[1] = __high2float(ha); w2[2] = __low2float(hb); w2[3] = __high2float(hb);
                    ha = *(const __half2*)&WmgT[jj + 96][ch]; hb = *(const __half2*)&WmgT[jj + 96][ch + 2];
                    w3v[0] = __low2float(ha); w3v[1] = __high2float(ha); w3v[2] = __low2float(hb); w3v[3] = __high2float(hb);
                }
#pragma unroll
                for (int si = 0; si < 4; ++si) {
                    const float4 a = *(const float4*)&sc1[s0 + 16 * si][kk << 2];
                    acc0[si] += a.x * w0[0]  + a.y * w0[1]  + a.z * w0[2]  + a.w * w0[3];
                    acc1[si] += a.x * w1[0]  + a.y * w1[1]  + a.z * w1[2]  + a.w * w1[3];
                    acc2[si] += a.x * w2[0]  + a.y * w2[1]  + a.z * w2[2]  + a.w * w2[3];
                    acc3[si] += a.x * w3v[0] + a.y * w3v[1] + a.z * w3v[2] + a.w * w3v[3];
                }
            }
            const float vj0 = vt[jj], vj1 = vt[jj + 32];
#pragma unroll
            for (int si = 0; si < 4; ++si) {
                const int s = s0 + 16 * si;
                const float vs_ = vt[s];
                float gi0 = fsigm(acc0[si] + ib), gf0 = fsigm(acc2[si] + fb);
                float gi1 = fsigm(acc1[si] + ib), gf1 = fsigm(acc3[si] + fb);
                Mi[s][jj]      = gf0 * Mi[s][jj]      + gi0 * ftanh(vs_ * vj0);
                Mi[s][jj + 32] = gf1 * Mi[s][jj + 32] + gi1 * ftanh(vs_ * vj1);
            }
        }
        __syncthreads();

        // ---- C: qkv = Mi@Wqkv + b_qkv, LayerNorm over all 768 ----
        float cacc = 0.f; int cs = 0, cc = 0;
        if (tid < 768) {
            cs = tid / 12; cc = tid - cs * 12;
            cacc = b_qkv[cc];
            for (int k = 0; k < S_; ++k) cacc = fmaf(Mi[cs][k], Wqkv[k * 12 + cc], cacc);
        }
        {
            float v1 = (tid < 768) ? cacc : 0.f;
            float v2 = v1 * v1;
#pragma unroll
            for (int off = 32; off; off >>= 1) { v1 += __shfl_down(v1, off); v2 += __shfl_down(v2, off); }
            if ((tid & 63) == 0) { red1[tid >> 6] = v1; red2[tid >> 6] = v2; }
        }
        __syncthreads();
        if (tid == 0) {
            float s1 = 0.f, s2 = 0.f;
#pragma unroll
            for (int i = 0; i < 16; ++i) { s1 += red1[i]; s2 += red2[i]; }
            float mu = s1 / 768.f;
            float var = s2 / 768.f - mu * mu;
            stat[0] = mu; stat[1] = rsqrtf(var + 1e-5f);
        }
        __syncthreads();
        if (tid < 768) {
            float qn = (cacc - stat[0]) * stat[1] * ln_g[tid] + ln_b[tid];
            qkvn[tid] = qn;
            if (cc >= 8) vvs[cc - 8][cs] = qn;
        }
        __syncthreads();

        // ---- D: A = softmax(q k^T / sqrt(S)); wv = vv @ Wrel ----
        if (tid < 16) {
            int n = tid >> 2, m = tid & 3;
            float a = 0.f;
            for (int k = 0; k < S_; ++k) a = fmaf(qkvn[k * 12 + n], qkvn[k * 12 + 4 + m], a);
            Amat[n][m] = a * 0.125f;
        } else if (tid >= 256 && tid < 512) {
            int m = (tid >> 6) & 3, r = tid & 63;
            float a = 0.f;
            for (int s = 0; s < S_; ++s) a = fmaf(vvs[m][s], Wrel[s * R_ + r], a);
            wvm[m][r] = a;
        }
        __syncthreads();
        if (tid < 4) {
            float x0 = Amat[tid][0], x1 = Amat[tid][1], x2 = Amat[tid][2], x3 = Amat[tid][3];
            float m = fmaxf(fmaxf(x0, x1), fmaxf(x2, x3));
            float e0 = expf(x0 - m), e1 = expf(x1 - m), e2 = expf(x2 - m), e3 = expf(x3 - m);
            float inv = 1.0f / (e0 + e1 + e2 + e3);
            Amat[tid][0] = e0 * inv; Amat[tid][1] = e1 * inv; Amat[tid][2] = e2 * inv; Amat[tid][3] = e3 * inv;
        }
        __syncthreads();

        // ---- E: Mr += a1*(Rt@Wrel + b_rel); transfer = sum_n w3 Mr (fused) ----
        {
            const int r = tid & 63, g = tid >> 6;    // g in 0..15
            const float brel = b_rel[r];
            const float wv0 = wvm[0][r], wv1 = wvm[1][r], wv2 = wvm[2][r], wv3 = wvm[3][r];
#pragma unroll
            for (int shi = 0; shi < 4; ++shi) {
                const int s = shi * 16 + g;
                const float vv0 = vvs[0][s], vv1 = vvs[1][s], vv2 = vvs[2][s], vv3 = vvs[3][s];
                float trans = 0.f;
#pragma unroll
                for (int n = 0; n < 4; ++n) {
                    float delta = (Amat[n][0] * vv0) * wv0 + (Amat[n][1] * vv1) * wv1
                                + (Amat[n][2] * vv2) * wv2 + (Amat[n][3] * vv3) * wv3;
                    const int idx = n * (S_ * R_) + s * R_ + r;
                    float upd = mrb[idx] + a1 * (delta + brel);
                    mrb[idx] = upd;
                    trans += w3s[n] * upd;
                }
                sc1[s][r] = trans;   // sc1 reused as transfer
            }
        }
        __syncthreads();

        // ---- F1: Mi += a2*tanh(transfer@Wvb + b_vb)  (tid<512)
        //          racc[n][r] = sum_s v[s]*Mr[n][s][r]  (tid 512..767)
        if (tid < 512) {
            const int jj = tid & 31, s0 = tid >> 5, jsw = jj & 15;
            float acc0[4], acc1[4];
            float bv0 = b_vb[jj], bv1 = b_vb[jj + 32];
#pragma unroll
            for (int si = 0; si < 4; ++si) { acc0[si] = bv0; acc1[si] = bv1; }
            for (int kk = 0; kk < 16; ++kk) {
                const int ch = ((kk ^ jsw) << 2);
                float w0[4], w1[4];
                {
                    __half2 ha, hb;
                    ha = *(const __half2*)&WvbT[jj][ch];      hb = *(const __half2*)&WvbT[jj][ch + 2];
                    w0[0] = __low2float(ha); w0[1] = __high2float(ha); w0[2] = __low2float(hb); w0[3] = __high2float(hb);
                    ha = *(const __half2*)&WvbT[jj + 32][ch]; hb = *(const __half2*)&WvbT[jj + 32][ch + 2];
                    w1[0] = __low2float(ha); w1[1] = __high2float(ha); w1[2] = __low2float(hb); w1[3] = __high2float(hb);
                }
#pragma unroll
                for (int si = 0; si < 4; ++si) {
                    const float4 a = *(const float4*)&sc1[s0 + 16 * si][kk << 2];
                    acc0[si] += a.x * w0[0] + a.y * w0[1] + a.z * w0[2] + a.w * w0[3];
                    acc1[si] += a.x * w1[0] + a.y * w1[1] + a.z * w1[2] + a.w * w1[3];
                }
            }
#pragma unroll
            for (int si = 0; si < 4; ++si) {
                const int s = s0 + 16 * si;
                Mi[s][jj]      += a2v * ftanh(acc0[si]);
                Mi[s][jj + 32] += a2v * ftanh(acc1[si]);
            }
        } else if (tid < 768) {
            const int n = (tid - 512) >> 6, r = tid & 63;
            const float* mr = mrb + n * (S_ * R_) + r;
            float a = 0.f;
            for (int s = 0; s < S_; ++s) a = fmaf(vt[s], mr[s * R_], a);
            racc[n][r] = a;
        }
        __syncthreads();

        // ---- F2: r3 = racc @ Wrel3 + b_rel3 ----
        if (tid < 256) {
            const int n = tid >> 6, o = tid & 63;
            float a = b_rel3[o];
            for (int rr = 0; rr < R_; ++rr) a = fmaf(racc[n][rr], Wrel3[rr * O_ + o], a);
            r3s[n][o] = a;
        }
        __syncthreads();

        // ---- F3: o = sum_n w3[n]*r3[n] + xo ----
        if (tid < O_) {
            float a = xo_all[f * O_ + tid];
            a += w3s[0] * r3s[0][tid] + w3s[1] * r3s[1][tid]
               + w3s[2] * r3s[2][tid] + w3s[3] * r3s[3][tid];
            o_all[f * O_ + tid] = a;
        }
        __syncthreads();
    }
}

// ---------------------------------------------------------------------------
// K3: post-pass MLP + final head for all (t,b):
//   h1 = relu(o@Wm1+b); h2 = relu(h1@Wm2+b); y = h2@Wout+b;
//   yn = LN(y)*fc_g + fc_b; logits = relu(yn)@Wfc + b_fc -> out[b][v][t]
// ---------------------------------------------------------------------------
__global__ __launch_bounds__(256)
void k3_post(const float* __restrict__ o_all,
             const float* __restrict__ Wm1, const float* __restrict__ b_m1,
             const float* __restrict__ Wm2, const float* __restrict__ b_m2,
             const float* __restrict__ Wout, const float* __restrict__ b_out,
             const float* __restrict__ fc_g, const float* __restrict__ fc_b,
             const float* __restrict__ Wfc, const float* __restrict__ b_fc,
             float* __restrict__ out)
{
    __shared__ float os[8][O_];
    __shared__ float h1[8][D_];
    __shared__ float h2[8][D_];
    __shared__ float mus[8], rst[8];
    const int tid = threadIdx.x;
    const int f0 = blockIdx.x * 8;

    for (int i = tid; i < 8 * O_; i += 256) os[i >> 6][i & 63] = o_all[f0 * O_ + i];
    __syncthreads();

    const int d0 = tid, d1 = tid + 256;
    { // h1 = relu(o @ Wm1 + b_m1), K = 64
        float a0[8], a1[8];
        float b0 = b_m1[d0], b1 = b_m1[d1];
#pragma unroll
        for (int r = 0; r < 8; ++r) { a0[r] = b0; a1[r] = b1; }
        for (int k = 0; k < O_; ++k) {
            float w0 = Wm1[k * D_ + d0], w1 = Wm1[k * D_ + d1];
#pragma unroll
            for (int r = 0; r < 8; ++r) {
                float e = os[r][k];
                a0[r] = fmaf(e, w0, a0[r]); a1[r] = fmaf(e, w1, a1[r]);
            }
        }
#pragma unroll
        for (int r = 0; r < 8; ++r) { h1[r][d0] = fmaxf(a0[r], 0.f); h1[r][d1] = fmaxf(a1[r], 0.f); }
    }
    __syncthreads();
    { // h2 = relu(h1 @ Wm2 + b_m2), K = 512
        float a0[8], a1[8];
        float b0 = b_m2[d0], b1 = b_m2[d1];
#pragma unroll
        for (int r = 0; r < 8; ++r) { a0[r] = b0; a1[r] = b1; }
        for (int k = 0; k < D_; ++k) {
            float w0 = Wm2[k * D_ + d0], w1 = Wm2[k * D_ + d1];
#pragma unroll
            for (int r = 0; r < 8; ++r) {
                float e = h1[r][k];
                a0[r] = fmaf(e, w0, a0[r]); a1[r] = fmaf(e, w1, a1[r]);
            }
        }
#pragma unroll
        for (int r = 0; r < 8; ++r) { h2[r][d0] = fmaxf(a0[r], 0.f); h2[r][d1] = fmaxf(a1[r], 0.f); }
    }
    __syncthreads();
    { // y = h2 @ Wout + b_out  -> into h1
        float a0[8], a1[8];
        float b0 = b_out[d0], b1 = b_out[d1];
#pragma unroll
        for (int r = 0; r < 8; ++r) { a0[r] = b0; a1[r] = b1; }
        for (int k = 0; k < D_; ++k) {
            float w0 = Wout[k * D_ + d0], w1 = Wout[k * D_ + d1];
#pragma unroll
            for (int r = 0; r < 8; ++r) {
                float e = h2[r][k];
                a0[r] = fmaf(e, w0, a0[r]); a1[r] = fmaf(e, w1, a1[r]);
            }
        }
#pragma unroll
        for (int r = 0; r < 8; ++r) { h1[r][d0] = a0[r]; h1[r][d1] = a1[r]; }
    }
    __syncthreads();
    { // LN stats per row
        const int r = tid >> 5, l = tid & 31;
        float s1 = 0.f, s2 = 0.f;
        for (int k = l; k < D_; k += 32) { float y = h1[r][k]; s1 += y; s2 += y * y; }
#pragma unroll
        for (int off = 16; off; off >>= 1) { s1 += __shfl_down(s1, off, 32); s2 += __shfl_down(s2, off, 32); }
        if (l == 0) {
            float mu = s1 / (float)D_;
            float var = s2 / (float)D_ - mu * mu;
            mus[r] = mu; rst[r] = rsqrtf(var + 1e-5f);
        }
    }
    __syncthreads();
    for (int i = tid; i < 8 * D_; i += 256) { // LN affine + relu, in place
        int r = i >> 9, d = i & (D_ - 1);
        float y = (h1[r][d] - mus[r]) * rst[r] * fc_g[d] + fc_b[d];
        h1[r][d] = fmaxf(y, 0.f);
    }
    __syncthreads();
    { // logits + transposed store
        const int v = tid & 127, r0 = tid >> 7;
#pragma unroll
        for (int ri = 0; ri < 4; ++ri) {
            int r = r0 + 2 * ri;
            float a = b_fc[v];
            for (int k = 0; k < D_; ++k) a = fmaf(h1[r][k], Wfc[k * V_ + v], a);
            int f = f0 + r, t = f >> 5, b = f & 31;
            out[b * (V_ * T_) + v * T_ + t] = a;
        }
    }
}

// ---------------------------------------------------------------------------
extern "C" void kernel_launch(void* const* d_in, const int* in_sizes, int n_in,
                              void* d_out, int out_size, void* d_ws, size_t ws_size,
                              hipStream_t stream)
{
    (void)in_sizes; (void)n_in; (void)out_size; (void)ws_size;
    const int*   ids   = (const int*)  d_in[0];
    const float* emb   = (const float*)d_in[1];
    const float* We    = (const float*)d_in[2];
    const float* be    = (const float*)d_in[3];
    const float* Win   = (const float*)d_in[4];
    const float* b_in  = (const float*)d_in[5];
    const float* Win2  = (const float*)d_in[6];
    const float* b_in2 = (const float*)d_in[7];
    const float* Win3  = (const float*)d_in[8];
    const float* b_in3 = (const float*)d_in[9];
    const float* Wig   = (const float*)d_in[10];
    const float* b_ig  = (const float*)d_in[11];
    const float* Wmg   = (const float*)d_in[12];
    const float* b_mg  = (const float*)d_in[13];
    const float* ibp   = (const float*)d_in[14];
    const float* fbp   = (const float*)d_in[15];
    const float* Wqkv  = (const float*)d_in[16];
    const float* b_qkv = (const float*)d_in[17];
    const float* ln_g  = (const float*)d_in[18];
    const float* ln_b  = (const float*)d_in[19];
    const float* a1p   = (const float*)d_in[20];
    const float* a2p   = (const float*)d_in[21];
    const float* Wrel  = (const float*)d_in[22];
    const float* b_rel = (const float*)d_in[23];
    const float* Wvb   = (const float*)d_in[24];
    const float* b_vb  = (const float*)d_in[25];
    const float* Wrel3 = (const float*)d_in[26];
    const float* b_rel3= (const float*)d_in[27];
    const float* Wm1   = (const float*)d_in[28];
    const float* b_m1  = (const float*)d_in[29];
    const float* Wm2   = (const float*)d_in[30];
    const float* b_m2  = (const float*)d_in[31];
    const float* Wout  = (const float*)d_in[32];
    const float* b_out = (const float*)d_in[33];
    const float* Mi0   = (const float*)d_in[34];
    const float* Mr0   = (const float*)d_in[35];
    const float* fc_g  = (const float*)d_in[36];
    const float* fc_b  = (const float*)d_in[37];
    const float* Wfc   = (const float*)d_in[38];
    const float* b_fc  = (const float*)d_in[39];

    float* ws = (float*)d_ws;
    float* v_all   = ws;                      // T*B*S    = 262144
    float* gIn_all = v_all   + T_ * B_ * S_;      // T*B*2S   = 524288
    float* w3_all  = gIn_all + T_ * B_ * 2 * S_;  // T*B*N    = 16384
    float* xo_all  = w3_all  + T_ * B_ * N_;      // T*B*O    = 262144
    float* o_all   = xo_all  + T_ * B_ * O_;      // T*B*O    = 262144
    float* Mr_g    = o_all   + T_ * B_ * O_;      // B*N*S*R  = 524288

    k1_pre<<<dim3((T_ * B_) / 8), dim3(256), 0, stream>>>(
        ids, emb, We, be, Win, b_in, Win2, b_in2, Win3, b_in3, Wig, b_ig,
        v_all, gIn_all, w3_all, xo_all);

    k2_scan<<<dim3(B_), dim3(1024), 0, stream>>>(
        v_all, gIn_all, w3_all, xo_all,
        Wmg, b_mg, Wqkv, b_qkv, ln_g, ln_b,
        Wrel, b_rel, Wvb, b_vb, Wrel3, b_rel3,
        Mi0, Mr0, ibp, fbp, a1p, a2p, Mr_g, o_all);

    k3_post<<<dim3((T_ * B_) / 8), dim3(256), 0, stream>>>(
        o_all, Wm1, b_m1, Wm2, b_m2, Wout, b_out, fc_g, fc_b, Wfc, b_fc,
        (float*)d_out);
}

// Round 2
// 4106.220 us; speedup vs baseline: 1.1182x; 1.1182x over previous
//
#include <hip/hip_runtime.h>
#include <hip/hip_fp16.h>
#include <math.h>

#define T_ 128
#define B_ 32
#define D_ 512
#define V_ 128
#define S_ 64
#define N_ 4
#define R_ 64
#define O_ 64

__device__ __forceinline__ float fsigm(float x) {
    return __fdividef(1.0f, 1.0f + __expf(-x));
}
__device__ __forceinline__ float ftanh(float x) {
    x = fminf(15.f, fmaxf(-15.f, x));
    float e = __expf(2.f * x);
    return 1.f - __fdividef(2.f, e + 1.f);
}

// ---------------------------------------------------------------------------
// K1: precompute (all t,b in parallel):
//   src = emb[ids]@We + be  (kept in LDS only)
//   v_all   = src@Win + b_in
//   xo_all  = src@Win2 + b_in2
//   w3_all  = softmax(src@Win3 + b_in3)
//   gIn_all = v@Wig + b_ig
// ---------------------------------------------------------------------------
__global__ __launch_bounds__(256)
void k1_pre(const int* __restrict__ ids, const float* __restrict__ emb,
            const float* __restrict__ We, const float* __restrict__ be,
            const float* __restrict__ Win, const float* __restrict__ b_in,
            const float* __restrict__ Win2, const float* __restrict__ b_in2,
            const float* __restrict__ Win3, const float* __restrict__ b_in3,
            const float* __restrict__ Wig, const float* __restrict__ b_ig,
            float* __restrict__ v_all, float* __restrict__ gIn_all,
            float* __restrict__ w3_all, float* __restrict__ xo_all)
{
    __shared__ float E[8][D_];
    __shared__ float X[8][D_];
    __shared__ float vs[8][S_];
    __shared__ float sc[8][N_];
    const int tid = threadIdx.x;
    const int f0 = blockIdx.x * 8;

    for (int i = tid; i < 8 * D_; i += 256) {
        int r = i >> 9, d = i & (D_ - 1);
        int f = f0 + r;
        int t = f >> 5, b = f & 31;               // B_ = 32
        E[r][d] = emb[ids[b * T_ + t] * D_ + d];
    }
    __syncthreads();

    { // src = E @ We + be
        const int d0 = tid, d1 = tid + 256;
        float a0[8], a1[8];
        float b0 = be[d0], b1 = be[d1];
#pragma unroll
        for (int r = 0; r < 8; ++r) { a0[r] = b0; a1[r] = b1; }
        for (int k = 0; k < D_; ++k) {
            float w0 = We[k * D_ + d0], w1 = We[k * D_ + d1];
#pragma unroll
            for (int r = 0; r < 8; ++r) {
                float e = E[r][k];
                a0[r] = fmaf(e, w0, a0[r]);
                a1[r] = fmaf(e, w1, a1[r]);
            }
        }
#pragma unroll
        for (int r = 0; r < 8; ++r) { X[r][d0] = a0[r]; X[r][d1] = a1[r]; }
    }
    __syncthreads();

    { // v and xo (share X reads)
        const int j = tid & 63, r0 = tid >> 6;
#pragma unroll
        for (int ri = 0; ri < 2; ++ri) {
            int r = r0 + 4 * ri;
            float a = b_in[j], a2 = b_in2[j];
            for (int k = 0; k < D_; ++k) {
                float x = X[r][k];
                a  = fmaf(x, Win [k * S_ + j], a);
                a2 = fmaf(x, Win2[k * O_ + j], a2);
            }
            vs[r][j] = a;
            v_all [(f0 + r) * S_ + j] = a;
            xo_all[(f0 + r) * O_ + j] = a2;
        }
    }
    if (tid < 32) { // w3 raw scores
        int r = tid >> 2, n = tid & 3;
        float a = b_in3[n];
        for (int k = 0; k < D_; ++k) a = fmaf(X[r][k], Win3[k * N_ + n], a);
        sc[r][n] = a;
    }
    __syncthreads();
    if (tid < 8) { // w3 softmax
        float x0 = sc[tid][0], x1 = sc[tid][1], x2 = sc[tid][2], x3 = sc[tid][3];
        float m = fmaxf(fmaxf(x0, x1), fmaxf(x2, x3));
        float e0 = expf(x0 - m), e1 = expf(x1 - m), e2 = expf(x2 - m), e3 = expf(x3 - m);
        float inv = 1.0f / (e0 + e1 + e2 + e3);
        float* w = &w3_all[(f0 + tid) * N_];
        w[0] = e0 * inv; w[1] = e1 * inv; w[2] = e2 * inv; w[3] = e3 * inv;
    }
    { // gIn = v@Wig + b_ig
        const int c = tid & 127, r0 = tid >> 7;
#pragma unroll
        for (int ri = 0; ri < 4; ++ri) {
            int r = r0 + 2 * ri;
            float a = b_ig[c];
            for (int k = 0; k < S_; ++k) a = fmaf(vs[r][k], Wig[k * 2 * S_ + c], a);
            gIn_all[(f0 + r) * 2 * S_ + c] = a;
        }
    }
}

// ---------------------------------------------------------------------------
// K2: the sequential scan. One block (1024 threads) per batch.
// Mi AND Mr fully resident in LDS (~130 KB of the CU's 160 KB) -> zero
// global traffic on the carry state. Wmg/Wvb staged transposed in LDS as
// fp16 with 4-elem XOR swizzle; Wqkv staged f32. Emits o_all only.
// ---------------------------------------------------------------------------
__global__ __launch_bounds__(1024)
void k2_scan(const float* __restrict__ v_all, const float* __restrict__ gIn_all,
             const float* __restrict__ w3_all, const float* __restrict__ xo_all,
             const float* __restrict__ Wmg, const float* __restrict__ b_mg,
             const float* __restrict__ Wqkv, const float* __restrict__ b_qkv,
             const float* __restrict__ ln_g, const float* __restrict__ ln_b,
             const float* __restrict__ Wrel, const float* __restrict__ b_rel,
             const float* __restrict__ Wvb, const float* __restrict__ b_vb,
             const float* __restrict__ Wrel3, const float* __restrict__ b_rel3,
             const float* __restrict__ Mi0, const float* __restrict__ Mr0,
             const float* __restrict__ p_ib, const float* __restrict__ p_fb,
             const float* __restrict__ p_a1, const float* __restrict__ p_a2,
             float* __restrict__ o_all)
{
    const int tid = threadIdx.x;
    const int b = blockIdx.x;

    __shared__ __align__(16) float Mrs[N_][S_][R_];   // 64 KB: relational memory
    __shared__ __align__(16) float Mi[S_][S_];        // 16 KB
    __shared__ __align__(16) float sc1[S_][S_];       // 16 KB: tanh(Mi) then transfer
    __shared__ __align__(16) __half WmgT[2 * S_][S_]; // 16 KB, [j][k] swizzled
    __shared__ __align__(16) __half WvbT[S_][S_];     // 8 KB,  [j][r] swizzled
    __shared__ __align__(16) float Wqkv_s[S_ * 12];   // 3 KB
    __shared__ float qkvn[S_ * 12];
    __shared__ float vvs[N_][S_];
    __shared__ float wvm[N_][S_];
    __shared__ float racc[N_][R_];
    __shared__ float r3s[N_][O_];
    __shared__ float Amat[N_][N_];
    __shared__ float vt[S_];
    __shared__ float w3s[N_];
    __shared__ float red1[16], red2[16];
    __shared__ float stat[2];

    const float ib = p_ib[0], fb = p_fb[0], a1 = p_a1[0], a2v = p_a2[0];

    // ---- init: stage swizzled fp16 weights, Wqkv, Mi <- Mi0, Mrs <- Mr0 ----
    for (int i = tid; i < 2 * S_ * S_; i += 1024) {       // Wmg (64,128)
        int k = i >> 7, j = i & 127;
        WmgT[j][(((k >> 2) ^ (j & 15)) << 2) | (k & 3)] = __float2half(Wmg[i]);
    }
    for (int i = tid; i < S_ * S_; i += 1024) {           // Wvb (64,64)
        int r = i >> 6, j = i & 63;
        WvbT[j][(((r >> 2) ^ (j & 15)) << 2) | (r & 3)] = __float2half(Wvb[i]);
    }
    if (tid < S_ * 12) Wqkv_s[tid] = Wqkv[tid];
    {
        float* mf = &Mi[0][0];
        for (int i = tid; i < S_ * S_; i += 1024) mf[i] = Mi0[i];
        float* ms = &Mrs[0][0][0];
        for (int i = tid; i < N_ * S_ * R_; i += 1024) ms[i] = Mr0[i];
    }
    __syncthreads();

    for (int t = 0; t < T_; ++t) {
        const int f = t * B_ + b;

        // ---- top: per-step loads + sc1 = tanh(Mi) ----
        if (tid < S_) vt[tid] = v_all[f * S_ + tid];
        if (tid < N_) w3s[tid] = w3_all[f * N_ + tid];
        {
            const float* mf = &Mi[0][0];
            float* s1 = &sc1[0][0];
#pragma unroll
            for (int i = 0; i < 4; ++i) s1[tid + i * 1024] = ftanh(mf[tid + i * 1024]);
        }
        __syncthreads();

        // ---- B: gates = tanh(Mi)@Wmg + b_mg + gIn ; Mi = gf*Mi + gi*tanh(v v^T)
        if (tid < 512) {
            const int jj = tid & 31, s0 = tid >> 5, jsw = jj & 15;
            float acc0[4], acc1[4], acc2[4], acc3[4];
            {
                const float* gin = &gIn_all[f * 2 * S_];
                float g0 = b_mg[jj]      + gin[jj];
                float g1 = b_mg[jj + 32] + gin[jj + 32];
                float g2 = b_mg[jj + 64] + gin[jj + 64];
                float g3 = b_mg[jj + 96] + gin[jj + 96];
#pragma unroll
                for (int si = 0; si < 4; ++si) { acc0[si] = g0; acc1[si] = g1; acc2[si] = g2; acc3[si] = g3; }
            }
            for (int kk = 0; kk < 16; ++kk) {
                const int ch = ((kk ^ jsw) << 2);
                float w0[4], w1[4], w2[4], w3v[4];
                {
                    __half2 ha, hb;
                    ha = *(const __half2*)&WmgT[jj][ch];      hb = *(const __half2*)&WmgT[jj][ch + 2];
                    w0[0] = __low2float(ha); w0[1] = __high2float(ha); w0[2] = __low2float(hb); w0[3] = __high2float(hb);
                    ha = *(const __half2*)&WmgT[jj + 32][ch]; hb = *(const __half2*)&WmgT[jj + 32][ch + 2];
                    w1[0] = __low2float(ha); w1[1] = __high2float(ha); w1[2] = __low2float(hb); w1[3] = __high2float(hb);
                    ha = *(const __half2*)&WmgT[jj + 64][ch]; hb = *(const __half2*)&WmgT[jj + 64][ch + 2];
                    w2[0] = __low2float(ha); w2[1] = __high2float(ha); w2[2] = __low2float(hb); w2[3] = __high2float(hb);
                    ha = *(const __half2*)&WmgT[jj + 96][ch]; hb = *(const __half2*)&WmgT[jj + 96][ch + 2];
                    w3v[0] = __low2float(ha); w3v[1] = __high2float(ha); w3v[2] = __low2float(hb); w3v[3] = __high2float(hb);
                }
#pragma unroll
                for (int si = 0; si < 4; ++si) {
                    const float4 a = *(const float4*)&sc1[s0 + 16 * si][kk << 2];
                    acc0[si] += a.x * w0[0]  + a.y * w0[1]  + a.z * w0[2]  + a.w * w0[3];
                    acc1[si] += a.x * w1[0]  + a.y * w1[1]  + a.z * w1[2]  + a.w * w1[3];
                    acc2[si] += a.x * w2[0]  + a.y * w2[1]  + a.z * w2[2]  + a.w * w2[3];
                    acc3[si] += a.x * w3v[0] + a.y * w3v[1] + a.z * w3v[2] + a.w * w3v[3];
                }
            }
            const float vj0 = vt[jj], vj1 = vt[jj + 32];
#pragma unroll
            for (int si = 0; si < 4; ++si) {
                const int s = s0 + 16 * si;
                const float vs_ = vt[s];
                float gi0 = fsigm(acc0[si] + ib), gf0 = fsigm(acc2[si] + fb);
                float gi1 = fsigm(acc1[si] + ib), gf1 = fsigm(acc3[si] + fb);
                Mi[s][jj]      = gf0 * Mi[s][jj]      + gi0 * ftanh(vs_ * vj0);
                Mi[s][jj + 32] = gf1 * Mi[s][jj + 32] + gi1 * ftanh(vs_ * vj1);
            }
        }
        __syncthreads();

        // ---- C: qkv = Mi@Wqkv + b_qkv, LayerNorm over all 768 ----
        float cacc = 0.f; int cs = 0, cc = 0;
        if (tid < 768) {
            cs = tid / 12; cc = tid - cs * 12;
            cacc = b_qkv[cc];
            for (int k = 0; k < S_; ++k) cacc = fmaf(Mi[cs][k], Wqkv_s[k * 12 + cc], cacc);
        }
        {
            float v1 = (tid < 768) ? cacc : 0.f;
            float v2 = v1 * v1;
#pragma unroll
            for (int off = 32; off; off >>= 1) { v1 += __shfl_down(v1, off); v2 += __shfl_down(v2, off); }
            if ((tid & 63) == 0) { red1[tid >> 6] = v1; red2[tid >> 6] = v2; }
        }
        __syncthreads();
        if (tid == 0) {
            float s1 = 0.f, s2 = 0.f;
#pragma unroll
            for (int i = 0; i < 16; ++i) { s1 += red1[i]; s2 += red2[i]; }
            float mu = s1 / 768.f;
            float var = s2 / 768.f - mu * mu;
            stat[0] = mu; stat[1] = rsqrtf(var + 1e-5f);
        }
        __syncthreads();
        if (tid < 768) {
            float qn = (cacc - stat[0]) * stat[1] * ln_g[tid] + ln_b[tid];
            qkvn[tid] = qn;
            if (cc >= 8) vvs[cc - 8][cs] = qn;
        }
        __syncthreads();

        // ---- D: A = softmax(q k^T / sqrt(S)); wv = vv @ Wrel ----
        if (tid < 16) {
            int n = tid >> 2, m = tid & 3;
            float a = 0.f;
            for (int k = 0; k < S_; ++k) a = fmaf(qkvn[k * 12 + n], qkvn[k * 12 + 4 + m], a);
            Amat[n][m] = a * 0.125f;
        } else if (tid >= 256 && tid < 512) {
            int m = (tid >> 6) & 3, r = tid & 63;
            float a = 0.f;
            for (int s = 0; s < S_; ++s) a = fmaf(vvs[m][s], Wrel[s * R_ + r], a);
            wvm[m][r] = a;
        }
        __syncthreads();
        if (tid < 4) {
            float x0 = Amat[tid][0], x1 = Amat[tid][1], x2 = Amat[tid][2], x3 = Amat[tid][3];
            float m = fmaxf(fmaxf(x0, x1), fmaxf(x2, x3));
            float e0 = expf(x0 - m), e1 = expf(x1 - m), e2 = expf(x2 - m), e3 = expf(x3 - m);
            float inv = 1.0f / (e0 + e1 + e2 + e3);
            Amat[tid][0] = e0 * inv; Amat[tid][1] = e1 * inv; Amat[tid][2] = e2 * inv; Amat[tid][3] = e3 * inv;
        }
        __syncthreads();

        // ---- E: Mrs += a1*(Rt@Wrel + b_rel); transfer = sum_n w3 Mrs (fused) ----
        {
            const int r = tid & 63, g = tid >> 6;    // g in 0..15
            const float brel = b_rel[r];
            const float wv0 = wvm[0][r], wv1 = wvm[1][r], wv2 = wvm[2][r], wv3 = wvm[3][r];
#pragma unroll
            for (int shi = 0; shi < 4; ++shi) {
                const int s = shi * 16 + g;
                const float vv0 = vvs[0][s], vv1 = vvs[1][s], vv2 = vvs[2][s], vv3 = vvs[3][s];
                float trans = 0.f;
#pragma unroll
                for (int n = 0; n < 4; ++n) {
                    float delta = (Amat[n][0] * vv0) * wv0 + (Amat[n][1] * vv1) * wv1
                                + (Amat[n][2] * vv2) * wv2 + (Amat[n][3] * vv3) * wv3;
                    float upd = Mrs[n][s][r] + a1 * (delta + brel);
                    Mrs[n][s][r] = upd;
                    trans += w3s[n] * upd;
                }
                sc1[s][r] = trans;   // sc1 reused as transfer
            }
        }
        __syncthreads();

        // ---- F1: Mi += a2*tanh(transfer@Wvb + b_vb)  (tid<512)
        //          racc[n][r] = sum_s v[s]*Mrs[n][s][r]  (tid 512..767)
        if (tid < 512) {
            const int jj = tid & 31, s0 = tid >> 5, jsw = jj & 15;
            float acc0[4], acc1[4];
            float bv0 = b_vb[jj], bv1 = b_vb[jj + 32];
#pragma unroll
            for (int si = 0; si < 4; ++si) { acc0[si] = bv0; acc1[si] = bv1; }
            for (int kk = 0; kk < 16; ++kk) {
                const int ch = ((kk ^ jsw) << 2);
                float w0[4], w1[4];
                {
                    __half2 ha, hb;
                    ha = *(const __half2*)&WvbT[jj][ch];      hb = *(const __half2*)&WvbT[jj][ch + 2];
                    w0[0] = __low2float(ha); w0[1] = __high2float(ha); w0[2] = __low2float(hb); w0[3] = __high2float(hb);
                    ha = *(const __half2*)&WvbT[jj + 32][ch]; hb = *(const __half2*)&WvbT[jj + 32][ch + 2];
                    w1[0] = __low2float(ha); w1[1] = __high2float(ha); w1[2] = __low2float(hb); w1[3] = __high2float(hb);
                }
#pragma unroll
                for (int si = 0; si < 4; ++si) {
                    const float4 a = *(const float4*)&sc1[s0 + 16 * si][kk << 2];
                    acc0[si] += a.x * w0[0] + a.y * w0[1] + a.z * w0[2] + a.w * w0[3];
                    acc1[si] += a.x * w1[0] + a.y * w1[1] + a.z * w1[2] + a.w * w1[3];
                }
            }
#pragma unroll
            for (int si = 0; si < 4; ++si) {
                const int s = s0 + 16 * si;
                Mi[s][jj]      += a2v * ftanh(acc0[si]);
                Mi[s][jj + 32] += a2v * ftanh(acc1[si]);
            }
        } else if (tid < 768) {
            const int n = (tid - 512) >> 6, r = tid & 63;
            const float* mr = &Mrs[n][0][r];
            float a = 0.f;
            for (int s = 0; s < S_; ++s) a = fmaf(vt[s], mr[s * R_], a);
            racc[n][r] = a;
        }
        __syncthreads();

        // ---- F2: r3 = racc @ Wrel3 + b_rel3 ----
        if (tid < 256) {
            const int n = tid >> 6, o = tid & 63;
            float a = b_rel3[o];
            for (int rr = 0; rr < R_; ++rr) a = fmaf(racc[n][rr], Wrel3[rr * O_ + o], a);
            r3s[n][o] = a;
        }
        __syncthreads();

        // ---- F3: o = sum_n w3[n]*r3[n] + xo ----
        if (tid < O_) {
            float a = xo_all[f * O_ + tid];
            a += w3s[0] * r3s[0][tid] + w3s[1] * r3s[1][tid]
               + w3s[2] * r3s[2][tid] + w3s[3] * r3s[3][tid];
            o_all[f * O_ + tid] = a;
        }
        __syncthreads();
    }
}

// ---------------------------------------------------------------------------
// K3: post-pass MLP + final head for all (t,b):
//   h1 = relu(o@Wm1+b); h2 = relu(h1@Wm2+b); y = h2@Wout+b;
//   yn = LN(y)*fc_g + fc_b; logits = relu(yn)@Wfc + b_fc -> out[b][v][t]
// ---------------------------------------------------------------------------
__global__ __launch_bounds__(256)
void k3_post(const float* __restrict__ o_all,
             const float* __restrict__ Wm1, const float* __restrict__ b_m1,
             const float* __restrict__ Wm2, const float* __restrict__ b_m2,
             const float* __restrict__ Wout, const float* __restrict__ b_out,
             const float* __restrict__ fc_g, const float* __restrict__ fc_b,
             const float* __restrict__ Wfc, const float* __restrict__ b_fc,
             float* __restrict__ out)
{
    __shared__ float os[8][O_];
    __shared__ float h1[8][D_];
    __shared__ float h2[8][D_];
    __shared__ float mus[8], rst[8];
    const int tid = threadIdx.x;
    const int f0 = blockIdx.x * 8;

    for (int i = tid; i < 8 * O_; i += 256) os[i >> 6][i & 63] = o_all[f0 * O_ + i];
    __syncthreads();

    const int d0 = tid, d1 = tid + 256;
    { // h1 = relu(o @ Wm1 + b_m1), K = 64
        float a0[8], a1[8];
        float b0 = b_m1[d0], b1 = b_m1[d1];
#pragma unroll
        for (int r = 0; r < 8; ++r) { a0[r] = b0; a1[r] = b1; }
        for (int k = 0; k < O_; ++k) {
            float w0 = Wm1[k * D_ + d0], w1 = Wm1[k * D_ + d1];
#pragma unroll
            for (int r = 0; r < 8; ++r) {
                float e = os[r][k];
                a0[r] = fmaf(e, w0, a0[r]); a1[r] = fmaf(e, w1, a1[r]);
            }
        }
#pragma unroll
        for (int r = 0; r < 8; ++r) { h1[r][d0] = fmaxf(a0[r], 0.f); h1[r][d1] = fmaxf(a1[r], 0.f); }
    }
    __syncthreads();
    { // h2 = relu(h1 @ Wm2 + b_m2), K = 512
        float a0[8], a1[8];
        float b0 = b_m2[d0], b1 = b_m2[d1];
#pragma unroll
        for (int r = 0; r < 8; ++r) { a0[r] = b0; a1[r] = b1; }
        for (int k = 0; k < D_; ++k) {
            float w0 = Wm2[k * D_ + d0], w1 = Wm2[k * D_ + d1];
#pragma unroll
            for (int r = 0; r < 8; ++r) {
                float e = h1[r][k];
                a0[r] = fmaf(e, w0, a0[r]); a1[r] = fmaf(e, w1, a1[r]);
            }
        }
#pragma unroll
        for (int r = 0; r < 8; ++r) { h2[r][d0] = fmaxf(a0[r], 0.f); h2[r][d1] = fmaxf(a1[r], 0.f); }
    }
    __syncthreads();
    { // y = h2 @ Wout + b_out  -> into h1
        float a0[8], a1[8];
        float b0 = b_out[d0], b1 = b_out[d1];
#pragma unroll
        for (int r = 0; r < 8; ++r) { a0[r] = b0; a1[r] = b1; }
        for (int k = 0; k < D_; ++k) {
            float w0 = Wout[k * D_ + d0], w1 = Wout[k * D_ + d1];
#pragma unroll
            for (int r = 0; r < 8; ++r) {
                float e = h2[r][k];
                a0[r] = fmaf(e, w0, a0[r]); a1[r] = fmaf(e, w1, a1[r]);
            }
        }
#pragma unroll
        for (int r = 0; r < 8; ++r) { h1[r][d0] = a0[r]; h1[r][d1] = a1[r]; }
    }
    __syncthreads();
    { // LN stats per row
        const int r = tid >> 5, l = tid & 31;
        float s1 = 0.f, s2 = 0.f;
        for (int k = l; k < D_; k += 32) { float y = h1[r][k]; s1 += y; s2 += y * y; }
#pragma unroll
        for (int off = 16; off; off >>= 1) { s1 += __shfl_down(s1, off, 32); s2 += __shfl_down(s2, off, 32); }
        if (l == 0) {
            float mu = s1 / (float)D_;
            float var = s2 / (float)D_ - mu * mu;
            mus[r] = mu; rst[r] = rsqrtf(var + 1e-5f);
        }
    }
    __syncthreads();
    for (int i = tid; i < 8 * D_; i += 256) { // LN affine + relu, in place
        int r = i >> 9, d = i & (D_ - 1);
        float y = (h1[r][d] - mus[r]) * rst[r] * fc_g[d] + fc_b[d];
        h1[r][d] = fmaxf(y, 0.f);
    }
    __syncthreads();
    { // logits + transposed store
        const int v = tid & 127, r0 = tid >> 7;
#pragma unroll
        for (int ri = 0; ri < 4; ++ri) {
            int r = r0 + 2 * ri;
            float a = b_fc[v];
            for (int k = 0; k < D_; ++k) a = fmaf(h1[r][k], Wfc[k * V_ + v], a);
            int f = f0 + r, t = f >> 5, b = f & 31;
            out[b * (V_ * T_) + v * T_ + t] = a;
        }
    }
}

// ---------------------------------------------------------------------------
extern "C" void kernel_launch(void* const* d_in, const int* in_sizes, int n_in,
                              void* d_out, int out_size, void* d_ws, size_t ws_size,
                              hipStream_t stream)
{
    (void)in_sizes; (void)n_in; (void)out_size; (void)ws_size;
    const int*   ids   = (const int*)  d_in[0];
    const float* emb   = (const float*)d_in[1];
    const float* We    = (const float*)d_in[2];
    const float* be    = (const float*)d_in[3];
    const float* Win   = (const float*)d_in[4];
    const float* b_in  = (const float*)d_in[5];
    const float* Win2  = (const float*)d_in[6];
    const float* b_in2 = (const float*)d_in[7];
    const float* Win3  = (const float*)d_in[8];
    const float* b_in3 = (const float*)d_in[9];
    const float* Wig   = (const float*)d_in[10];
    const float* b_ig  = (const float*)d_in[11];
    const float* Wmg   = (const float*)d_in[12];
    const float* b_mg  = (const float*)d_in[13];
    const float* ibp   = (const float*)d_in[14];
    const float* fbp   = (const float*)d_in[15];
    const float* Wqkv  = (const float*)d_in[16];
    const float* b_qkv = (const float*)d_in[17];
    const float* ln_g  = (const float*)d_in[18];
    const float* ln_b  = (const float*)d_in[19];
    const float* a1p   = (const float*)d_in[20];
    const float* a2p   = (const float*)d_in[21];
    const float* Wrel  = (const float*)d_in[22];
    const float* b_rel = (const float*)d_in[23];
    const float* Wvb   = (const float*)d_in[24];
    const float* b_vb  = (const float*)d_in[25];
    const float* Wrel3 = (const float*)d_in[26];
    const float* b_rel3= (const float*)d_in[27];
    const float* Wm1   = (const float*)d_in[28];
    const float* b_m1  = (const float*)d_in[29];
    const float* Wm2   = (const float*)d_in[30];
    const float* b_m2  = (const float*)d_in[31];
    const float* Wout  = (const float*)d_in[32];
    const float* b_out = (const float*)d_in[33];
    const float* Mi0   = (const float*)d_in[34];
    const float* Mr0   = (const float*)d_in[35];
    const float* fc_g  = (const float*)d_in[36];
    const float* fc_b  = (const float*)d_in[37];
    const float* Wfc   = (const float*)d_in[38];
    const float* b_fc  = (const float*)d_in[39];

    float* ws = (float*)d_ws;
    float* v_all   = ws;                          // T*B*S    = 262144
    float* gIn_all = v_all   + T_ * B_ * S_;      // T*B*2S   = 524288
    float* w3_all  = gIn_all + T_ * B_ * 2 * S_;  // T*B*N    = 16384
    float* xo_all  = w3_all  + T_ * B_ * N_;      // T*B*O    = 262144
    float* o_all   = xo_all  + T_ * B_ * O_;      // T*B*O    = 262144

    k1_pre<<<dim3((T_ * B_) / 8), dim3(256), 0, stream>>>(
        ids, emb, We, be, Win, b_in, Win2, b_in2, Win3, b_in3, Wig, b_ig,
        v_all, gIn_all, w3_all, xo_all);

    k2_scan<<<dim3(B_), dim3(1024), 0, stream>>>(
        v_all, gIn_all, w3_all, xo_all,
        Wmg, b_mg, Wqkv, b_qkv, ln_g, ln_b,
        Wrel, b_rel, Wvb, b_vb, Wrel3, b_rel3,
        Mi0, Mr0, ibp, fbp, a1p, a2p, o_all);

    k3_post<<<dim3((T_ * B_) / 8), dim3(256), 0, stream>>>(
        o_all, Wm1, b_m1, Wm2, b_m2, Wout, b_out, fc_g, fc_b, Wfc, b_fc,
        (float*)d_out);
}

// Round 3
// 1493.728 us; speedup vs baseline: 3.0738x; 2.7490x over previous
//
#include <hip/hip_runtime.h>
#include <hip/hip_fp16.h>
#include <math.h>

#define T_ 128
#define B_ 32
#define D_ 512
#define V_ 128
#define S_ 64
#define N_ 4
#define R_ 64
#define O_ 64

typedef _Float16 h4 __attribute__((ext_vector_type(4)));
typedef _Float16 h8 __attribute__((ext_vector_type(8)));
typedef float f4 __attribute__((ext_vector_type(4)));

__device__ __forceinline__ float fsigm(float x) {
    return __fdividef(1.0f, 1.0f + __expf(-x));
}
__device__ __forceinline__ float ftanh(float x) {
    x = fminf(15.f, fmaxf(-15.f, x));
    float e = __expf(2.f * x);
    return 1.f - __fdividef(2.f, e + 1.f);
}

// swizzled f16 element offset for a [rows][64] operand tile:
// logical (row, k) -> row*64 + (((k&~3) ^ ((row&7)<<2)) | (k&3))
__device__ __forceinline__ int swz(int row, int k) {
    return row * 64 + (((k & ~3) ^ ((row & 7) << 2)) | (k & 3));
}

// ---------------------------------------------------------------------------
// K1: precompute (all t,b in parallel) — unchanged from round 2
// ---------------------------------------------------------------------------
__global__ __launch_bounds__(256)
void k1_pre(const int* __restrict__ ids, const float* __restrict__ emb,
            const float* __restrict__ We, const float* __restrict__ be,
            const float* __restrict__ Win, const float* __restrict__ b_in,
            const float* __restrict__ Win2, const float* __restrict__ b_in2,
            const float* __restrict__ Win3, const float* __restrict__ b_in3,
            const float* __restrict__ Wig, const float* __restrict__ b_ig,
            float* __restrict__ v_all, float* __restrict__ gIn_all,
            float* __restrict__ w3_all, float* __restrict__ xo_all)
{
    __shared__ float E[8][D_];
    __shared__ float X[8][D_];
    __shared__ float vs[8][S_];
    __shared__ float sc[8][N_];
    const int tid = threadIdx.x;
    const int f0 = blockIdx.x * 8;

    for (int i = tid; i < 8 * D_; i += 256) {
        int r = i >> 9, d = i & (D_ - 1);
        int f = f0 + r;
        int t = f >> 5, b = f & 31;
        E[r][d] = emb[ids[b * T_ + t] * D_ + d];
    }
    __syncthreads();

    { // src = E @ We + be
        const int d0 = tid, d1 = tid + 256;
        float a0[8], a1[8];
        float b0 = be[d0], b1 = be[d1];
#pragma unroll
        for (int r = 0; r < 8; ++r) { a0[r] = b0; a1[r] = b1; }
        for (int k = 0; k < D_; ++k) {
            float w0 = We[k * D_ + d0], w1 = We[k * D_ + d1];
#pragma unroll
            for (int r = 0; r < 8; ++r) {
                float e = E[r][k];
                a0[r] = fmaf(e, w0, a0[r]);
                a1[r] = fmaf(e, w1, a1[r]);
            }
        }
#pragma unroll
        for (int r = 0; r < 8; ++r) { X[r][d0] = a0[r]; X[r][d1] = a1[r]; }
    }
    __syncthreads();

    { // v and xo
        const int j = tid & 63, r0 = tid >> 6;
#pragma unroll
        for (int ri = 0; ri < 2; ++ri) {
            int r = r0 + 4 * ri;
            float a = b_in[j], a2 = b_in2[j];
            for (int k = 0; k < D_; ++k) {
                float x = X[r][k];
                a  = fmaf(x, Win [k * S_ + j], a);
                a2 = fmaf(x, Win2[k * O_ + j], a2);
            }
            vs[r][j] = a;
            v_all [(f0 + r) * S_ + j] = a;
            xo_all[(f0 + r) * O_ + j] = a2;
        }
    }
    if (tid < 32) {
        int r = tid >> 2, n = tid & 3;
        float a = b_in3[n];
        for (int k = 0; k < D_; ++k) a = fmaf(X[r][k], Win3[k * N_ + n], a);
        sc[r][n] = a;
    }
    __syncthreads();
    if (tid < 8) {
        float x0 = sc[tid][0], x1 = sc[tid][1], x2 = sc[tid][2], x3 = sc[tid][3];
        float m = fmaxf(fmaxf(x0, x1), fmaxf(x2, x3));
        float e0 = expf(x0 - m), e1 = expf(x1 - m), e2 = expf(x2 - m), e3 = expf(x3 - m);
        float inv = 1.0f / (e0 + e1 + e2 + e3);
        float* w = &w3_all[(f0 + tid) * N_];
        w[0] = e0 * inv; w[1] = e1 * inv; w[2] = e2 * inv; w[3] = e3 * inv;
    }
    {
        const int c = tid & 127, r0 = tid >> 7;
#pragma unroll
        for (int ri = 0; ri < 4; ++ri) {
            int r = r0 + 2 * ri;
            float a = b_ig[c];
            for (int k = 0; k < S_; ++k) a = fmaf(vs[r][k], Wig[k * 2 * S_ + c], a);
            gIn_all[(f0 + r) * 2 * S_ + c] = a;
        }
    }
}

// ---------------------------------------------------------------------------
// K2: sequential scan, MFMA edition. One block (1024 thr) per batch.
// All matmul phases on v_mfma_f32_16x16x32_f16 with fp16 operands staged in
// swizzled LDS; Mi/Mrs f32 in LDS; all loop-invariant weights staged.
// ---------------------------------------------------------------------------
__global__ __launch_bounds__(1024)
void k2_scan(const float* __restrict__ v_all, const float* __restrict__ gIn_all,
             const float* __restrict__ w3_all, const float* __restrict__ xo_all,
             const float* __restrict__ Wmg, const float* __restrict__ b_mg,
             const float* __restrict__ Wqkv, const float* __restrict__ b_qkv,
             const float* __restrict__ ln_g, const float* __restrict__ ln_b,
             const float* __restrict__ Wrel, const float* __restrict__ b_rel,
             const float* __restrict__ Wvb, const float* __restrict__ b_vb,
             const float* __restrict__ Wrel3, const float* __restrict__ b_rel3,
             const float* __restrict__ Mi0, const float* __restrict__ Mr0,
             const float* __restrict__ p_ib, const float* __restrict__ p_fb,
             const float* __restrict__ p_a1, const float* __restrict__ p_a2,
             float* __restrict__ o_all)
{
    const int tid = threadIdx.x;
    const int b = blockIdx.x;
    const int wv = tid >> 6;        // wave id 0..15
    const int ln = tid & 63;        // lane
    const int g  = ln >> 4;         // 4-lane-group (k-chunk selector)
    const int li = ln & 15;         // index within 16

    __shared__ __align__(16) float MrsF[N_ * S_ * R_];      // 65536
    __shared__ __align__(16) float Mi_s[S_ * 68];           // 17408 (padded rows)
    __shared__ __align__(16) _Float16 As[S_ * S_];          // 8192: tanh(Mi), then transfer
    __shared__ __align__(16) _Float16 Mif16[S_ * S_];       // 8192: Mi after phase B
    __shared__ __align__(16) _Float16 vvA[16 * S_];         // 2048 (rows 4-15 zero)
    __shared__ __align__(16) _Float16 raccA[16 * S_];       // 2048 (rows 4-15 zero)
    __shared__ __align__(16) _Float16 WmgT[2 * S_ * S_];    // 16384 [j][k]
    __shared__ __align__(16) _Float16 WvbT[S_ * S_];        // 8192  [j][r]
    __shared__ __align__(16) _Float16 WrelT[S_ * S_];       // 8192  [r][s]
    __shared__ __align__(16) _Float16 Wrel3T[S_ * S_];      // 8192  [o][r]
    __shared__ __align__(16) _Float16 WqkvT[16 * S_];       // 2048  [c][k], c>=12 zero
    __shared__ float ln_g_s[768], ln_b_s[768];              // 6144
    __shared__ float bmgin[128];                            // b_mg + gIn(t)
    __shared__ float b_mg_s[128];
    __shared__ float b_vb_s[64], b_rel_s[64], b_rel3_s[64];
    __shared__ float b_qkv_s[16];
    __shared__ float qkvp[768];                             // qkv pre-LN [s][c]
    __shared__ float qkn[512];                              // post-LN q,k [s][8]
    __shared__ float vvs[N_][S_];
    __shared__ float wvm[N_][S_];
    __shared__ float Amat[N_][N_];
    __shared__ float vt[S_];
    __shared__ float w3s[N_];
    __shared__ float red1[4], red2[4];

    const float ib = p_ib[0], fb = p_fb[0], a1 = p_a1[0], a2v = p_a2[0];

    #define MI(r, c) Mi_s[(r) * 68 + (c)]

    // ---- prefetch t=0 per-step inputs into regs ----
    float pf_v = 0.f, pf_w3 = 0.f, pf_gin = 0.f;
    {
        const int f0 = b;  // t=0: f = 0*B+b
        if (tid < 64) pf_v = v_all[f0 * S_ + tid];
        else if (tid < 68) pf_w3 = w3_all[f0 * N_ + (tid - 64)];
        if (tid >= 128 && tid < 256) pf_gin = gIn_all[f0 * 2 * S_ + (tid - 128)];
    }

    // ---- init: stage swizzled f16 weights, biases, Mi, Mrs ----
    for (int i = tid; i < 2 * S_ * S_; i += 1024) {        // Wmg (64,128) -> WmgT[j][k]
        int k = i >> 7, j = i & 127;
        WmgT[swz(j, k)] = (_Float16)Wmg[i];
    }
    for (int i = tid; i < S_ * S_; i += 1024) {            // Wvb (64,64) -> WvbT[j][r]
        int r = i >> 6, j = i & 63;
        WvbT[swz(j, r)] = (_Float16)Wvb[i];
    }
    for (int i = tid; i < S_ * S_; i += 1024) {            // Wrel (64s,64r) -> WrelT[r][s]
        int s = i >> 6, r = i & 63;
        WrelT[swz(r, s)] = (_Float16)Wrel[i];
    }
    for (int i = tid; i < S_ * S_; i += 1024) {            // Wrel3 (64r,64o) -> Wrel3T[o][r]
        int r = i >> 6, o = i & 63;
        Wrel3T[swz(o, r)] = (_Float16)Wrel3[i];
    }
    if (tid < 16 * S_) {                                    // Wqkv (64,12) -> WqkvT[c][k]
        int c = tid >> 6, k = tid & 63;
        float w = (c < 12) ? Wqkv[k * 12 + c] : 0.f;
        WqkvT[swz(c, k)] = (_Float16)w;
    }
    if (tid < 768) { ln_g_s[tid] = ln_g[tid]; ln_b_s[tid] = ln_b[tid]; }
    if (tid < 128) b_mg_s[tid] = b_mg[tid];
    else if (tid < 192) b_vb_s[tid - 128] = b_vb[tid - 128];
    else if (tid < 256) b_rel_s[tid - 192] = b_rel[tid - 192];
    else if (tid < 320) b_rel3_s[tid - 256] = b_rel3[tid - 256];
    else if (tid < 336) b_qkv_s[tid - 320] = (tid - 320 < 12) ? b_qkv[tid - 320] : 0.f;
    if (tid < 1024) { vvA[tid] = (_Float16)0.f; raccA[tid] = (_Float16)0.f; }
    for (int i = tid; i < S_ * S_; i += 1024) MI(i >> 6, i & 63) = Mi0[i];
    for (int i = tid; i < N_ * S_ * R_; i += 1024) MrsF[i] = Mr0[i];
    __syncthreads();

    float xo_reg = 0.f, w3r0 = 0.f, w3r1 = 0.f, w3r2 = 0.f, w3r3 = 0.f;

    for (int t = 0; t < T_; ++t) {
        const int f = t * B_ + b;

        // ============ TOP: write prefetched inputs; As = tanh(Mi) ============
        if (tid < 64) vt[tid] = pf_v;
        else if (tid < 68) w3s[tid - 64] = pf_w3;
        if (tid >= 128 && tid < 256) bmgin[tid - 128] = b_mg_s[tid - 128] + pf_gin;
        {
            const int row = tid >> 4, k0 = (tid & 15) << 2;
            const float4 m4 = *(const float4*)&MI(row, k0);
            h4 t4;
            t4[0] = (_Float16)ftanh(m4.x); t4[1] = (_Float16)ftanh(m4.y);
            t4[2] = (_Float16)ftanh(m4.z); t4[3] = (_Float16)ftanh(m4.w);
            *(h4*)&As[row * 64 + (k0 ^ ((row & 7) << 2))] = t4;
        }
        __syncthreads();   // (1)

        // ============ B: gates MFMA; Mi = gf*Mi + gi*tanh(v v^T) ============
        if (wv < 8) {
            const int rowbase = (wv & 3) << 4;
            const int tc0 = (wv >> 2) << 1;
            h8 afr[2];
#pragma unroll
            for (int ks = 0; ks < 2; ++ks) {
                const int i = rowbase + li;
                const int sw = (i & 7) << 2;
                const int c0 = (ks << 5) + (g << 2);
                h4 lo = *(const h4*)&As[i * 64 + (c0 ^ sw)];
                h4 hi = *(const h4*)&As[i * 64 + ((c0 + 16) ^ sw)];
                afr[ks] = __builtin_shufflevector(lo, hi, 0, 1, 2, 3, 4, 5, 6, 7);
            }
#pragma unroll
            for (int tt = 0; tt < 2; ++tt) {
                const int tc = tc0 + tt;
                const int colI = (tc << 4) + li;
                const int colF = colI + 64;
                const float bi = bmgin[colI], bfv = bmgin[colF];
                f4 accI = {bi, bi, bi, bi};
                f4 accF = {bfv, bfv, bfv, bfv};
#pragma unroll
                for (int ks = 0; ks < 2; ++ks) {
                    const int c0 = (ks << 5) + (g << 2);
                    const int swc = (colI & 7) << 2;   // colF has same low bits
                    h4 blo = *(const h4*)&WmgT[colI * 64 + (c0 ^ swc)];
                    h4 bhi = *(const h4*)&WmgT[colI * 64 + ((c0 + 16) ^ swc)];
                    h8 bfr = __builtin_shufflevector(blo, bhi, 0, 1, 2, 3, 4, 5, 6, 7);
                    accI = __builtin_amdgcn_mfma_f32_16x16x32_f16(afr[ks], bfr, accI, 0, 0, 0);
                    blo = *(const h4*)&WmgT[colF * 64 + (c0 ^ swc)];
                    bhi = *(const h4*)&WmgT[colF * 64 + ((c0 + 16) ^ swc)];
                    bfr = __builtin_shufflevector(blo, bhi, 0, 1, 2, 3, 4, 5, 6, 7);
                    accF = __builtin_amdgcn_mfma_f32_16x16x32_f16(afr[ks], bfr, accF, 0, 0, 0);
                }
                const float vc = vt[colI];
#pragma unroll
                for (int r = 0; r < 4; ++r) {
                    const int row = rowbase + (g << 2) + r;
                    const float gi = fsigm(accI[r] + ib);
                    const float gf = fsigm(accF[r] + fb);
                    const float mo = MI(row, colI);
                    const float mn = gf * mo + gi * ftanh(vt[row] * vc);
                    MI(row, colI) = mn;
                    Mif16[swz(row, colI)] = (_Float16)mn;
                }
            }
        }
        __syncthreads();   // (2)

        // ============ C: qkv MFMA + LayerNorm(768) ============
        if (wv < 4) {
            const int rowbase = wv << 4;
            h8 afr[2];
#pragma unroll
            for (int ks = 0; ks < 2; ++ks) {
                const int i = rowbase + li;
                const int sw = (i & 7) << 2;
                const int c0 = (ks << 5) + (g << 2);
                h4 lo = *(const h4*)&Mif16[i * 64 + (c0 ^ sw)];
                h4 hi = *(const h4*)&Mif16[i * 64 + ((c0 + 16) ^ sw)];
                afr[ks] = __builtin_shufflevector(lo, hi, 0, 1, 2, 3, 4, 5, 6, 7);
            }
            const float bq = b_qkv_s[li];
            f4 qacc = {bq, bq, bq, bq};
#pragma unroll
            for (int ks = 0; ks < 2; ++ks) {
                const int c0 = (ks << 5) + (g << 2);
                const int sw = (li & 7) << 2;
                h4 blo = *(const h4*)&WqkvT[li * 64 + (c0 ^ sw)];
                h4 bhi = *(const h4*)&WqkvT[li * 64 + ((c0 + 16) ^ sw)];
                h8 bfr = __builtin_shufflevector(blo, bhi, 0, 1, 2, 3, 4, 5, 6, 7);
                qacc = __builtin_amdgcn_mfma_f32_16x16x32_f16(afr[ks], bfr, qacc, 0, 0, 0);
            }
            float s1 = 0.f, s2 = 0.f;
            if (li < 12) {
#pragma unroll
                for (int r = 0; r < 4; ++r) {
                    const int row = rowbase + (g << 2) + r;
                    qkvp[row * 12 + li] = qacc[r];
                    s1 += qacc[r]; s2 += qacc[r] * qacc[r];
                }
            }
#pragma unroll
            for (int off = 32; off; off >>= 1) {
                s1 += __shfl_down(s1, off); s2 += __shfl_down(s2, off);
            }
            if (ln == 0) { red1[wv] = s1; red2[wv] = s2; }
        }
        __syncthreads();   // (3)
        {
            const float sA = red1[0] + red1[1] + red1[2] + red1[3];
            const float sB = red2[0] + red2[1] + red2[2] + red2[3];
            const float mu = sA * (1.f / 768.f);
            const float var = sB * (1.f / 768.f) - mu * mu;
            const float rstd = rsqrtf(var + 1e-5f);
            if (tid < 768) {
                const int cs = tid / 12, cc = tid - cs * 12;
                const float qn = (qkvp[tid] - mu) * rstd * ln_g_s[tid] + ln_b_s[tid];
                if (cc < 8) qkn[cs * 8 + cc] = qn;
                else {
                    const int m = cc - 8;
                    vvs[m][cs] = qn;
                    vvA[swz(m, cs)] = (_Float16)qn;
                }
            }
        }
        __syncthreads();   // (4)

        // ============ D: wvm = vv @ Wrel (MFMA); Amat softmax (wave 8) ======
        if (wv < 4) {
            if (ln < 16) xo_reg = xo_all[f * O_ + (wv << 4) + ln];  // early for F2
            h8 afr[2];
#pragma unroll
            for (int ks = 0; ks < 2; ++ks) {
                const int sw = (li & 7) << 2;
                const int c0 = (ks << 5) + (g << 2);
                h4 lo = *(const h4*)&vvA[li * 64 + (c0 ^ sw)];
                h4 hi = *(const h4*)&vvA[li * 64 + ((c0 + 16) ^ sw)];
                afr[ks] = __builtin_shufflevector(lo, hi, 0, 1, 2, 3, 4, 5, 6, 7);
            }
            const int col = (wv << 4) + li;
            f4 acc = {0.f, 0.f, 0.f, 0.f};
#pragma unroll
            for (int ks = 0; ks < 2; ++ks) {
                const int c0 = (ks << 5) + (g << 2);
                const int sw = (col & 7) << 2;
                h4 blo = *(const h4*)&WrelT[col * 64 + (c0 ^ sw)];
                h4 bhi = *(const h4*)&WrelT[col * 64 + ((c0 + 16) ^ sw)];
                h8 bfr = __builtin_shufflevector(blo, bhi, 0, 1, 2, 3, 4, 5, 6, 7);
                acc = __builtin_amdgcn_mfma_f32_16x16x32_f16(afr[ks], bfr, acc, 0, 0, 0);
            }
            if (ln < 16) {
#pragma unroll
                for (int r = 0; r < 4; ++r) wvm[r][(wv << 4) + ln] = acc[r];
            }
        } else if (wv == 8 && ln < 16) {
            const int n = ln >> 2, m = ln & 3;
            float a = 0.f;
            for (int k = 0; k < S_; ++k) a = fmaf(qkn[k * 8 + n], qkn[k * 8 + 4 + m], a);
            a *= 0.125f;  // 1/sqrt(64)
            float mx = fmaxf(a, __shfl_xor(a, 1));
            mx = fmaxf(mx, __shfl_xor(mx, 2));
            float e = __expf(a - mx);
            float sm = e + __shfl_xor(e, 1);
            sm = sm + __shfl_xor(sm, 2);
            Amat[n][m] = __fdividef(e, sm);
        }
        __syncthreads();   // (5)

        // ============ E: Mrs += a1*(delta + b_rel); transfer -> As (f16) ====
        {
            const int rr = tid & 63, g2 = tid >> 6;
            // prefetch next-step inputs (independent global loads)
            const int fn = ((t < T_ - 1) ? t + 1 : t) * B_ + b;
            if (tid < 64) pf_v = v_all[fn * S_ + tid];
            else if (tid < 68) pf_w3 = w3_all[fn * N_ + (tid - 64)];
            if (tid >= 128 && tid < 256) pf_gin = gIn_all[fn * 2 * S_ + (tid - 128)];

            const float brel = b_rel_s[rr];
            const float wv0 = wvm[0][rr], wv1 = wvm[1][rr], wv2 = wvm[2][rr], wv3 = wvm[3][rr];
#pragma unroll
            for (int shi = 0; shi < 4; ++shi) {
                const int s = (shi << 4) + g2;
                const float vv0 = vvs[0][s], vv1 = vvs[1][s], vv2 = vvs[2][s], vv3 = vvs[3][s];
                float trans = 0.f;
#pragma unroll
                for (int n = 0; n < 4; ++n) {
                    const float delta = (Amat[n][0] * vv0) * wv0 + (Amat[n][1] * vv1) * wv1
                                      + (Amat[n][2] * vv2) * wv2 + (Amat[n][3] * vv3) * wv3;
                    const int idx = n * (S_ * R_) + s * R_ + rr;
                    const float upd = MrsF[idx] + a1 * (delta + brel);
                    MrsF[idx] = upd;
                    trans += w3s[n] * upd;
                }
                As[swz(s, rr)] = (_Float16)trans;   // As reused as transfer operand
            }
        }
        __syncthreads();   // (6)

        // ============ F1: Mi += a2*tanh(transfer@Wvb + b_vb) (waves 0-7 MFMA)
        //              racc = v . Mrs (waves 8-11, VALU) =====================
        if (wv < 8) {
            w3r0 = w3s[0]; w3r1 = w3s[1]; w3r2 = w3s[2]; w3r3 = w3s[3];
            const int rowbase = (wv & 3) << 4;
            const int tc0 = (wv >> 2) << 1;
            h8 afr[2];
#pragma unroll
            for (int ks = 0; ks < 2; ++ks) {
                const int i = rowbase + li;
                const int sw = (i & 7) << 2;
                const int c0 = (ks << 5) + (g << 2);
                h4 lo = *(const h4*)&As[i * 64 + (c0 ^ sw)];
                h4 hi = *(const h4*)&As[i * 64 + ((c0 + 16) ^ sw)];
                afr[ks] = __builtin_shufflevector(lo, hi, 0, 1, 2, 3, 4, 5, 6, 7);
            }
#pragma unroll
            for (int tt = 0; tt < 2; ++tt) {
                const int col = ((tc0 + tt) << 4) + li;
                const float bv = b_vb_s[col];
                f4 acc = {bv, bv, bv, bv};
#pragma unroll
                for (int ks = 0; ks < 2; ++ks) {
                    const int c0 = (ks << 5) + (g << 2);
                    const int sw = (col & 7) << 2;
                    h4 blo = *(const h4*)&WvbT[col * 64 + (c0 ^ sw)];
                    h4 bhi = *(const h4*)&WvbT[col * 64 + ((c0 + 16) ^ sw)];
                    h8 bfr = __builtin_shufflevector(blo, bhi, 0, 1, 2, 3, 4, 5, 6, 7);
                    acc = __builtin_amdgcn_mfma_f32_16x16x32_f16(afr[ks], bfr, acc, 0, 0, 0);
                }
#pragma unroll
                for (int r = 0; r < 4; ++r) {
                    const int row = rowbase + (g << 2) + r;
                    MI(row, col) += a2v * ftanh(acc[r]);
                }
            }
        } else if (wv < 12) {
            const int n = wv - 8;
            const float* mrp = &MrsF[n * (S_ * R_) + ln];
            float a = 0.f;
#pragma unroll 8
            for (int s = 0; s < S_; ++s) a = fmaf(vt[s], mrp[s * R_], a);
            raccA[swz(n, ln)] = (_Float16)a;
        }
        __syncthreads();   // (7)

        // ============ F2 (+F3 fused): r3 MFMA; o -> global =================
        if (wv < 4) {
            h8 afr[2];
#pragma unroll
            for (int ks = 0; ks < 2; ++ks) {
                const int sw = (li & 7) << 2;
                const int c0 = (ks << 5) + (g << 2);
                h4 lo = *(const h4*)&raccA[li * 64 + (c0 ^ sw)];
                h4 hi = *(const h4*)&raccA[li * 64 + ((c0 + 16) ^ sw)];
                afr[ks] = __builtin_shufflevector(lo, hi, 0, 1, 2, 3, 4, 5, 6, 7);
            }
            const int col = (wv << 4) + li;
            const float br3 = b_rel3_s[col];
            f4 acc = {br3, br3, br3, br3};
#pragma unroll
            for (int ks = 0; ks < 2; ++ks) {
                const int c0 = (ks << 5) + (g << 2);
                const int sw = (col & 7) << 2;
                h4 blo = *(const h4*)&Wrel3T[col * 64 + (c0 ^ sw)];
                h4 bhi = *(const h4*)&Wrel3T[col * 64 + ((c0 + 16) ^ sw)];
                h8 bfr = __builtin_shufflevector(blo, bhi, 0, 1, 2, 3, 4, 5, 6, 7);
                acc = __builtin_amdgcn_mfma_f32_16x16x32_f16(afr[ks], bfr, acc, 0, 0, 0);
            }
            if (ln < 16) {
                const float o = w3r0 * acc[0] + w3r1 * acc[1] + w3r2 * acc[2] + w3r3 * acc[3]
                              + xo_reg;
                o_all[f * O_ + (wv << 4) + ln] = o;
            }
        }
        // no barrier here: next TOP only touches {vt,w3s,bmgin,As,Mi} which
        // F2 does not read/write (w3/xo are in registers); barrier (1) gates B.
    }
    #undef MI
}

// ---------------------------------------------------------------------------
// K3: post-pass MLP + final head — unchanged from round 2
// ---------------------------------------------------------------------------
__global__ __launch_bounds__(256)
void k3_post(const float* __restrict__ o_all,
             const float* __restrict__ Wm1, const float* __restrict__ b_m1,
             const float* __restrict__ Wm2, const float* __restrict__ b_m2,
             const float* __restrict__ Wout, const float* __restrict__ b_out,
             const float* __restrict__ fc_g, const float* __restrict__ fc_b,
             const float* __restrict__ Wfc, const float* __restrict__ b_fc,
             float* __restrict__ out)
{
    __shared__ float os[8][O_];
    __shared__ float h1[8][D_];
    __shared__ float h2[8][D_];
    __shared__ float mus[8], rst[8];
    const int tid = threadIdx.x;
    const int f0 = blockIdx.x * 8;

    for (int i = tid; i < 8 * O_; i += 256) os[i >> 6][i & 63] = o_all[f0 * O_ + i];
    __syncthreads();

    const int d0 = tid, d1 = tid + 256;
    {
        float a0[8], a1[8];
        float b0 = b_m1[d0], b1 = b_m1[d1];
#pragma unroll
        for (int r = 0; r < 8; ++r) { a0[r] = b0; a1[r] = b1; }
        for (int k = 0; k < O_; ++k) {
            float w0 = Wm1[k * D_ + d0], w1 = Wm1[k * D_ + d1];
#pragma unroll
            for (int r = 0; r < 8; ++r) {
                float e = os[r][k];
                a0[r] = fmaf(e, w0, a0[r]); a1[r] = fmaf(e, w1, a1[r]);
            }
        }
#pragma unroll
        for (int r = 0; r < 8; ++r) { h1[r][d0] = fmaxf(a0[r], 0.f); h1[r][d1] = fmaxf(a1[r], 0.f); }
    }
    __syncthreads();
    {
        float a0[8], a1[8];
        float b0 = b_m2[d0], b1 = b_m2[d1];
#pragma unroll
        for (int r = 0; r < 8; ++r) { a0[r] = b0; a1[r] = b1; }
        for (int k = 0; k < D_; ++k) {
            float w0 = Wm2[k * D_ + d0], w1 = Wm2[k * D_ + d1];
#pragma unroll
            for (int r = 0; r < 8; ++r) {
                float e = h1[r][k];
                a0[r] = fmaf(e, w0, a0[r]); a1[r] = fmaf(e, w1, a1[r]);
            }
        }
#pragma unroll
        for (int r = 0; r < 8; ++r) { h2[r][d0] = fmaxf(a0[r], 0.f); h2[r][d1] = fmaxf(a1[r], 0.f); }
    }
    __syncthreads();
    {
        float a0[8], a1[8];
        float b0 = b_out[d0], b1 = b_out[d1];
#pragma unroll
        for (int r = 0; r < 8; ++r) { a0[r] = b0; a1[r] = b1; }
        for (int k = 0; k < D_; ++k) {
            float w0 = Wout[k * D_ + d0], w1 = Wout[k * D_ + d1];
#pragma unroll
            for (int r = 0; r < 8; ++r) {
                float e = h2[r][k];
                a0[r] = fmaf(e, w0, a0[r]); a1[r] = fmaf(e, w1, a1[r]);
            }
        }
#pragma unroll
        for (int r = 0; r < 8; ++r) { h1[r][d0] = a0[r]; h1[r][d1] = a1[r]; }
    }
    __syncthreads();
    {
        const int r = tid >> 5, l = tid & 31;
        float s1 = 0.f, s2 = 0.f;
        for (int k = l; k < D_; k += 32) { float y = h1[r][k]; s1 += y; s2 += y * y; }
#pragma unroll
        for (int off = 16; off; off >>= 1) { s1 += __shfl_down(s1, off, 32); s2 += __shfl_down(s2, off, 32); }
        if (l == 0) {
            float mu = s1 / (float)D_;
            float var = s2 / (float)D_ - mu * mu;
            mus[r] = mu; rst[r] = rsqrtf(var + 1e-5f);
        }
    }
    __syncthreads();
    for (int i = tid; i < 8 * D_; i += 256) {
        int r = i >> 9, d = i & (D_ - 1);
        float y = (h1[r][d] - mus[r]) * rst[r] * fc_g[d] + fc_b[d];
        h1[r][d] = fmaxf(y, 0.f);
    }
    __syncthreads();
    {
        const int v = tid & 127, r0 = tid >> 7;
#pragma unroll
        for (int ri = 0; ri < 4; ++ri) {
            int r = r0 + 2 * ri;
            float a = b_fc[v];
            for (int k = 0; k < D_; ++k) a = fmaf(h1[r][k], Wfc[k * V_ + v], a);
            int f = f0 + r, t = f >> 5, b = f & 31;
            out[b * (V_ * T_) + v * T_ + t] = a;
        }
    }
}

// ---------------------------------------------------------------------------
extern "C" void kernel_launch(void* const* d_in, const int* in_sizes, int n_in,
                              void* d_out, int out_size, void* d_ws, size_t ws_size,
                              hipStream_t stream)
{
    (void)in_sizes; (void)n_in; (void)out_size; (void)ws_size;
    const int*   ids   = (const int*)  d_in[0];
    const float* emb   = (const float*)d_in[1];
    const float* We    = (const float*)d_in[2];
    const float* be    = (const float*)d_in[3];
    const float* Win   = (const float*)d_in[4];
    const float* b_in  = (const float*)d_in[5];
    const float* Win2  = (const float*)d_in[6];
    const float* b_in2 = (const float*)d_in[7];
    const float* Win3  = (const float*)d_in[8];
    const float* b_in3 = (const float*)d_in[9];
    const float* Wig   = (const float*)d_in[10];
    const float* b_ig  = (const float*)d_in[11];
    const float* Wmg   = (const float*)d_in[12];
    const float* b_mg  = (const float*)d_in[13];
    const float* ibp   = (const float*)d_in[14];
    const float* fbp   = (const float*)d_in[15];
    const float* Wqkv  = (const float*)d_in[16];
    const float* b_qkv = (const float*)d_in[17];
    const float* ln_g  = (const float*)d_in[18];
    const float* ln_b  = (const float*)d_in[19];
    const float* a1p   = (const float*)d_in[20];
    const float* a2p   = (const float*)d_in[21];
    const float* Wrel  = (const float*)d_in[22];
    const float* b_rel = (const float*)d_in[23];
    const float* Wvb   = (const float*)d_in[24];
    const float* b_vb  = (const float*)d_in[25];
    const float* Wrel3 = (const float*)d_in[26];
    const float* b_rel3= (const float*)d_in[27];
    const float* Wm1   = (const float*)d_in[28];
    const float* b_m1  = (const float*)d_in[29];
    const float* Wm2   = (const float*)d_in[30];
    const float* b_m2  = (const float*)d_in[31];
    const float* Wout  = (const float*)d_in[32];
    const float* b_out = (const float*)d_in[33];
    const float* Mi0   = (const float*)d_in[34];
    const float* Mr0   = (const float*)d_in[35];
    const float* fc_g  = (const float*)d_in[36];
    const float* fc_b  = (const float*)d_in[37];
    const float* Wfc   = (const float*)d_in[38];
    const float* b_fc  = (const float*)d_in[39];

    float* ws = (float*)d_ws;
    float* v_all   = ws;                          // T*B*S
    float* gIn_all = v_all   + T_ * B_ * S_;      // T*B*2S
    float* w3_all  = gIn_all + T_ * B_ * 2 * S_;  // T*B*N
    float* xo_all  = w3_all  + T_ * B_ * N_;      // T*B*O
    float* o_all   = xo_all  + T_ * B_ * O_;      // T*B*O

    k1_pre<<<dim3((T_ * B_) / 8), dim3(256), 0, stream>>>(
        ids, emb, We, be, Win, b_in, Win2, b_in2, Win3, b_in3, Wig, b_ig,
        v_all, gIn_all, w3_all, xo_all);

    k2_scan<<<dim3(B_), dim3(1024), 0, stream>>>(
        v_all, gIn_all, w3_all, xo_all,
        Wmg, b_mg, Wqkv, b_qkv, ln_g, ln_b,
        Wrel, b_rel, Wvb, b_vb, Wrel3, b_rel3,
        Mi0, Mr0, ibp, fbp, a1p, a2p, o_all);

    k3_post<<<dim3((T_ * B_) / 8), dim3(256), 0, stream>>>(
        o_all, Wm1, b_m1, Wm2, b_m2, Wout, b_out, fc_g, fc_b, Wfc, b_fc,
        (float*)d_out);
}

// Round 4
// 1374.721 us; speedup vs baseline: 3.3399x; 1.0866x over previous
//
#include <hip/hip_runtime.h>
#include <hip/hip_fp16.h>
#include <math.h>

#define T_ 128
#define B_ 32
#define D_ 512
#define V_ 128
#define S_ 64
#define N_ 4
#define R_ 64
#define O_ 64

typedef _Float16 h4 __attribute__((ext_vector_type(4)));
typedef _Float16 h8 __attribute__((ext_vector_type(8)));
typedef float f4 __attribute__((ext_vector_type(4)));

__device__ __forceinline__ float fsigm(float x) {
    return __fdividef(1.0f, 1.0f + __expf(-x));
}
__device__ __forceinline__ float ftanh(float x) {
    x = fminf(15.f, fmaxf(-15.f, x));
    float e = __expf(2.f * x);
    return 1.f - __fdividef(2.f, e + 1.f);
}

// swizzled f16 element offset for a [rows][64] operand tile
__device__ __forceinline__ int swz(int row, int k) {
    return row * 64 + (((k & ~3) ^ ((row & 7) << 2)) | (k & 3));
}

// ---------------------------------------------------------------------------
// K1: precompute (all t,b in parallel) — unchanged
// ---------------------------------------------------------------------------
__global__ __launch_bounds__(256)
void k1_pre(const int* __restrict__ ids, const float* __restrict__ emb,
            const float* __restrict__ We, const float* __restrict__ be,
            const float* __restrict__ Win, const float* __restrict__ b_in,
            const float* __restrict__ Win2, const float* __restrict__ b_in2,
            const float* __restrict__ Win3, const float* __restrict__ b_in3,
            const float* __restrict__ Wig, const float* __restrict__ b_ig,
            float* __restrict__ v_all, float* __restrict__ gIn_all,
            float* __restrict__ w3_all, float* __restrict__ xo_all)
{
    __shared__ float E[8][D_];
    __shared__ float X[8][D_];
    __shared__ float vs[8][S_];
    __shared__ float sc[8][N_];
    const int tid = threadIdx.x;
    const int f0 = blockIdx.x * 8;

    for (int i = tid; i < 8 * D_; i += 256) {
        int r = i >> 9, d = i & (D_ - 1);
        int f = f0 + r;
        int t = f >> 5, b = f & 31;
        E[r][d] = emb[ids[b * T_ + t] * D_ + d];
    }
    __syncthreads();

    { // src = E @ We + be
        const int d0 = tid, d1 = tid + 256;
        float a0[8], a1[8];
        float b0 = be[d0], b1 = be[d1];
#pragma unroll
        for (int r = 0; r < 8; ++r) { a0[r] = b0; a1[r] = b1; }
        for (int k = 0; k < D_; ++k) {
            float w0 = We[k * D_ + d0], w1 = We[k * D_ + d1];
#pragma unroll
            for (int r = 0; r < 8; ++r) {
                float e = E[r][k];
                a0[r] = fmaf(e, w0, a0[r]);
                a1[r] = fmaf(e, w1, a1[r]);
            }
        }
#pragma unroll
        for (int r = 0; r < 8; ++r) { X[r][d0] = a0[r]; X[r][d1] = a1[r]; }
    }
    __syncthreads();

    { // v and xo
        const int j = tid & 63, r0 = tid >> 6;
#pragma unroll
        for (int ri = 0; ri < 2; ++ri) {
            int r = r0 + 4 * ri;
            float a = b_in[j], a2 = b_in2[j];
            for (int k = 0; k < D_; ++k) {
                float x = X[r][k];
                a  = fmaf(x, Win [k * S_ + j], a);
                a2 = fmaf(x, Win2[k * O_ + j], a2);
            }
            vs[r][j] = a;
            v_all [(f0 + r) * S_ + j] = a;
            xo_all[(f0 + r) * O_ + j] = a2;
        }
    }
    if (tid < 32) {
        int r = tid >> 2, n = tid & 3;
        float a = b_in3[n];
        for (int k = 0; k < D_; ++k) a = fmaf(X[r][k], Win3[k * N_ + n], a);
        sc[r][n] = a;
    }
    __syncthreads();
    if (tid < 8) {
        float x0 = sc[tid][0], x1 = sc[tid][1], x2 = sc[tid][2], x3 = sc[tid][3];
        float m = fmaxf(fmaxf(x0, x1), fmaxf(x2, x3));
        float e0 = expf(x0 - m), e1 = expf(x1 - m), e2 = expf(x2 - m), e3 = expf(x3 - m);
        float inv = 1.0f / (e0 + e1 + e2 + e3);
        float* w = &w3_all[(f0 + tid) * N_];
        w[0] = e0 * inv; w[1] = e1 * inv; w[2] = e2 * inv; w[3] = e3 * inv;
    }
    {
        const int c = tid & 127, r0 = tid >> 7;
#pragma unroll
        for (int ri = 0; ri < 4; ++ri) {
            int r = r0 + 2 * ri;
            float a = b_ig[c];
            for (int k = 0; k < S_; ++k) a = fmaf(vs[r][k], Wig[k * 2 * S_ + c], a);
            gIn_all[(f0 + r) * 2 * S_ + c] = a;
        }
    }
}

// ---------------------------------------------------------------------------
// K2: sequential scan. Mrs in REGISTERS (16 f32/thread). Mi in LDS.
// o = (v^T @ transfer) @ Wrel3 + b_rel3 + xo  (racc/r3 eliminated via Σw3=1).
// ---------------------------------------------------------------------------
__global__ __launch_bounds__(1024)
void k2_scan(const float* __restrict__ v_all, const float* __restrict__ gIn_all,
             const float* __restrict__ w3_all, const float* __restrict__ xo_all,
             const float* __restrict__ Wmg, const float* __restrict__ b_mg,
             const float* __restrict__ Wqkv, const float* __restrict__ b_qkv,
             const float* __restrict__ ln_g, const float* __restrict__ ln_b,
             const float* __restrict__ Wrel, const float* __restrict__ b_rel,
             const float* __restrict__ Wvb, const float* __restrict__ b_vb,
             const float* __restrict__ Wrel3, const float* __restrict__ b_rel3,
             const float* __restrict__ Mi0, const float* __restrict__ Mr0,
             const float* __restrict__ p_ib, const float* __restrict__ p_fb,
             const float* __restrict__ p_a1, const float* __restrict__ p_a2,
             float* __restrict__ o_all)
{
    const int tid = threadIdx.x;
    const int b = blockIdx.x;
    const int wv = tid >> 6;        // wave id 0..15
    const int ln = tid & 63;        // lane
    const int g  = ln >> 4;         // 4-lane-group
    const int li = ln & 15;

    __shared__ __align__(16) float Mi_s[S_ * 68];           // 17408
    __shared__ __align__(16) _Float16 AsT[S_ * S_];         // tanh(Mi): gates A-op
    __shared__ __align__(16) _Float16 AsX[S_ * S_];         // transfer: Wvb A-op
    __shared__ __align__(16) _Float16 Mif16[S_ * S_];       // Mi after gates: qkv A-op
    __shared__ __align__(16) _Float16 vvA[16 * S_];         // rows 4-15 zero
    __shared__ __align__(16) _Float16 tvecA[16 * S_];       // rows 1-15 zero
    __shared__ __align__(16) _Float16 WmgT[2 * S_ * S_];
    __shared__ __align__(16) _Float16 WvbT[S_ * S_];
    __shared__ __align__(16) _Float16 WrelT[S_ * S_];
    __shared__ __align__(16) _Float16 Wrel3T[S_ * S_];
    __shared__ __align__(16) _Float16 WqkvT[16 * S_];
    __shared__ float ln_g_s[768], ln_b_s[768];
    __shared__ __align__(16) float qkvp[768];
    __shared__ __align__(16) float qkT[8 * 68];             // q,k transposed, padded
    __shared__ __align__(16) float vvsT[S_ * 4];            // [s][m]
    __shared__ __align__(16) float wvm[N_][S_];
    __shared__ __align__(16) float wavepart[16][S_];
    __shared__ float bmgin[128];
    __shared__ float b_mg_s[128];
    __shared__ __align__(16) float b_vb_s[64], b_rel_s[64], b_rel3_s[64];
    __shared__ float b_qkv_s[16];
    __shared__ float vt[S_];
    __shared__ __align__(16) float w3s4[4];
    __shared__ __align__(16) float Amat[N_][N_];
    __shared__ float red1[4], red2[4];

    const float ib = p_ib[0], fb = p_fb[0], a1 = p_a1[0], a2v = p_a2[0];

    #define MI(r, c) Mi_s[(r) * 68 + (c)]

    // ---- init: stage weights/biases, Mi, AsT=tanh(Mi0), Mrs -> regs ----
    for (int i = tid; i < 2 * S_ * S_; i += 1024) {
        int k = i >> 7, j = i & 127;
        WmgT[swz(j, k)] = (_Float16)Wmg[i];
    }
    for (int i = tid; i < S_ * S_; i += 1024) {
        int r = i >> 6, j = i & 63;
        WvbT[swz(j, r)] = (_Float16)Wvb[i];
    }
    for (int i = tid; i < S_ * S_; i += 1024) {
        int s = i >> 6, r = i & 63;
        WrelT[swz(r, s)] = (_Float16)Wrel[i];
    }
    for (int i = tid; i < S_ * S_; i += 1024) {
        int r = i >> 6, o = i & 63;
        Wrel3T[swz(o, r)] = (_Float16)Wrel3[i];
    }
    if (tid < 16 * S_) {
        int c = tid >> 6, k = tid & 63;
        float w = (c < 12) ? Wqkv[k * 12 + c] : 0.f;
        WqkvT[swz(c, k)] = (_Float16)w;
    }
    if (tid < 768) { ln_g_s[tid] = ln_g[tid]; ln_b_s[tid] = ln_b[tid]; }
    if (tid < 128) b_mg_s[tid] = b_mg[tid];
    else if (tid < 192) b_vb_s[tid - 128] = b_vb[tid - 128];
    else if (tid < 256) b_rel_s[tid - 192] = b_rel[tid - 192];
    else if (tid < 320) b_rel3_s[tid - 256] = b_rel3[tid - 256];
    else if (tid < 336) b_qkv_s[tid - 320] = (tid - 320 < 12) ? b_qkv[tid - 320] : 0.f;
    if (tid < 1024) { vvA[tid] = (_Float16)0.f; tvecA[tid] = (_Float16)0.f; }
    for (int i = tid; i < S_ * S_; i += 1024) MI(i >> 6, i & 63) = Mi0[i];
    {   // AsT = tanh(Mi0), swizzled h4
        const int row = tid >> 4, k0 = (tid & 15) << 2;
        const float* mp = Mi0 + (tid << 2);
        h4 t4;
        t4[0] = (_Float16)ftanh(mp[0]); t4[1] = (_Float16)ftanh(mp[1]);
        t4[2] = (_Float16)ftanh(mp[2]); t4[3] = (_Float16)ftanh(mp[3]);
        *(h4*)&AsT[row * 64 + (k0 ^ ((row & 7) << 2))] = t4;
    }
    // Mrs -> registers: thread owns (s = tid>>4, r4 = (tid&15)*4), n = 0..3
    f4 mrs0, mrs1, mrs2, mrs3;
    {
        const int s0i = tid >> 4, r4i = (tid & 15) << 2;
        const float* mrp = Mr0 + s0i * 64 + r4i;
        mrs0 = *(const f4*)&mrp[0];
        mrs1 = *(const f4*)&mrp[4096];
        mrs2 = *(const f4*)&mrp[8192];
        mrs3 = *(const f4*)&mrp[12288];
    }
    // t=0 step inputs
    if (tid < 64) vt[tid] = v_all[b * S_ + tid];
    else if (tid < 68) w3s4[tid - 64] = w3_all[b * N_ + (tid - 64)];
    if (tid >= 128 && tid < 256)
        bmgin[tid - 128] = b_mg[tid - 128] + gIn_all[b * 2 * S_ + (tid - 128)];
    __syncthreads();

    float xo_reg = 0.f;

    for (int t = 0; t < T_; ++t) {
        const int f = t * B_ + b;

        // ===== P1: gates MFMA over 16 waves; Mi gate-update; Mif16 ========
        // prefetch next-step inputs (written to LDS in P7)
        float pf = 0.f;
        {
            const int fn = ((t + 1 < T_) ? t + 1 : t) * B_ + b;
            if (tid >= 512 && tid < 576) pf = v_all[fn * S_ + (tid - 512)];
            else if (tid >= 576 && tid < 580) pf = w3_all[fn * N_ + (tid - 576)];
            else if (tid >= 640 && tid < 768) pf = gIn_all[fn * 2 * S_ + (tid - 640)];
        }
        {
            const int rowbase = (wv & 3) << 4;
            const int tc = wv >> 2;
            h8 afr[2];
#pragma unroll
            for (int ks = 0; ks < 2; ++ks) {
                const int i = rowbase + li;
                const int sw = (i & 7) << 2;
                const int c0 = (ks << 5) + (g << 2);
                h4 lo = *(const h4*)&AsT[i * 64 + (c0 ^ sw)];
                h4 hi = *(const h4*)&AsT[i * 64 + ((c0 + 16) ^ sw)];
                afr[ks] = __builtin_shufflevector(lo, hi, 0, 1, 2, 3, 4, 5, 6, 7);
            }
            const int colI = (tc << 4) + li;
            const int colF = colI + 64;
            const float bi = bmgin[colI], bfv = bmgin[colF];
            f4 accI = {bi, bi, bi, bi};
            f4 accF = {bfv, bfv, bfv, bfv};
#pragma unroll
            for (int ks = 0; ks < 2; ++ks) {
                const int c0 = (ks << 5) + (g << 2);
                const int swc = (colI & 7) << 2;
                h4 blo = *(const h4*)&WmgT[colI * 64 + (c0 ^ swc)];
                h4 bhi = *(const h4*)&WmgT[colI * 64 + ((c0 + 16) ^ swc)];
                h8 bfr = __builtin_shufflevector(blo, bhi, 0, 1, 2, 3, 4, 5, 6, 7);
                accI = __builtin_amdgcn_mfma_f32_16x16x32_f16(afr[ks], bfr, accI, 0, 0, 0);
                blo = *(const h4*)&WmgT[colF * 64 + (c0 ^ swc)];
                bhi = *(const h4*)&WmgT[colF * 64 + ((c0 + 16) ^ swc)];
                bfr = __builtin_shufflevector(blo, bhi, 0, 1, 2, 3, 4, 5, 6, 7);
                accF = __builtin_amdgcn_mfma_f32_16x16x32_f16(afr[ks], bfr, accF, 0, 0, 0);
            }
            const float vc = vt[colI];
#pragma unroll
            for (int r = 0; r < 4; ++r) {
                const int row = rowbase + (g << 2) + r;
                const float gi = fsigm(accI[r] + ib);
                const float gf = fsigm(accF[r] + fb);
                const float mo = MI(row, colI);
                const float mn = gf * mo + gi * ftanh(vt[row] * vc);
                MI(row, colI) = mn;
                Mif16[swz(row, colI)] = (_Float16)mn;
            }
        }
        __syncthreads();   // (1)

        // ===== P2: qkv MFMA (waves 0-3) + LN partial sums =================
        if (wv < 4) {
            const int rowbase = wv << 4;
            h8 afr[2];
#pragma unroll
            for (int ks = 0; ks < 2; ++ks) {
                const int i = rowbase + li;
                const int sw = (i & 7) << 2;
                const int c0 = (ks << 5) + (g << 2);
                h4 lo = *(const h4*)&Mif16[i * 64 + (c0 ^ sw)];
                h4 hi = *(const h4*)&Mif16[i * 64 + ((c0 + 16) ^ sw)];
                afr[ks] = __builtin_shufflevector(lo, hi, 0, 1, 2, 3, 4, 5, 6, 7);
            }
            const float bq = b_qkv_s[li];
            f4 qacc = {bq, bq, bq, bq};
#pragma unroll
            for (int ks = 0; ks < 2; ++ks) {
                const int c0 = (ks << 5) + (g << 2);
                const int sw = (li & 7) << 2;
                h4 blo = *(const h4*)&WqkvT[li * 64 + (c0 ^ sw)];
                h4 bhi = *(const h4*)&WqkvT[li * 64 + ((c0 + 16) ^ sw)];
                h8 bfr = __builtin_shufflevector(blo, bhi, 0, 1, 2, 3, 4, 5, 6, 7);
                qacc = __builtin_amdgcn_mfma_f32_16x16x32_f16(afr[ks], bfr, qacc, 0, 0, 0);
            }
            float s1 = 0.f, s2 = 0.f;
            if (li < 12) {
#pragma unroll
                for (int r = 0; r < 4; ++r) {
                    const int row = rowbase + (g << 2) + r;
                    qkvp[row * 12 + li] = qacc[r];
                    s1 += qacc[r]; s2 += qacc[r] * qacc[r];
                }
            }
#pragma unroll
            for (int off = 32; off; off >>= 1) {
                s1 += __shfl_down(s1, off); s2 += __shfl_down(s2, off);
            }
            if (ln == 0) { red1[wv] = s1; red2[wv] = s2; }
        }
        __syncthreads();   // (2)

        // ===== P3: LN apply; write qkT (f32 transposed) + vvsT + vvA ======
        {
            const float sA = red1[0] + red1[1] + red1[2] + red1[3];
            const float sB = red2[0] + red2[1] + red2[2] + red2[3];
            const float mu = sA * (1.f / 768.f);
            const float var = sB * (1.f / 768.f) - mu * mu;
            const float rstd = rsqrtf(var + 1e-5f);
            if (tid < 768) {
                const int cs = tid / 12, cc = tid - cs * 12;
                const float qn = (qkvp[tid] - mu) * rstd * ln_g_s[tid] + ln_b_s[tid];
                if (cc < 8) qkT[cc * 68 + cs] = qn;
                else {
                    const int m = cc - 8;
                    vvsT[(cs << 2) + m] = qn;
                    vvA[swz(m, cs)] = (_Float16)qn;
                }
            }
        }
        __syncthreads();   // (3)

        // ===== P4: wvm = vv@Wrel MFMA (waves 0-3); A-scores (wave 4) ======
        if (wv < 4) {
            if (ln < 16) xo_reg = xo_all[f * O_ + (wv << 4) + ln];
            h8 afr[2];
#pragma unroll
            for (int ks = 0; ks < 2; ++ks) {
                const int sw = (li & 7) << 2;
                const int c0 = (ks << 5) + (g << 2);
                h4 lo = *(const h4*)&vvA[li * 64 + (c0 ^ sw)];
                h4 hi = *(const h4*)&vvA[li * 64 + ((c0 + 16) ^ sw)];
                afr[ks] = __builtin_shufflevector(lo, hi, 0, 1, 2, 3, 4, 5, 6, 7);
            }
            const int col = (wv << 4) + li;
            f4 acc = {0.f, 0.f, 0.f, 0.f};
#pragma unroll
            for (int ks = 0; ks < 2; ++ks) {
                const int c0 = (ks << 5) + (g << 2);
                const int sw = (col & 7) << 2;
                h4 blo = *(const h4*)&WrelT[col * 64 + (c0 ^ sw)];
                h4 bhi = *(const h4*)&WrelT[col * 64 + ((c0 + 16) ^ sw)];
                h8 bfr = __builtin_shufflevector(blo, bhi, 0, 1, 2, 3, 4, 5, 6, 7);
                acc = __builtin_amdgcn_mfma_f32_16x16x32_f16(afr[ks], bfr, acc, 0, 0, 0);
            }
            if (ln < 16) {
#pragma unroll
                for (int r = 0; r < 4; ++r) wvm[r][(wv << 4) + ln] = acc[r];
            }
        } else if (wv == 4) {
            const int nm = ln & 15, kc = ln >> 4;
            const int n = nm >> 2, m = nm & 3;
            const float* qp = &qkT[n * 68 + (kc << 4)];
            const float* kp = &qkT[(4 + m) * 68 + (kc << 4)];
            float a = 0.f;
#pragma unroll
            for (int j4 = 0; j4 < 4; ++j4) {
                f4 q = *(const f4*)&qp[j4 << 2];
                f4 k = *(const f4*)&kp[j4 << 2];
                a += q[0] * k[0] + q[1] * k[1] + q[2] * k[2] + q[3] * k[3];
            }
            a *= 0.125f;
            a += __shfl_xor(a, 16);
            a += __shfl_xor(a, 32);
            float mx = fmaxf(a, __shfl_xor(a, 1));
            mx = fmaxf(mx, __shfl_xor(mx, 2));
            float e = __expf(a - mx);
            float sm = e + __shfl_xor(e, 1);
            sm = sm + __shfl_xor(sm, 2);
            if (ln < 16) Amat[n][m] = __fdividef(e, sm);
        }
        __syncthreads();   // (4)

        // ===== P5: in-register Mrs update + transfer + tvec partials ======
        {
            const int s = tid >> 4, rq = tid & 15, r4 = rq << 2;
            f4 Am0 = *(const f4*)&Amat[0][0];
            f4 Am1 = *(const f4*)&Amat[1][0];
            f4 Am2 = *(const f4*)&Amat[2][0];
            f4 Am3 = *(const f4*)&Amat[3][0];
            f4 w3r = *(const f4*)&w3s4[0];
            f4 vv4 = *(const f4*)&vvsT[s << 2];
            f4 brel4 = *(const f4*)&b_rel_s[r4];
            f4 wvA4 = *(const f4*)&wvm[0][r4];
            f4 wvB4 = *(const f4*)&wvm[1][r4];
            f4 wvC4 = *(const f4*)&wvm[2][r4];
            f4 wvD4 = *(const f4*)&wvm[3][r4];
            float tr0 = 0.f, tr1 = 0.f, tr2 = 0.f, tr3 = 0.f;
            {   // n = 0
                float c0 = Am0[0] * vv4[0], c1 = Am0[1] * vv4[1];
                float c2 = Am0[2] * vv4[2], c3 = Am0[3] * vv4[3];
#pragma unroll
                for (int j = 0; j < 4; ++j) {
                    float dl = c0 * wvA4[j] + c1 * wvB4[j] + c2 * wvC4[j] + c3 * wvD4[j];
                    mrs0[j] += a1 * (dl + brel4[j]);
                }
                tr0 += w3r[0] * mrs0[0]; tr1 += w3r[0] * mrs0[1];
                tr2 += w3r[0] * mrs0[2]; tr3 += w3r[0] * mrs0[3];
            }
            {   // n = 1
                float c0 = Am1[0] * vv4[0], c1 = Am1[1] * vv4[1];
                float c2 = Am1[2] * vv4[2], c3 = Am1[3] * vv4[3];
#pragma unroll
                for (int j = 0; j < 4; ++j) {
                    float dl = c0 * wvA4[j] + c1 * wvB4[j] + c2 * wvC4[j] + c3 * wvD4[j];
                    mrs1[j] += a1 * (dl + brel4[j]);
                }
                tr0 += w3r[1] * mrs1[0]; tr1 += w3r[1] * mrs1[1];
                tr2 += w3r[1] * mrs1[2]; tr3 += w3r[1] * mrs1[3];
            }
            {   // n = 2
                float c0 = Am2[0] * vv4[0], c1 = Am2[1] * vv4[1];
                float c2 = Am2[2] * vv4[2], c3 = Am2[3] * vv4[3];
#pragma unroll
                for (int j = 0; j < 4; ++j) {
                    float dl = c0 * wvA4[j] + c1 * wvB4[j] + c2 * wvC4[j] + c3 * wvD4[j];
                    mrs2[j] += a1 * (dl + brel4[j]);
                }
                tr0 += w3r[2] * mrs2[0]; tr1 += w3r[2] * mrs2[1];
                tr2 += w3r[2] * mrs2[2]; tr3 += w3r[2] * mrs2[3];
            }
            {   // n = 3
                float c0 = Am3[0] * vv4[0], c1 = Am3[1] * vv4[1];
                float c2 = Am3[2] * vv4[2], c3 = Am3[3] * vv4[3];
#pragma unroll
                for (int j = 0; j < 4; ++j) {
                    float dl = c0 * wvA4[j] + c1 * wvB4[j] + c2 * wvC4[j] + c3 * wvD4[j];
                    mrs3[j] += a1 * (dl + brel4[j]);
                }
                tr0 += w3r[3] * mrs3[0]; tr1 += w3r[3] * mrs3[1];
                tr2 += w3r[3] * mrs3[2]; tr3 += w3r[3] * mrs3[3];
            }
            h4 trh;
            trh[0] = (_Float16)tr0; trh[1] = (_Float16)tr1;
            trh[2] = (_Float16)tr2; trh[3] = (_Float16)tr3;
            *(h4*)&AsX[s * 64 + (r4 ^ ((s & 7) << 2))] = trh;
            const float vts = vt[s];
            float tp0 = vts * tr0, tp1 = vts * tr1, tp2 = vts * tr2, tp3 = vts * tr3;
            tp0 += __shfl_xor(tp0, 16); tp0 += __shfl_xor(tp0, 32);
            tp1 += __shfl_xor(tp1, 16); tp1 += __shfl_xor(tp1, 32);
            tp2 += __shfl_xor(tp2, 16); tp2 += __shfl_xor(tp2, 32);
            tp3 += __shfl_xor(tp3, 16); tp3 += __shfl_xor(tp3, 32);
            if (ln < 16) {
                f4 w = {tp0, tp1, tp2, tp3};
                *(f4*)&wavepart[wv][rq << 2] = w;
            }
        }
        __syncthreads();   // (5)

        // ===== P6: Wvb MFMA (waves 0-7); Mi final + AsT=tanh(Mi); tvec ====
        if (wv < 8) {
            const int rowbase = (wv & 3) << 4;
            const int tc0 = (wv >> 2) << 1;
            h8 afr[2];
#pragma unroll
            for (int ks = 0; ks < 2; ++ks) {
                const int i = rowbase + li;
                const int sw = (i & 7) << 2;
                const int c0 = (ks << 5) + (g << 2);
                h4 lo = *(const h4*)&AsX[i * 64 + (c0 ^ sw)];
                h4 hi = *(const h4*)&AsX[i * 64 + ((c0 + 16) ^ sw)];
                afr[ks] = __builtin_shufflevector(lo, hi, 0, 1, 2, 3, 4, 5, 6, 7);
            }
#pragma unroll
            for (int tt = 0; tt < 2; ++tt) {
                const int col = ((tc0 + tt) << 4) + li;
                const float bv = b_vb_s[col];
                f4 acc = {bv, bv, bv, bv};
#pragma unroll
                for (int ks = 0; ks < 2; ++ks) {
                    const int c0 = (ks << 5) + (g << 2);
                    const int sw = (col & 7) << 2;
                    h4 blo = *(const h4*)&WvbT[col * 64 + (c0 ^ sw)];
                    h4 bhi = *(const h4*)&WvbT[col * 64 + ((c0 + 16) ^ sw)];
                    h8 bfr = __builtin_shufflevector(blo, bhi, 0, 1, 2, 3, 4, 5, 6, 7);
                    acc = __builtin_amdgcn_mfma_f32_16x16x32_f16(afr[ks], bfr, acc, 0, 0, 0);
                }
#pragma unroll
                for (int r = 0; r < 4; ++r) {
                    const int row = rowbase + (g << 2) + r;
                    const float mn = MI(row, col) + a2v * ftanh(acc[r]);
                    MI(row, col) = mn;
                    AsT[swz(row, col)] = (_Float16)ftanh(mn);
                }
            }
        } else if (wv == 8) {
            float tv = 0.f;
#pragma unroll
            for (int w = 0; w < 16; ++w) tv += wavepart[w][ln];
            tvecA[ln] = (_Float16)tv;   // swz(0, ln) == ln
        }
        __syncthreads();   // (6)

        // ===== P7: o = tvec@Wrel3 + b_rel3 + xo (MFMA); stage next inputs =
        if (wv < 4) {
            h8 afr[2];
#pragma unroll
            for (int ks = 0; ks < 2; ++ks) {
                const int sw = (li & 7) << 2;
                const int c0 = (ks << 5) + (g << 2);
                h4 lo = *(const h4*)&tvecA[li * 64 + (c0 ^ sw)];
                h4 hi = *(const h4*)&tvecA[li * 64 + ((c0 + 16) ^ sw)];
                afr[ks] = __builtin_shufflevector(lo, hi, 0, 1, 2, 3, 4, 5, 6, 7);
            }
            const int col = (wv << 4) + li;
            const float br3 = b_rel3_s[col];
            f4 acc = {br3, br3, br3, br3};
#pragma unroll
            for (int ks = 0; ks < 2; ++ks) {
                const int c0 = (ks << 5) + (g << 2);
                const int sw = (col & 7) << 2;
                h4 blo = *(const h4*)&Wrel3T[col * 64 + (c0 ^ sw)];
                h4 bhi = *(const h4*)&Wrel3T[col * 64 + ((c0 + 16) ^ sw)];
                h8 bfr = __builtin_shufflevector(blo, bhi, 0, 1, 2, 3, 4, 5, 6, 7);
                acc = __builtin_amdgcn_mfma_f32_16x16x32_f16(afr[ks], bfr, acc, 0, 0, 0);
            }
            if (ln < 16) o_all[f * O_ + col] = acc[0] + xo_reg;
        } else if (tid >= 512) {
            if (tid < 576) vt[tid - 512] = pf;
            else if (tid < 580) w3s4[tid - 576] = pf;
            else if (tid >= 640 && tid < 768) bmgin[tid - 640] = b_mg_s[tid - 640] + pf;
        }
        __syncthreads();   // (7)
    }
    #undef MI
}

// ---------------------------------------------------------------------------
// K3: post-pass MLP + final head — unchanged
// ---------------------------------------------------------------------------
__global__ __launch_bounds__(256)
void k3_post(const float* __restrict__ o_all,
             const float* __restrict__ Wm1, const float* __restrict__ b_m1,
             const float* __restrict__ Wm2, const float* __restrict__ b_m2,
             const float* __restrict__ Wout, const float* __restrict__ b_out,
             const float* __restrict__ fc_g, const float* __restrict__ fc_b,
             const float* __restrict__ Wfc, const float* __restrict__ b_fc,
             float* __restrict__ out)
{
    __shared__ float os[8][O_];
    __shared__ float h1[8][D_];
    __shared__ float h2[8][D_];
    __shared__ float mus[8], rst[8];
    const int tid = threadIdx.x;
    const int f0 = blockIdx.x * 8;

    for (int i = tid; i < 8 * O_; i += 256) os[i >> 6][i & 63] = o_all[f0 * O_ + i];
    __syncthreads();

    const int d0 = tid, d1 = tid + 256;
    {
        float a0[8], a1[8];
        float b0 = b_m1[d0], b1 = b_m1[d1];
#pragma unroll
        for (int r = 0; r < 8; ++r) { a0[r] = b0; a1[r] = b1; }
        for (int k = 0; k < O_; ++k) {
            float w0 = Wm1[k * D_ + d0], w1 = Wm1[k * D_ + d1];
#pragma unroll
            for (int r = 0; r < 8; ++r) {
                float e = os[r][k];
                a0[r] = fmaf(e, w0, a0[r]); a1[r] = fmaf(e, w1, a1[r]);
            }
        }
#pragma unroll
        for (int r = 0; r < 8; ++r) { h1[r][d0] = fmaxf(a0[r], 0.f); h1[r][d1] = fmaxf(a1[r], 0.f); }
    }
    __syncthreads();
    {
        float a0[8], a1[8];
        float b0 = b_m2[d0], b1 = b_m2[d1];
#pragma unroll
        for (int r = 0; r < 8; ++r) { a0[r] = b0; a1[r] = b1; }
        for (int k = 0; k < D_; ++k) {
            float w0 = Wm2[k * D_ + d0], w1 = Wm2[k * D_ + d1];
#pragma unroll
            for (int r = 0; r < 8; ++r) {
                float e = h1[r][k];
                a0[r] = fmaf(e, w0, a0[r]); a1[r] = fmaf(e, w1, a1[r]);
            }
        }
#pragma unroll
        for (int r = 0; r < 8; ++r) { h2[r][d0] = fmaxf(a0[r], 0.f); h2[r][d1] = fmaxf(a1[r], 0.f); }
    }
    __syncthreads();
    {
        float a0[8], a1[8];
        float b0 = b_out[d0], b1 = b_out[d1];
#pragma unroll
        for (int r = 0; r < 8; ++r) { a0[r] = b0; a1[r] = b1; }
        for (int k = 0; k < D_; ++k) {
            float w0 = Wout[k * D_ + d0], w1 = Wout[k * D_ + d1];
#pragma unroll
            for (int r = 0; r < 8; ++r) {
                float e = h2[r][k];
                a0[r] = fmaf(e, w0, a0[r]); a1[r] = fmaf(e, w1, a1[r]);
            }
        }
#pragma unroll
        for (int r = 0; r < 8; ++r) { h1[r][d0] = a0[r]; h1[r][d1] = a1[r]; }
    }
    __syncthreads();
    {
        const int r = tid >> 5, l = tid & 31;
        float s1 = 0.f, s2 = 0.f;
        for (int k = l; k < D_; k += 32) { float y = h1[r][k]; s1 += y; s2 += y * y; }
#pragma unroll
        for (int off = 16; off; off >>= 1) { s1 += __shfl_down(s1, off, 32); s2 += __shfl_down(s2, off, 32); }
        if (l == 0) {
            float mu = s1 / (float)D_;
            float var = s2 / (float)D_ - mu * mu;
            mus[r] = mu; rst[r] = rsqrtf(var + 1e-5f);
        }
    }
    __syncthreads();
    for (int i = tid; i < 8 * D_; i += 256) {
        int r = i >> 9, d = i & (D_ - 1);
        float y = (h1[r][d] - mus[r]) * rst[r] * fc_g[d] + fc_b[d];
        h1[r][d] = fmaxf(y, 0.f);
    }
    __syncthreads();
    {
        const int v = tid & 127, r0 = tid >> 7;
#pragma unroll
        for (int ri = 0; ri < 4; ++ri) {
            int r = r0 + 2 * ri;
            float a = b_fc[v];
            for (int k = 0; k < D_; ++k) a = fmaf(h1[r][k], Wfc[k * V_ + v], a);
            int f = f0 + r, t = f >> 5, b = f & 31;
            out[b * (V_ * T_) + v * T_ + t] = a;
        }
    }
}

// ---------------------------------------------------------------------------
extern "C" void kernel_launch(void* const* d_in, const int* in_sizes, int n_in,
                              void* d_out, int out_size, void* d_ws, size_t ws_size,
                              hipStream_t stream)
{
    (void)in_sizes; (void)n_in; (void)out_size; (void)ws_size;
    const int*   ids   = (const int*)  d_in[0];
    const float* emb   = (const float*)d_in[1];
    const float* We    = (const float*)d_in[2];
    const float* be    = (const float*)d_in[3];
    const float* Win   = (const float*)d_in[4];
    const float* b_in  = (const float*)d_in[5];
    const float* Win2  = (const float*)d_in[6];
    const float* b_in2 = (const float*)d_in[7];
    const float* Win3  = (const float*)d_in[8];
    const float* b_in3 = (const float*)d_in[9];
    const float* Wig   = (const float*)d_in[10];
    const float* b_ig  = (const float*)d_in[11];
    const float* Wmg   = (const float*)d_in[12];
    const float* b_mg  = (const float*)d_in[13];
    const float* ibp   = (const float*)d_in[14];
    const float* fbp   = (const float*)d_in[15];
    const float* Wqkv  = (const float*)d_in[16];
    const float* b_qkv = (const float*)d_in[17];
    const float* ln_g  = (const float*)d_in[18];
    const float* ln_b  = (const float*)d_in[19];
    const float* a1p   = (const float*)d_in[20];
    const float* a2p   = (const float*)d_in[21];
    const float* Wrel  = (const float*)d_in[22];
    const float* b_rel = (const float*)d_in[23];
    const float* Wvb   = (const float*)d_in[24];
    const float* b_vb  = (const float*)d_in[25];
    const float* Wrel3 = (const float*)d_in[26];
    const float* b_rel3= (const float*)d_in[27];
    const float* Wm1   = (const float*)d_in[28];
    const float* b_m1  = (const float*)d_in[29];
    const float* Wm2   = (const float*)d_in[30];
    const float* b_m2  = (const float*)d_in[31];
    const float* Wout  = (const float*)d_in[32];
    const float* b_out = (const float*)d_in[33];
    const float* Mi0   = (const float*)d_in[34];
    const float* Mr0   = (const float*)d_in[35];
    const float* fc_g  = (const float*)d_in[36];
    const float* fc_b  = (const float*)d_in[37];
    const float* Wfc   = (const float*)d_in[38];
    const float* b_fc  = (const float*)d_in[39];

    float* ws = (float*)d_ws;
    float* v_all   = ws;
    float* gIn_all = v_all   + T_ * B_ * S_;
    float* w3_all  = gIn_all + T_ * B_ * 2 * S_;
    float* xo_all  = w3_all  + T_ * B_ * N_;
    float* o_all   = xo_all  + T_ * B_ * O_;

    k1_pre<<<dim3((T_ * B_) / 8), dim3(256), 0, stream>>>(
        ids, emb, We, be, Win, b_in, Win2, b_in2, Win3, b_in3, Wig, b_ig,
        v_all, gIn_all, w3_all, xo_all);

    k2_scan<<<dim3(B_), dim3(1024), 0, stream>>>(
        v_all, gIn_all, w3_all, xo_all,
        Wmg, b_mg, Wqkv, b_qkv, ln_g, ln_b,
        Wrel, b_rel, Wvb, b_vb, Wrel3, b_rel3,
        Mi0, Mr0, ibp, fbp, a1p, a2p, o_all);

    k3_post<<<dim3((T_ * B_) / 8), dim3(256), 0, stream>>>(
        o_all, Wm1, b_m1, Wm2, b_m2, Wout, b_out, fc_g, fc_b, Wfc, b_fc,
        (float*)d_out);
}

// Round 5
// 1264.376 us; speedup vs baseline: 3.6314x; 1.0873x over previous
//
#include <hip/hip_runtime.h>
#include <hip/hip_fp16.h>
#include <math.h>

#define T_ 128
#define B_ 32
#define D_ 512
#define V_ 128
#define S_ 64
#define N_ 4
#define R_ 64
#define O_ 64

typedef _Float16 h4 __attribute__((ext_vector_type(4)));
typedef _Float16 h8 __attribute__((ext_vector_type(8)));
typedef float f4 __attribute__((ext_vector_type(4)));

__device__ __forceinline__ float fsigm(float x) {
    return __fdividef(1.0f, 1.0f + __expf(-x));
}
__device__ __forceinline__ float ftanh(float x) {
    x = fminf(15.f, fmaxf(-15.f, x));
    float e = __expf(2.f * x);
    return 1.f - __fdividef(2.f, e + 1.f);
}

// swizzled f16 element offset for a [rows][64] operand tile
__device__ __forceinline__ int swz(int row, int k) {
    return row * 64 + (((k & ~3) ^ ((row & 7) << 2)) | (k & 3));
}

// ---------------------------------------------------------------------------
// K1: precompute (all t,b in parallel) — unchanged
// ---------------------------------------------------------------------------
__global__ __launch_bounds__(256)
void k1_pre(const int* __restrict__ ids, const float* __restrict__ emb,
            const float* __restrict__ We, const float* __restrict__ be,
            const float* __restrict__ Win, const float* __restrict__ b_in,
            const float* __restrict__ Win2, const float* __restrict__ b_in2,
            const float* __restrict__ Win3, const float* __restrict__ b_in3,
            const float* __restrict__ Wig, const float* __restrict__ b_ig,
            float* __restrict__ v_all, float* __restrict__ gIn_all,
            float* __restrict__ w3_all, float* __restrict__ xo_all)
{
    __shared__ float E[8][D_];
    __shared__ float X[8][D_];
    __shared__ float vs[8][S_];
    __shared__ float sc[8][N_];
    const int tid = threadIdx.x;
    const int f0 = blockIdx.x * 8;

    for (int i = tid; i < 8 * D_; i += 256) {
        int r = i >> 9, d = i & (D_ - 1);
        int f = f0 + r;
        int t = f >> 5, b = f & 31;
        E[r][d] = emb[ids[b * T_ + t] * D_ + d];
    }
    __syncthreads();

    { // src = E @ We + be
        const int d0 = tid, d1 = tid + 256;
        float a0[8], a1[8];
        float b0 = be[d0], b1 = be[d1];
#pragma unroll
        for (int r = 0; r < 8; ++r) { a0[r] = b0; a1[r] = b1; }
        for (int k = 0; k < D_; ++k) {
            float w0 = We[k * D_ + d0], w1 = We[k * D_ + d1];
#pragma unroll
            for (int r = 0; r < 8; ++r) {
                float e = E[r][k];
                a0[r] = fmaf(e, w0, a0[r]);
                a1[r] = fmaf(e, w1, a1[r]);
            }
        }
#pragma unroll
        for (int r = 0; r < 8; ++r) { X[r][d0] = a0[r]; X[r][d1] = a1[r]; }
    }
    __syncthreads();

    { // v and xo
        const int j = tid & 63, r0 = tid >> 6;
#pragma unroll
        for (int ri = 0; ri < 2; ++ri) {
            int r = r0 + 4 * ri;
            float a = b_in[j], a2 = b_in2[j];
            for (int k = 0; k < D_; ++k) {
                float x = X[r][k];
                a  = fmaf(x, Win [k * S_ + j], a);
                a2 = fmaf(x, Win2[k * O_ + j], a2);
            }
            vs[r][j] = a;
            v_all [(f0 + r) * S_ + j] = a;
            xo_all[(f0 + r) * O_ + j] = a2;
        }
    }
    if (tid < 32) {
        int r = tid >> 2, n = tid & 3;
        float a = b_in3[n];
        for (int k = 0; k < D_; ++k) a = fmaf(X[r][k], Win3[k * N_ + n], a);
        sc[r][n] = a;
    }
    __syncthreads();
    if (tid < 8) {
        float x0 = sc[tid][0], x1 = sc[tid][1], x2 = sc[tid][2], x3 = sc[tid][3];
        float m = fmaxf(fmaxf(x0, x1), fmaxf(x2, x3));
        float e0 = expf(x0 - m), e1 = expf(x1 - m), e2 = expf(x2 - m), e3 = expf(x3 - m);
        float inv = 1.0f / (e0 + e1 + e2 + e3);
        float* w = &w3_all[(f0 + tid) * N_];
        w[0] = e0 * inv; w[1] = e1 * inv; w[2] = e2 * inv; w[3] = e3 * inv;
    }
    {
        const int c = tid & 127, r0 = tid >> 7;
#pragma unroll
        for (int ri = 0; ri < 4; ++ri) {
            int r = r0 + 2 * ri;
            float a = b_ig[c];
            for (int k = 0; k < S_; ++k) a = fmaf(vs[r][k], Wig[k * 2 * S_ + c], a);
            gIn_all[(f0 + r) * 2 * S_ + c] = a;
        }
    }
}

// ---------------------------------------------------------------------------
// K2: sequential scan, 5-barrier edition.
//   P1: gates MFMA (16w) + o-MFMA(t-1) on w0-3 + global prefetch (w8-11)
//   P2: qkv MFMA + LN partials + P-operand write (LN folded)
//   P3: wvm MFMA (LN-folded corrections) + A-scores (w4) + vvsT (w8-11)
//   P5: in-register Mrs update + transfer + tvec partials
//   P6: Wvb MFMA + Mi final + AsT; stage next inputs (w8-11); tvec (w15)
// ---------------------------------------------------------------------------
__global__ __launch_bounds__(1024)
void k2_scan(const float* __restrict__ v_all, const float* __restrict__ gIn_all,
             const float* __restrict__ w3_all, const float* __restrict__ xo_all,
             const float* __restrict__ Wmg, const float* __restrict__ b_mg,
             const float* __restrict__ Wqkv, const float* __restrict__ b_qkv,
             const float* __restrict__ ln_g, const float* __restrict__ ln_b,
             const float* __restrict__ Wrel, const float* __restrict__ b_rel,
             const float* __restrict__ Wvb, const float* __restrict__ b_vb,
             const float* __restrict__ Wrel3, const float* __restrict__ b_rel3,
             const float* __restrict__ Mi0, const float* __restrict__ Mr0,
             const float* __restrict__ p_ib, const float* __restrict__ p_fb,
             const float* __restrict__ p_a1, const float* __restrict__ p_a2,
             float* __restrict__ o_all)
{
    const int tid = threadIdx.x;
    const int b = blockIdx.x;
    const int wv = tid >> 6;        // wave id 0..15
    const int ln = tid & 63;        // lane
    const int g  = ln >> 4;         // 4-lane-group
    const int li = ln & 15;

    __shared__ __align__(16) float Mi_s[S_ * 68];           // 17408
    __shared__ __align__(16) _Float16 AsT[S_ * S_];         // tanh(Mi): gates A-op
    __shared__ __align__(16) _Float16 AsX[S_ * S_];         // transfer: Wvb A-op
    __shared__ __align__(16) _Float16 Mif16[S_ * S_];       // Mi after gates: qkv A-op
    __shared__ __align__(16) _Float16 P_op[16 * S_];        // qkv_v*ln_g operand (rows 4-15 zero)
    __shared__ __align__(16) _Float16 tvecA[16 * S_];       // rows 1-15 zero
    __shared__ __align__(16) _Float16 WmgT[2 * S_ * S_];
    __shared__ __align__(16) _Float16 WvbT[S_ * S_];
    __shared__ __align__(16) _Float16 WrelT[S_ * S_];
    __shared__ __align__(16) _Float16 Wrel3T[S_ * S_];
    __shared__ __align__(16) _Float16 WqkvT[16 * S_];
    __shared__ float ln_g_s[768], ln_b_s[768];
    __shared__ __align__(16) float qkvp[768];
    __shared__ __align__(16) float vvsT[S_ * 4];            // [s][m] post-LN vv
    __shared__ __align__(16) float wvm[N_][S_];             // a1-scaled
    __shared__ __align__(16) float G2s[N_][S_];             // ln_g_v @ Wrel
    __shared__ __align__(16) float B2s[N_][S_];             // a1 * (ln_b_v @ Wrel)
    __shared__ __align__(16) float wavepart[16][S_];
    __shared__ float bmgin[128];
    __shared__ float b_mg_s[128];
    __shared__ __align__(16) float b_vb_s[64], b_rel3_s[64];
    __shared__ float b_qkv_s[16];
    __shared__ float vt[S_];
    __shared__ __align__(16) float w3s4[4];
    __shared__ __align__(16) float Amat[N_][N_];
    __shared__ float red1[4], red2[4];

    const float ib = p_ib[0], fb = p_fb[0], a1 = p_a1[0], a2v = p_a2[0];

    #define MI(r, c) Mi_s[(r) * 68 + (c)]

    // ---- init: stage weights/biases, Mi, AsT=tanh(Mi0), G2/B2, Mrs->regs ----
    for (int i = tid; i < 2 * S_ * S_; i += 1024) {
        int k = i >> 7, j = i & 127;
        WmgT[swz(j, k)] = (_Float16)Wmg[i];
    }
    for (int i = tid; i < S_ * S_; i += 1024) {
        int r = i >> 6, j = i & 63;
        WvbT[swz(j, r)] = (_Float16)Wvb[i];
    }
    for (int i = tid; i < S_ * S_; i += 1024) {
        int s = i >> 6, r = i & 63;
        WrelT[swz(r, s)] = (_Float16)Wrel[i];
    }
    for (int i = tid; i < S_ * S_; i += 1024) {
        int r = i >> 6, o = i & 63;
        Wrel3T[swz(o, r)] = (_Float16)Wrel3[i];
    }
    if (tid < 16 * S_) {
        int c = tid >> 6, k = tid & 63;
        float w = (c < 12) ? Wqkv[k * 12 + c] : 0.f;
        WqkvT[swz(c, k)] = (_Float16)w;
    }
    if (tid < 768) { ln_g_s[tid] = ln_g[tid]; ln_b_s[tid] = ln_b[tid]; }
    if (tid < 128) b_mg_s[tid] = b_mg[tid];
    else if (tid < 192) b_vb_s[tid - 128] = b_vb[tid - 128];
    else if (tid < 256) b_rel3_s[tid - 192] = b_rel3[tid - 192];
    else if (tid < 272) b_qkv_s[tid - 256] = (tid - 256 < 12) ? b_qkv[tid - 256] : 0.f;
    if (tid < 1024) { P_op[tid] = (_Float16)0.f; tvecA[tid] = (_Float16)0.f; }
    // G2/B2 correction tables (global reads, one-time)
    if (tid < 256) {
        const int m = tid >> 6, r = tid & 63;
        float g2 = 0.f, b2 = 0.f;
        for (int s = 0; s < S_; ++s) {
            float w = Wrel[s * R_ + r];
            g2 = fmaf(ln_g[s * 12 + 8 + m], w, g2);
            b2 = fmaf(ln_b[s * 12 + 8 + m], w, b2);
        }
        G2s[m][r] = g2;
        B2s[m][r] = a1 * b2;
    }
    for (int i = tid; i < S_ * S_; i += 1024) MI(i >> 6, i & 63) = Mi0[i];
    {   // AsT = tanh(Mi0), swizzled h4
        const int row = tid >> 4, k0 = (tid & 15) << 2;
        const float* mp = Mi0 + (tid << 2);
        h4 t4;
        t4[0] = (_Float16)ftanh(mp[0]); t4[1] = (_Float16)ftanh(mp[1]);
        t4[2] = (_Float16)ftanh(mp[2]); t4[3] = (_Float16)ftanh(mp[3]);
        *(h4*)&AsT[row * 64 + (k0 ^ ((row & 7) << 2))] = t4;
    }
    // Mrs -> registers: thread owns (s = tid>>4, r4 = (tid&15)*4), n = 0..3
    f4 mrs0, mrs1, mrs2, mrs3, a1brel4;
    {
        const int s0i = tid >> 4, r4i = (tid & 15) << 2;
        const float* mrp = Mr0 + s0i * 64 + r4i;
        mrs0 = *(const f4*)&mrp[0];
        mrs1 = *(const f4*)&mrp[4096];
        mrs2 = *(const f4*)&mrp[8192];
        mrs3 = *(const f4*)&mrp[12288];
        f4 br = *(const f4*)&b_rel[r4i];
        a1brel4 = a1 * br;
    }
    // t=0 step inputs
    if (tid < 64) vt[tid] = v_all[b * S_ + tid];
    else if (tid < 68) w3s4[tid - 64] = w3_all[b * N_ + (tid - 64)];
    if (tid >= 128 && tid < 256)
        bmgin[tid - 128] = b_mg[tid - 128] + gIn_all[b * 2 * S_ + (tid - 128)];
    __syncthreads();

    float xo_reg = 0.f;

    for (int t = 0; t < T_; ++t) {
        const int f = t * B_ + b;

        // ===== P1: gates MFMA (16 waves) + o-MFMA(t-1) on w0-3 ============
        float pf = 0.f;
        {
            const int fn = ((t + 1 < T_) ? t + 1 : t) * B_ + b;
            if (tid >= 512 && tid < 576) pf = v_all[fn * S_ + (tid - 512)];
            else if (tid >= 576 && tid < 580) pf = w3_all[fn * N_ + (tid - 576)];
            else if (tid >= 640 && tid < 768) pf = gIn_all[fn * 2 * S_ + (tid - 640)];
        }
        if (wv < 4 && t > 0) {      // o-MFMA for step t-1
            h8 afr[2];
#pragma unroll
            for (int ks = 0; ks < 2; ++ks) {
                const int sw = (li & 7) << 2;
                const int c0 = (ks << 5) + (g << 2);
                h4 lo = *(const h4*)&tvecA[li * 64 + (c0 ^ sw)];
                h4 hi = *(const h4*)&tvecA[li * 64 + ((c0 + 16) ^ sw)];
                afr[ks] = __builtin_shufflevector(lo, hi, 0, 1, 2, 3, 4, 5, 6, 7);
            }
            const int col = (wv << 4) + li;
            const float br3 = b_rel3_s[col];
            f4 acc = {br3, br3, br3, br3};
#pragma unroll
            for (int ks = 0; ks < 2; ++ks) {
                const int c0 = (ks << 5) + (g << 2);
                const int sw = (col & 7) << 2;
                h4 blo = *(const h4*)&Wrel3T[col * 64 + (c0 ^ sw)];
                h4 bhi = *(const h4*)&Wrel3T[col * 64 + ((c0 + 16) ^ sw)];
                h8 bfr = __builtin_shufflevector(blo, bhi, 0, 1, 2, 3, 4, 5, 6, 7);
                acc = __builtin_amdgcn_mfma_f32_16x16x32_f16(afr[ks], bfr, acc, 0, 0, 0);
            }
            if (ln < 16) o_all[(f - B_) * O_ + col] = acc[0] + xo_reg;
        }
        {   // gates: all 16 waves, tile (rowblock = wv&3, colblock = wv>>2)
            const int rowbase = (wv & 3) << 4;
            const int tc = wv >> 2;
            h8 afr[2];
#pragma unroll
            for (int ks = 0; ks < 2; ++ks) {
                const int i = rowbase + li;
                const int sw = (i & 7) << 2;
                const int c0 = (ks << 5) + (g << 2);
                h4 lo = *(const h4*)&AsT[i * 64 + (c0 ^ sw)];
                h4 hi = *(const h4*)&AsT[i * 64 + ((c0 + 16) ^ sw)];
                afr[ks] = __builtin_shufflevector(lo, hi, 0, 1, 2, 3, 4, 5, 6, 7);
            }
            const int colI = (tc << 4) + li;
            const int colF = colI + 64;
            const float bi = bmgin[colI], bfv = bmgin[colF];
            f4 accI = {bi, bi, bi, bi};
            f4 accF = {bfv, bfv, bfv, bfv};
#pragma unroll
            for (int ks = 0; ks < 2; ++ks) {
                const int c0 = (ks << 5) + (g << 2);
                const int swc = (colI & 7) << 2;
                h4 blo = *(const h4*)&WmgT[colI * 64 + (c0 ^ swc)];
                h4 bhi = *(const h4*)&WmgT[colI * 64 + ((c0 + 16) ^ swc)];
                h8 bfr = __builtin_shufflevector(blo, bhi, 0, 1, 2, 3, 4, 5, 6, 7);
                accI = __builtin_amdgcn_mfma_f32_16x16x32_f16(afr[ks], bfr, accI, 0, 0, 0);
                blo = *(const h4*)&WmgT[colF * 64 + (c0 ^ swc)];
                bhi = *(const h4*)&WmgT[colF * 64 + ((c0 + 16) ^ swc)];
                bfr = __builtin_shufflevector(blo, bhi, 0, 1, 2, 3, 4, 5, 6, 7);
                accF = __builtin_amdgcn_mfma_f32_16x16x32_f16(afr[ks], bfr, accF, 0, 0, 0);
            }
            const float vc = vt[colI];
#pragma unroll
            for (int r = 0; r < 4; ++r) {
                const int row = rowbase + (g << 2) + r;
                const float gi = fsigm(accI[r] + ib);
                const float gf = fsigm(accF[r] + fb);
                const float mo = MI(row, colI);
                const float mn = gf * mo + gi * ftanh(vt[row] * vc);
                MI(row, colI) = mn;
                Mif16[swz(row, colI)] = (_Float16)mn;
            }
        }
        __syncthreads();   // (1)

        // ===== P2: qkv MFMA (w0-3) + LN partials + P-operand ==============
        if (wv < 4) {
            const int rowbase = wv << 4;
            h8 afr[2];
#pragma unroll
            for (int ks = 0; ks < 2; ++ks) {
                const int i = rowbase + li;
                const int sw = (i & 7) << 2;
                const int c0 = (ks << 5) + (g << 2);
                h4 lo = *(const h4*)&Mif16[i * 64 + (c0 ^ sw)];
                h4 hi = *(const h4*)&Mif16[i * 64 + ((c0 + 16) ^ sw)];
                afr[ks] = __builtin_shufflevector(lo, hi, 0, 1, 2, 3, 4, 5, 6, 7);
            }
            const float bq = b_qkv_s[li];
            f4 qacc = {bq, bq, bq, bq};
#pragma unroll
            for (int ks = 0; ks < 2; ++ks) {
                const int c0 = (ks << 5) + (g << 2);
                const int sw = (li & 7) << 2;
                h4 blo = *(const h4*)&WqkvT[li * 64 + (c0 ^ sw)];
                h4 bhi = *(const h4*)&WqkvT[li * 64 + ((c0 + 16) ^ sw)];
                h8 bfr = __builtin_shufflevector(blo, bhi, 0, 1, 2, 3, 4, 5, 6, 7);
                qacc = __builtin_amdgcn_mfma_f32_16x16x32_f16(afr[ks], bfr, qacc, 0, 0, 0);
            }
            float s1 = 0.f, s2 = 0.f;
            if (li < 12) {
                const int srow = rowbase + (g << 2);
#pragma unroll
                for (int r = 0; r < 4; ++r) {
                    qkvp[(srow + r) * 12 + li] = qacc[r];
                    s1 += qacc[r]; s2 += qacc[r] * qacc[r];
                }
                if (li >= 8) {   // P-operand: P[m][s] = qkv_v * ln_g_v (pre-LN-stats)
                    const int m = li - 8;
                    h4 p4;
#pragma unroll
                    for (int r = 0; r < 4; ++r)
                        p4[r] = (_Float16)(qacc[r] * ln_g_s[(srow + r) * 12 + 8 + m]);
                    *(h4*)&P_op[m * 64 + (srow ^ ((m & 7) << 2))] = p4;
                }
            }
#pragma unroll
            for (int off = 32; off; off >>= 1) {
                s1 += __shfl_down(s1, off); s2 += __shfl_down(s2, off);
            }
            if (ln == 0) { red1[wv] = s1; red2[wv] = s2; }
        }
        __syncthreads();   // (2)

        // ===== P3: wvm MFMA + corrections (w0-3); A-scores (w4); vvsT =====
        {
            const float sA = red1[0] + red1[1] + red1[2] + red1[3];
            const float sB = red2[0] + red2[1] + red2[2] + red2[3];
            const float mu = sA * (1.f / 768.f);
            const float var = sB * (1.f / 768.f) - mu * mu;
            const float rstd = rsqrtf(var + 1e-5f);
            if (wv < 4) {
                if (ln < 16) xo_reg = xo_all[f * O_ + (wv << 4) + ln];
                h8 afr[2];
#pragma unroll
                for (int ks = 0; ks < 2; ++ks) {
                    const int sw = (li & 7) << 2;
                    const int c0 = (ks << 5) + (g << 2);
                    h4 lo = *(const h4*)&P_op[li * 64 + (c0 ^ sw)];
                    h4 hi = *(const h4*)&P_op[li * 64 + ((c0 + 16) ^ sw)];
                    afr[ks] = __builtin_shufflevector(lo, hi, 0, 1, 2, 3, 4, 5, 6, 7);
                }
                const int col = (wv << 4) + li;
                f4 acc = {0.f, 0.f, 0.f, 0.f};
#pragma unroll
                for (int ks = 0; ks < 2; ++ks) {
                    const int c0 = (ks << 5) + (g << 2);
                    const int sw = (col & 7) << 2;
                    h4 blo = *(const h4*)&WrelT[col * 64 + (c0 ^ sw)];
                    h4 bhi = *(const h4*)&WrelT[col * 64 + ((c0 + 16) ^ sw)];
                    h8 bfr = __builtin_shufflevector(blo, bhi, 0, 1, 2, 3, 4, 5, 6, 7);
                    acc = __builtin_amdgcn_mfma_f32_16x16x32_f16(afr[ks], bfr, acc, 0, 0, 0);
                }
                if (ln < 16) {
                    const float sa = a1 * rstd;
                    const float sb = -a1 * rstd * mu;
#pragma unroll
                    for (int r = 0; r < 4; ++r)
                        wvm[r][col] = sa * acc[r] + sb * G2s[r][col] + B2s[r][col];
                }
            } else if (wv == 4) {
                // A-scores with inline LN from qkvp
                const int nm = ln & 15, kc = ln >> 4;
                const int n = nm >> 2, m = nm & 3;
                float a = 0.f;
#pragma unroll 4
                for (int si = 0; si < 16; ++si) {
                    const int s = (kc << 4) + si;
                    const int cq = s * 12 + n, ck = s * 12 + 4 + m;
                    const float qv = (qkvp[cq] - mu) * rstd * ln_g_s[cq] + ln_b_s[cq];
                    const float kv = (qkvp[ck] - mu) * rstd * ln_g_s[ck] + ln_b_s[ck];
                    a = fmaf(qv, kv, a);
                }
                a *= 0.125f;
                a += __shfl_xor(a, 16);
                a += __shfl_xor(a, 32);
                float mx = fmaxf(a, __shfl_xor(a, 1));
                mx = fmaxf(mx, __shfl_xor(mx, 2));
                float e = __expf(a - mx);
                float sm = e + __shfl_xor(e, 1);
                sm = sm + __shfl_xor(sm, 2);
                if (ln < 16) Amat[n][m] = __fdividef(e, sm);
            } else if (tid >= 512 && tid < 768) {
                const int i = tid - 512;          // s = i>>2, m = i&3
                const int c = (i >> 2) * 12 + 8 + (i & 3);
                vvsT[i] = (qkvp[c] - mu) * rstd * ln_g_s[c] + ln_b_s[c];
            }
        }
        __syncthreads();   // (3)

        // ===== P5: in-register Mrs update + transfer + tvec partials ======
        {
            const int s = tid >> 4, rq = tid & 15, r4 = rq << 2;
            f4 Am0 = *(const f4*)&Amat[0][0];
            f4 Am1 = *(const f4*)&Amat[1][0];
            f4 Am2 = *(const f4*)&Amat[2][0];
            f4 Am3 = *(const f4*)&Amat[3][0];
            f4 w3r = *(const f4*)&w3s4[0];
            f4 vv4 = *(const f4*)&vvsT[s << 2];
            f4 wvA4 = *(const f4*)&wvm[0][r4];   // a1-scaled
            f4 wvB4 = *(const f4*)&wvm[1][r4];
            f4 wvC4 = *(const f4*)&wvm[2][r4];
            f4 wvD4 = *(const f4*)&wvm[3][r4];
            float tr0 = 0.f, tr1 = 0.f, tr2 = 0.f, tr3 = 0.f;
            {   // n = 0
                float c0 = Am0[0] * vv4[0], c1 = Am0[1] * vv4[1];
                float c2 = Am0[2] * vv4[2], c3 = Am0[3] * vv4[3];
#pragma unroll
                for (int j = 0; j < 4; ++j)
                    mrs0[j] += a1brel4[j] + c0 * wvA4[j] + c1 * wvB4[j] + c2 * wvC4[j] + c3 * wvD4[j];
                tr0 += w3r[0] * mrs0[0]; tr1 += w3r[0] * mrs0[1];
                tr2 += w3r[0] * mrs0[2]; tr3 += w3r[0] * mrs0[3];
            }
            {   // n = 1
                float c0 = Am1[0] * vv4[0], c1 = Am1[1] * vv4[1];
                float c2 = Am1[2] * vv4[2], c3 = Am1[3] * vv4[3];
#pragma unroll
                for (int j = 0; j < 4; ++j)
                    mrs1[j] += a1brel4[j] + c0 * wvA4[j] + c1 * wvB4[j] + c2 * wvC4[j] + c3 * wvD4[j];
                tr0 += w3r[1] * mrs1[0]; tr1 += w3r[1] * mrs1[1];
                tr2 += w3r[1] * mrs1[2]; tr3 += w3r[1] * mrs1[3];
            }
            {   // n = 2
                float c0 = Am2[0] * vv4[0], c1 = Am2[1] * vv4[1];
                float c2 = Am2[2] * vv4[2], c3 = Am2[3] * vv4[3];
#pragma unroll
                for (int j = 0; j < 4; ++j)
                    mrs2[j] += a1brel4[j] + c0 * wvA4[j] + c1 * wvB4[j] + c2 * wvC4[j] + c3 * wvD4[j];
                tr0 += w3r[2] * mrs2[0]; tr1 += w3r[2] * mrs2[1];
                tr2 += w3r[2] * mrs2[2]; tr3 += w3r[2] * mrs2[3];
            }
            {   // n = 3
                float c0 = Am3[0] * vv4[0], c1 = Am3[1] * vv4[1];
                float c2 = Am3[2] * vv4[2], c3 = Am3[3] * vv4[3];
#pragma unroll
                for (int j = 0; j < 4; ++j)
                    mrs3[j] += a1brel4[j] + c0 * wvA4[j] + c1 * wvB4[j] + c2 * wvC4[j] + c3 * wvD4[j];
                tr0 += w3r[3] * mrs3[0]; tr1 += w3r[3] * mrs3[1];
                tr2 += w3r[3] * mrs3[2]; tr3 += w3r[3] * mrs3[3];
            }
            h4 trh;
            trh[0] = (_Float16)tr0; trh[1] = (_Float16)tr1;
            trh[2] = (_Float16)tr2; trh[3] = (_Float16)tr3;
            *(h4*)&AsX[s * 64 + (r4 ^ ((s & 7) << 2))] = trh;
            const float vts = vt[s];
            float tp0 = vts * tr0, tp1 = vts * tr1, tp2 = vts * tr2, tp3 = vts * tr3;
            tp0 += __shfl_xor(tp0, 16); tp0 += __shfl_xor(tp0, 32);
            tp1 += __shfl_xor(tp1, 16); tp1 += __shfl_xor(tp1, 32);
            tp2 += __shfl_xor(tp2, 16); tp2 += __shfl_xor(tp2, 32);
            tp3 += __shfl_xor(tp3, 16); tp3 += __shfl_xor(tp3, 32);
            if (ln < 16) {
                f4 w = {tp0, tp1, tp2, tp3};
                *(f4*)&wavepart[wv][rq << 2] = w;
            }
        }
        __syncthreads();   // (4)

        // ===== P6: Wvb MFMA (w0-7) + Mi final + AsT; stage inputs; tvec ===
        if (wv < 8) {
            const int rowbase = (wv & 3) << 4;
            const int tc0 = (wv >> 2) << 1;
            h8 afr[2];
#pragma unroll
            for (int ks = 0; ks < 2; ++ks) {
                const int i = rowbase + li;
                const int sw = (i & 7) << 2;
                const int c0 = (ks << 5) + (g << 2);
                h4 lo = *(const h4*)&AsX[i * 64 + (c0 ^ sw)];
                h4 hi = *(const h4*)&AsX[i * 64 + ((c0 + 16) ^ sw)];
                afr[ks] = __builtin_shufflevector(lo, hi, 0, 1, 2, 3, 4, 5, 6, 7);
            }
#pragma unroll
            for (int tt = 0; tt < 2; ++tt) {
                const int col = ((tc0 + tt) << 4) + li;
                const float bv = b_vb_s[col];
                f4 acc = {bv, bv, bv, bv};
#pragma unroll
                for (int ks = 0; ks < 2; ++ks) {
                    const int c0 = (ks << 5) + (g << 2);
                    const int sw = (col & 7) << 2;
                    h4 blo = *(const h4*)&WvbT[col * 64 + (c0 ^ sw)];
                    h4 bhi = *(const h4*)&WvbT[col * 64 + ((c0 + 16) ^ sw)];
                    h8 bfr = __builtin_shufflevector(blo, bhi, 0, 1, 2, 3, 4, 5, 6, 7);
                    acc = __builtin_amdgcn_mfma_f32_16x16x32_f16(afr[ks], bfr, acc, 0, 0, 0);
                }
#pragma unroll
                for (int r = 0; r < 4; ++r) {
                    const int row = rowbase + (g << 2) + r;
                    const float mn = MI(row, col) + a2v * ftanh(acc[r]);
                    MI(row, col) = mn;
                    AsT[swz(row, col)] = (_Float16)ftanh(mn);
                }
            }
        } else if (wv == 15) {
            float tv = 0.f;
#pragma unroll
            for (int w = 0; w < 16; ++w) tv += wavepart[w][ln];
            tvecA[ln] = (_Float16)tv;   // swz(0, ln) == ln
        } else {
            if (tid >= 512 && tid < 576) vt[tid - 512] = pf;
            else if (tid >= 576 && tid < 580) w3s4[tid - 576] = pf;
            else if (tid >= 640 && tid < 768) bmgin[tid - 640] = b_mg_s[tid - 640] + pf;
        }
        __syncthreads();   // (5)
    }

    // ---- flush: o-MFMA for t = T-1 ----
    if (wv < 4) {
        h8 afr[2];
#pragma unroll
        for (int ks = 0; ks < 2; ++ks) {
            const int sw = (li & 7) << 2;
            const int c0 = (ks << 5) + (g << 2);
            h4 lo = *(const h4*)&tvecA[li * 64 + (c0 ^ sw)];
            h4 hi = *(const h4*)&tvecA[li * 64 + ((c0 + 16) ^ sw)];
            afr[ks] = __builtin_shufflevector(lo, hi, 0, 1, 2, 3, 4, 5, 6, 7);
        }
        const int col = (wv << 4) + li;
        const float br3 = b_rel3_s[col];
        f4 acc = {br3, br3, br3, br3};
#pragma unroll
        for (int ks = 0; ks < 2; ++ks) {
            const int c0 = (ks << 5) + (g << 2);
            const int sw = (col & 7) << 2;
            h4 blo = *(const h4*)&Wrel3T[col * 64 + (c0 ^ sw)];
            h4 bhi = *(const h4*)&Wrel3T[col * 64 + ((c0 + 16) ^ sw)];
            h8 bfr = __builtin_shufflevector(blo, bhi, 0, 1, 2, 3, 4, 5, 6, 7);
            acc = __builtin_amdgcn_mfma_f32_16x16x32_f16(afr[ks], bfr, acc, 0, 0, 0);
        }
        if (ln < 16) o_all[(T_ - 1) * B_ * O_ + b * O_ + col] = acc[0] + xo_reg;
    }
    #undef MI
}

// ---------------------------------------------------------------------------
// K3: post-pass MLP + final head — unchanged
// ---------------------------------------------------------------------------
__global__ __launch_bounds__(256)
void k3_post(const float* __restrict__ o_all,
             const float* __restrict__ Wm1, const float* __restrict__ b_m1,
             const float* __restrict__ Wm2, const float* __restrict__ b_m2,
             const float* __restrict__ Wout, const float* __restrict__ b_out,
             const float* __restrict__ fc_g, const float* __restrict__ fc_b,
             const float* __restrict__ Wfc, const float* __restrict__ b_fc,
             float* __restrict__ out)
{
    __shared__ float os[8][O_];
    __shared__ float h1[8][D_];
    __shared__ float h2[8][D_];
    __shared__ float mus[8], rst[8];
    const int tid = threadIdx.x;
    const int f0 = blockIdx.x * 8;

    for (int i = tid; i < 8 * O_; i += 256) os[i >> 6][i & 63] = o_all[f0 * O_ + i];
    __syncthreads();

    const int d0 = tid, d1 = tid + 256;
    {
        float a0[8], a1[8];
        float b0 = b_m1[d0], b1 = b_m1[d1];
#pragma unroll
        for (int r = 0; r < 8; ++r) { a0[r] = b0; a1[r] = b1; }
        for (int k = 0; k < O_; ++k) {
            float w0 = Wm1[k * D_ + d0], w1 = Wm1[k * D_ + d1];
#pragma unroll
            for (int r = 0; r < 8; ++r) {
                float e = os[r][k];
                a0[r] = fmaf(e, w0, a0[r]); a1[r] = fmaf(e, w1, a1[r]);
            }
        }
#pragma unroll
        for (int r = 0; r < 8; ++r) { h1[r][d0] = fmaxf(a0[r], 0.f); h1[r][d1] = fmaxf(a1[r], 0.f); }
    }
    __syncthreads();
    {
        float a0[8], a1[8];
        float b0 = b_m2[d0], b1 = b_m2[d1];
#pragma unroll
        for (int r = 0; r < 8; ++r) { a0[r] = b0; a1[r] = b1; }
        for (int k = 0; k < D_; ++k) {
            float w0 = Wm2[k * D_ + d0], w1 = Wm2[k * D_ + d1];
#pragma unroll
            for (int r = 0; r < 8; ++r) {
                float e = h1[r][k];
                a0[r] = fmaf(e, w0, a0[r]); a1[r] = fmaf(e, w1, a1[r]);
            }
        }
#pragma unroll
        for (int r = 0; r < 8; ++r) { h2[r][d0] = fmaxf(a0[r], 0.f); h2[r][d1] = fmaxf(a1[r], 0.f); }
    }
    __syncthreads();
    {
        float a0[8], a1[8];
        float b0 = b_out[d0], b1 = b_out[d1];
#pragma unroll
        for (int r = 0; r < 8; ++r) { a0[r] = b0; a1[r] = b1; }
        for (int k = 0; k < D_; ++k) {
            float w0 = Wout[k * D_ + d0], w1 = Wout[k * D_ + d1];
#pragma unroll
            for (int r = 0; r < 8; ++r) {
                float e = h2[r][k];
                a0[r] = fmaf(e, w0, a0[r]); a1[r] = fmaf(e, w1, a1[r]);
            }
        }
#pragma unroll
        for (int r = 0; r < 8; ++r) { h1[r][d0] = a0[r]; h1[r][d1] = a1[r]; }
    }
    __syncthreads();
    {
        const int r = tid >> 5, l = tid & 31;
        float s1 = 0.f, s2 = 0.f;
        for (int k = l; k < D_; k += 32) { float y = h1[r][k]; s1 += y; s2 += y * y; }
#pragma unroll
        for (int off = 16; off; off >>= 1) { s1 += __shfl_down(s1, off, 32); s2 += __shfl_down(s2, off, 32); }
        if (l == 0) {
            float mu = s1 / (float)D_;
            float var = s2 / (float)D_ - mu * mu;
            mus[r] = mu; rst[r] = rsqrtf(var + 1e-5f);
        }
    }
    __syncthreads();
    for (int i = tid; i < 8 * D_; i += 256) {
        int r = i >> 9, d = i & (D_ - 1);
        float y = (h1[r][d] - mus[r]) * rst[r] * fc_g[d] + fc_b[d];
        h1[r][d] = fmaxf(y, 0.f);
    }
    __syncthreads();
    {
        const int v = tid & 127, r0 = tid >> 7;
#pragma unroll
        for (int ri = 0; ri < 4; ++ri) {
            int r = r0 + 2 * ri;
            float a = b_fc[v];
            for (int k = 0; k < D_; ++k) a = fmaf(h1[r][k], Wfc[k * V_ + v], a);
            int f = f0 + r, t = f >> 5, b = f & 31;
            out[b * (V_ * T_) + v * T_ + t] = a;
        }
    }
}

// ---------------------------------------------------------------------------
extern "C" void kernel_launch(void* const* d_in, const int* in_sizes, int n_in,
                              void* d_out, int out_size, void* d_ws, size_t ws_size,
                              hipStream_t stream)
{
    (void)in_sizes; (void)n_in; (void)out_size; (void)ws_size;
    const int*   ids   = (const int*)  d_in[0];
    const float* emb   = (const float*)d_in[1];
    const float* We    = (const float*)d_in[2];
    const float* be    = (const float*)d_in[3];
    const float* Win   = (const float*)d_in[4];
    const float* b_in  = (const float*)d_in[5];
    const float* Win2  = (const float*)d_in[6];
    const float* b_in2 = (const float*)d_in[7];
    const float* Win3  = (const float*)d_in[8];
    const float* b_in3 = (const float*)d_in[9];
    const float* Wig   = (const float*)d_in[10];
    const float* b_ig  = (const float*)d_in[11];
    const float* Wmg   = (const float*)d_in[12];
    const float* b_mg  = (const float*)d_in[13];
    const float* ibp   = (const float*)d_in[14];
    const float* fbp   = (const float*)d_in[15];
    const float* Wqkv  = (const float*)d_in[16];
    const float* b_qkv = (const float*)d_in[17];
    const float* ln_g  = (const float*)d_in[18];
    const float* ln_b  = (const float*)d_in[19];
    const float* a1p   = (const float*)d_in[20];
    const float* a2p   = (const float*)d_in[21];
    const float* Wrel  = (const float*)d_in[22];
    const float* b_rel = (const float*)d_in[23];
    const float* Wvb   = (const float*)d_in[24];
    const float* b_vb  = (const float*)d_in[25];
    const float* Wrel3 = (const float*)d_in[26];
    const float* b_rel3= (const float*)d_in[27];
    const float* Wm1   = (const float*)d_in[28];
    const float* b_m1  = (const float*)d_in[29];
    const float* Wm2   = (const float*)d_in[30];
    const float* b_m2  = (const float*)d_in[31];
    const float* Wout  = (const float*)d_in[32];
    const float* b_out = (const float*)d_in[33];
    const float* Mi0   = (const float*)d_in[34];
    const float* Mr0   = (const float*)d_in[35];
    const float* fc_g  = (const float*)d_in[36];
    const float* fc_b  = (const float*)d_in[37];
    const float* Wfc   = (const float*)d_in[38];
    const float* b_fc  = (const float*)d_in[39];

    float* ws = (float*)d_ws;
    float* v_all   = ws;
    float* gIn_all = v_all   + T_ * B_ * S_;
    float* w3_all  = gIn_all + T_ * B_ * 2 * S_;
    float* xo_all  = w3_all  + T_ * B_ * N_;
    float* o_all   = xo_all  + T_ * B_ * O_;

    k1_pre<<<dim3((T_ * B_) / 8), dim3(256), 0, stream>>>(
        ids, emb, We, be, Win, b_in, Win2, b_in2, Win3, b_in3, Wig, b_ig,
        v_all, gIn_all, w3_all, xo_all);

    k2_scan<<<dim3(B_), dim3(1024), 0, stream>>>(
        v_all, gIn_all, w3_all, xo_all,
        Wmg, b_mg, Wqkv, b_qkv, ln_g, ln_b,
        Wrel, b_rel, Wvb, b_vb, Wrel3, b_rel3,
        Mi0, Mr0, ibp, fbp, a1p, a2p, o_all);

    k3_post<<<dim3((T_ * B_) / 8), dim3(256), 0, stream>>>(
        o_all, Wm1, b_m1, Wm2, b_m2, Wout, b_out, fc_g, fc_b, Wfc, b_fc,
        (float*)d_out);
}

// Round 6
// 1009.891 us; speedup vs baseline: 4.5465x; 1.2520x over previous
//
#include <hip/hip_runtime.h>
#include <hip/hip_fp16.h>
#include <math.h>

#define T_ 128
#define B_ 32
#define D_ 512
#define V_ 128
#define S_ 64
#define N_ 4
#define R_ 64
#define O_ 64

typedef _Float16 h4 __attribute__((ext_vector_type(4)));
typedef _Float16 h8 __attribute__((ext_vector_type(8)));
typedef float f4 __attribute__((ext_vector_type(4)));

__device__ __forceinline__ float fsigm(float x) {
    return __fdividef(1.0f, 1.0f + __expf(-x));
}
__device__ __forceinline__ float ftanh(float x) {
    // no clamp needed: exp(+inf)->inf -> 1; exp(-inf)->0 -> -1
    float e = __expf(2.f * x);
    return 1.f - __fdividef(2.f, e + 1.f);
}

// ---- h8-contiguous fragment layout for [rows][64] f16 operand tiles ----
// A lane (g, li) of a 16x16x32 MFMA reads, for k-slice ks, logical cols
// {ks*32+g*4+e} u {ks*32+16+g*4+e}, e=0..3. Store them contiguously:
// element (row,k): ks=k>>5, u=(k>>4)&1, gg=(k>>2)&3, e=k&3
//   sidx = row*64 + ((((ks<<2)|gg) ^ (row&7)) << 3) + (u<<2) + e
// Fragment (row,ks,g) is then one 16B-aligned h8 at:
__device__ __forceinline__ int fidx(int row, int ks, int g) {
    return row * 64 + ((((ks << 2) | g) ^ (row & 7)) << 3);
}
__device__ __forceinline__ int sidx(int row, int k) {
    int ks = k >> 5, u = (k >> 4) & 1, gg = (k >> 2) & 3, e = k & 3;
    return row * 64 + ((((ks << 2) | gg) ^ (row & 7)) << 3) + (u << 2) + e;
}

// ---------------------------------------------------------------------------
// K1: precompute (all t,b in parallel) — unchanged
// ---------------------------------------------------------------------------
__global__ __launch_bounds__(256)
void k1_pre(const int* __restrict__ ids, const float* __restrict__ emb,
            const float* __restrict__ We, const float* __restrict__ be,
            const float* __restrict__ Win, const float* __restrict__ b_in,
            const float* __restrict__ Win2, const float* __restrict__ b_in2,
            const float* __restrict__ Win3, const float* __restrict__ b_in3,
            const float* __restrict__ Wig, const float* __restrict__ b_ig,
            float* __restrict__ v_all, float* __restrict__ gIn_all,
            float* __restrict__ w3_all, float* __restrict__ xo_all)
{
    __shared__ float E[8][D_];
    __shared__ float X[8][D_];
    __shared__ float vs[8][S_];
    __shared__ float sc[8][N_];
    const int tid = threadIdx.x;
    const int f0 = blockIdx.x * 8;

    for (int i = tid; i < 8 * D_; i += 256) {
        int r = i >> 9, d = i & (D_ - 1);
        int f = f0 + r;
        int t = f >> 5, b = f & 31;
        E[r][d] = emb[ids[b * T_ + t] * D_ + d];
    }
    __syncthreads();

    { // src = E @ We + be
        const int d0 = tid, d1 = tid + 256;
        float a0[8], a1[8];
        float b0 = be[d0], b1 = be[d1];
#pragma unroll
        for (int r = 0; r < 8; ++r) { a0[r] = b0; a1[r] = b1; }
        for (int k = 0; k < D_; ++k) {
            float w0 = We[k * D_ + d0], w1 = We[k * D_ + d1];
#pragma unroll
            for (int r = 0; r < 8; ++r) {
                float e = E[r][k];
                a0[r] = fmaf(e, w0, a0[r]);
                a1[r] = fmaf(e, w1, a1[r]);
            }
        }
#pragma unroll
        for (int r = 0; r < 8; ++r) { X[r][d0] = a0[r]; X[r][d1] = a1[r]; }
    }
    __syncthreads();

    { // v and xo
        const int j = tid & 63, r0 = tid >> 6;
#pragma unroll
        for (int ri = 0; ri < 2; ++ri) {
            int r = r0 + 4 * ri;
            float a = b_in[j], a2 = b_in2[j];
            for (int k = 0; k < D_; ++k) {
                float x = X[r][k];
                a  = fmaf(x, Win [k * S_ + j], a);
                a2 = fmaf(x, Win2[k * O_ + j], a2);
            }
            vs[r][j] = a;
            v_all [(f0 + r) * S_ + j] = a;
            xo_all[(f0 + r) * O_ + j] = a2;
        }
    }
    if (tid < 32) {
        int r = tid >> 2, n = tid & 3;
        float a = b_in3[n];
        for (int k = 0; k < D_; ++k) a = fmaf(X[r][k], Win3[k * N_ + n], a);
        sc[r][n] = a;
    }
    __syncthreads();
    if (tid < 8) {
        float x0 = sc[tid][0], x1 = sc[tid][1], x2 = sc[tid][2], x3 = sc[tid][3];
        float m = fmaxf(fmaxf(x0, x1), fmaxf(x2, x3));
        float e0 = expf(x0 - m), e1 = expf(x1 - m), e2 = expf(x2 - m), e3 = expf(x3 - m);
        float inv = 1.0f / (e0 + e1 + e2 + e3);
        float* w = &w3_all[(f0 + tid) * N_];
        w[0] = e0 * inv; w[1] = e1 * inv; w[2] = e2 * inv; w[3] = e3 * inv;
    }
    {
        const int c = tid & 127, r0 = tid >> 7;
#pragma unroll
        for (int ri = 0; ri < 4; ++ri) {
            int r = r0 + 2 * ri;
            float a = b_ig[c];
            for (int k = 0; k < S_; ++k) a = fmaf(vs[r][k], Wig[k * 2 * S_ + c], a);
            gIn_all[(f0 + r) * 2 * S_ + c] = a;
        }
    }
}

// ---------------------------------------------------------------------------
// K2: sequential scan, h8-fragment edition. tvec -> global; o done in K3.
//   P1: gates MFMA (16w) + prefetch
//   P2: qkv MFMA (w0-3) + LN 16-partials + P_op
//   P3: wvm MFMA (w0-3) + A-scores (w4) + vvsT
//   P4: in-register Mrs update + transfer + tvec partials
//   P5: Wvb MFMA (w0-7) + Mi/AsT; tvec sum->global (w15); stage inputs
// ---------------------------------------------------------------------------
__global__ __launch_bounds__(1024, 4)
void k2_scan(const float* __restrict__ v_all, const float* __restrict__ gIn_all,
             const float* __restrict__ w3_all,
             const float* __restrict__ Wmg, const float* __restrict__ b_mg,
             const float* __restrict__ Wqkv, const float* __restrict__ b_qkv,
             const float* __restrict__ ln_g, const float* __restrict__ ln_b,
             const float* __restrict__ Wrel, const float* __restrict__ b_rel,
             const float* __restrict__ Wvb, const float* __restrict__ b_vb,
             const float* __restrict__ Mi0, const float* __restrict__ Mr0,
             const float* __restrict__ p_ib, const float* __restrict__ p_fb,
             const float* __restrict__ p_a1, const float* __restrict__ p_a2,
             float* __restrict__ tvec_all)
{
    const int tid = threadIdx.x;
    const int b = blockIdx.x;
    const int wv = tid >> 6;        // wave id 0..15
    const int ln = tid & 63;        // lane
    const int g  = ln >> 4;         // 4-lane-group
    const int li = ln & 15;

    __shared__ __align__(16) float Mi_s[S_ * 68];           // 17408
    __shared__ __align__(16) _Float16 AsT[S_ * S_];         // tanh(Mi): gates A-op
    __shared__ __align__(16) _Float16 AsX[S_ * S_];         // transfer: Wvb A-op
    __shared__ __align__(16) _Float16 Mif16[S_ * S_];       // Mi after gates: qkv A-op
    __shared__ __align__(16) _Float16 P_op[16 * S_];        // qkv_v*ln_g (rows 4-15 zero)
    __shared__ __align__(16) _Float16 WmgT[2 * S_ * S_];
    __shared__ __align__(16) _Float16 WvbT[S_ * S_];
    __shared__ __align__(16) _Float16 WrelT[S_ * S_];
    __shared__ __align__(16) _Float16 WqkvT[16 * S_];
    __shared__ float ln_g_s[768], ln_b_s[768];
    __shared__ __align__(16) float qkvp[768];
    __shared__ __align__(16) float vvsT[S_ * 4];            // [s][m] post-LN vv
    __shared__ __align__(16) float wvm[N_][S_];             // a1-scaled
    __shared__ __align__(16) float G2s[N_][S_];
    __shared__ __align__(16) float B2s[N_][S_];
    __shared__ __align__(16) float wavepart[16][S_];
    __shared__ float bmgin[128];
    __shared__ float b_mg_s[128];
    __shared__ __align__(16) float b_vb_s[64];
    __shared__ float b_qkv_s[16];
    __shared__ float vt[S_];
    __shared__ __align__(16) float w3s4[4];
    __shared__ __align__(16) float Amat[N_][N_];
    __shared__ __align__(16) float red1[16], red2[16];

    const float ib = p_ib[0], fb = p_fb[0], a1 = p_a1[0], a2v = p_a2[0];

    #define MI(r, c) Mi_s[(r) * 68 + (c)]

    // ---- init ----
    for (int i = tid; i < 2 * S_ * S_; i += 1024) {        // Wmg (64,128)
        int k = i >> 7, j = i & 127;
        WmgT[sidx(j, k)] = (_Float16)Wmg[i];
    }
    for (int i = tid; i < S_ * S_; i += 1024) {            // Wvb (64,64)
        int r = i >> 6, j = i & 63;
        WvbT[sidx(j, r)] = (_Float16)Wvb[i];
    }
    for (int i = tid; i < S_ * S_; i += 1024) {            // Wrel (64s,64r)
        int s = i >> 6, r = i & 63;
        WrelT[sidx(r, s)] = (_Float16)Wrel[i];
    }
    if (tid < 16 * S_) {                                    // Wqkv (64,12)
        int c = tid >> 6, k = tid & 63;
        float w = (c < 12) ? Wqkv[k * 12 + c] : 0.f;
        WqkvT[sidx(c, k)] = (_Float16)w;
    }
    if (tid < 768) { ln_g_s[tid] = ln_g[tid]; ln_b_s[tid] = ln_b[tid]; }
    if (tid < 128) b_mg_s[tid] = b_mg[tid];
    else if (tid < 192) b_vb_s[tid - 128] = b_vb[tid - 128];
    else if (tid < 208) b_qkv_s[tid - 192] = (tid - 192 < 12) ? b_qkv[tid - 192] : 0.f;
    if (tid < 1024) P_op[tid] = (_Float16)0.f;
    if (tid < 256) {   // G2/B2 correction tables
        const int m = tid >> 6, r = tid & 63;
        float g2 = 0.f, b2 = 0.f;
        for (int s = 0; s < S_; ++s) {
            float w = Wrel[s * R_ + r];
            g2 = fmaf(ln_g[s * 12 + 8 + m], w, g2);
            b2 = fmaf(ln_b[s * 12 + 8 + m], w, b2);
        }
        G2s[m][r] = g2;
        B2s[m][r] = a1 * b2;
    }
    for (int i = tid; i < S_ * S_; i += 1024) MI(i >> 6, i & 63) = Mi0[i];
    {   // AsT = tanh(Mi0)
        const int row = tid >> 4, k0 = (tid & 15) << 2;
        const float* mp = Mi0 + (tid << 2);
        h4 t4;
        t4[0] = (_Float16)ftanh(mp[0]); t4[1] = (_Float16)ftanh(mp[1]);
        t4[2] = (_Float16)ftanh(mp[2]); t4[3] = (_Float16)ftanh(mp[3]);
        *(h4*)&AsT[sidx(row, k0)] = t4;
    }
    // Mrs -> registers: thread owns (s = tid>>4, r4 = (tid&15)*4), n = 0..3
    f4 mrs0, mrs1, mrs2, mrs3, a1brel4;
    {
        const int s0i = tid >> 4, r4i = (tid & 15) << 2;
        const float* mrp = Mr0 + s0i * 64 + r4i;
        mrs0 = *(const f4*)&mrp[0];
        mrs1 = *(const f4*)&mrp[4096];
        mrs2 = *(const f4*)&mrp[8192];
        mrs3 = *(const f4*)&mrp[12288];
        f4 br = *(const f4*)&b_rel[r4i];
        a1brel4 = a1 * br;
    }
    // t=0 step inputs
    if (tid < 64) vt[tid] = v_all[b * S_ + tid];
    else if (tid < 68) w3s4[tid - 64] = w3_all[b * N_ + (tid - 64)];
    if (tid >= 128 && tid < 256)
        bmgin[tid - 128] = b_mg[tid - 128] + gIn_all[b * 2 * S_ + (tid - 128)];
    __syncthreads();

    for (int t = 0; t < T_; ++t) {
        const int f = t * B_ + b;

        // ===== P1: gates MFMA (16 waves); prefetch t+1 inputs =============
        float pf = 0.f;
        {
            const int fn = ((t + 1 < T_) ? t + 1 : t) * B_ + b;
            if (tid >= 512 && tid < 576) pf = v_all[fn * S_ + (tid - 512)];
            else if (tid >= 576 && tid < 580) pf = w3_all[fn * N_ + (tid - 576)];
            else if (tid >= 640 && tid < 768) pf = gIn_all[fn * 2 * S_ + (tid - 640)];
        }
        {
            const int rowbase = (wv & 3) << 4;
            const int arow = rowbase + li;
            const int colI = ((wv >> 2) << 4) + li;
            const int colF = colI + 64;
            h8 af0 = *(const h8*)&AsT[fidx(arow, 0, g)];
            h8 af1 = *(const h8*)&AsT[fidx(arow, 1, g)];
            const float bi = bmgin[colI], bfv = bmgin[colF];
            f4 accI = {bi, bi, bi, bi};
            f4 accF = {bfv, bfv, bfv, bfv};
            accI = __builtin_amdgcn_mfma_f32_16x16x32_f16(af0, *(const h8*)&WmgT[fidx(colI, 0, g)], accI, 0, 0, 0);
            accI = __builtin_amdgcn_mfma_f32_16x16x32_f16(af1, *(const h8*)&WmgT[fidx(colI, 1, g)], accI, 0, 0, 0);
            accF = __builtin_amdgcn_mfma_f32_16x16x32_f16(af0, *(const h8*)&WmgT[fidx(colF, 0, g)], accF, 0, 0, 0);
            accF = __builtin_amdgcn_mfma_f32_16x16x32_f16(af1, *(const h8*)&WmgT[fidx(colF, 1, g)], accF, 0, 0, 0);
            const float vc = vt[colI];
#pragma unroll
            for (int r = 0; r < 4; ++r) {
                const int row = rowbase + (g << 2) + r;
                const float gi = fsigm(accI[r] + ib);
                const float gf = fsigm(accF[r] + fb);
                const float mo = MI(row, colI);
                const float mn = gf * mo + gi * ftanh(vt[row] * vc);
                MI(row, colI) = mn;
                Mif16[sidx(row, colI)] = (_Float16)mn;
            }
        }
        __syncthreads();   // (1)

        // ===== P2: qkv MFMA (w0-3) + LN 16-partials + P_op ================
        if (wv < 4) {
            const int rowbase = wv << 4;
            const int arow = rowbase + li;
            h8 af0 = *(const h8*)&Mif16[fidx(arow, 0, g)];
            h8 af1 = *(const h8*)&Mif16[fidx(arow, 1, g)];
            const float bq = b_qkv_s[li];
            f4 qacc = {bq, bq, bq, bq};
            qacc = __builtin_amdgcn_mfma_f32_16x16x32_f16(af0, *(const h8*)&WqkvT[fidx(li, 0, g)], qacc, 0, 0, 0);
            qacc = __builtin_amdgcn_mfma_f32_16x16x32_f16(af1, *(const h8*)&WqkvT[fidx(li, 1, g)], qacc, 0, 0, 0);
            float s1 = 0.f, s2 = 0.f;
            if (li < 12) {
                const int srow = rowbase + (g << 2);
#pragma unroll
                for (int r = 0; r < 4; ++r) {
                    qkvp[(srow + r) * 12 + li] = qacc[r];
                    s1 += qacc[r]; s2 += qacc[r] * qacc[r];
                }
                if (li >= 8) {   // P-operand: rows m, cols s
                    const int m = li - 8;
                    h4 p4;
#pragma unroll
                    for (int r = 0; r < 4; ++r)
                        p4[r] = (_Float16)(qacc[r] * ln_g_s[(srow + r) * 12 + 8 + m]);
                    *(h4*)&P_op[sidx(m, srow)] = p4;
                }
            }
#pragma unroll
            for (int off = 8; off; off >>= 1) {   // reduce within 16-lane group
                s1 += __shfl_down(s1, off); s2 += __shfl_down(s2, off);
            }
            if (li == 0) { red1[(wv << 2) + g] = s1; red2[(wv << 2) + g] = s2; }
        }
        __syncthreads();   // (2)

        // ===== P3: wvm MFMA + corrections (w0-3); A-scores (w4); vvsT =====
        {
            float sA = 0.f, sB = 0.f;
#pragma unroll
            for (int i = 0; i < 16; ++i) { sA += red1[i]; sB += red2[i]; }
            const float mu = sA * (1.f / 768.f);
            const float var = sB * (1.f / 768.f) - mu * mu;
            const float rstd = rsqrtf(var + 1e-5f);
            if (wv < 4) {
                h8 af0 = *(const h8*)&P_op[fidx(li, 0, g)];
                h8 af1 = *(const h8*)&P_op[fidx(li, 1, g)];
                const int col = (wv << 4) + li;
                f4 acc = {0.f, 0.f, 0.f, 0.f};
                acc = __builtin_amdgcn_mfma_f32_16x16x32_f16(af0, *(const h8*)&WrelT[fidx(col, 0, g)], acc, 0, 0, 0);
                acc = __builtin_amdgcn_mfma_f32_16x16x32_f16(af1, *(const h8*)&WrelT[fidx(col, 1, g)], acc, 0, 0, 0);
                if (ln < 16) {
                    const float sa = a1 * rstd;
                    const float sb = -a1 * rstd * mu;
#pragma unroll
                    for (int r = 0; r < 4; ++r)
                        wvm[r][col] = sa * acc[r] + sb * G2s[r][col] + B2s[r][col];
                }
            } else if (wv == 4) {
                const int nm = ln & 15, kc = ln >> 4;
                const int n = nm >> 2, m = nm & 3;
                float a = 0.f;
#pragma unroll 4
                for (int si = 0; si < 16; ++si) {
                    const int s = (kc << 4) + si;
                    const int cq = s * 12 + n, ck = s * 12 + 4 + m;
                    const float qv = (qkvp[cq] - mu) * rstd * ln_g_s[cq] + ln_b_s[cq];
                    const float kv = (qkvp[ck] - mu) * rstd * ln_g_s[ck] + ln_b_s[ck];
                    a = fmaf(qv, kv, a);
                }
                a *= 0.125f;
                a += __shfl_xor(a, 16);
                a += __shfl_xor(a, 32);
                float mx = fmaxf(a, __shfl_xor(a, 1));
                mx = fmaxf(mx, __shfl_xor(mx, 2));
                float e = __expf(a - mx);
                float sm = e + __shfl_xor(e, 1);
                sm = sm + __shfl_xor(sm, 2);
                if (ln < 16) Amat[n][m] = __fdividef(e, sm);
            } else if (tid >= 512 && tid < 768) {
                const int i = tid - 512;          // s = i>>2, m = i&3
                const int c = (i >> 2) * 12 + 8 + (i & 3);
                vvsT[i] = (qkvp[c] - mu) * rstd * ln_g_s[c] + ln_b_s[c];
            }
        }
        __syncthreads();   // (3)

        // ===== P4: in-register Mrs update + transfer + tvec partials ======
        {
            const int s = tid >> 4, rq = tid & 15, r4 = rq << 2;
            f4 Am0 = *(const f4*)&Amat[0][0];
            f4 Am1 = *(const f4*)&Amat[1][0];
            f4 Am2 = *(const f4*)&Amat[2][0];
            f4 Am3 = *(const f4*)&Amat[3][0];
            f4 w3r = *(const f4*)&w3s4[0];
            f4 vv4 = *(const f4*)&vvsT[s << 2];
            f4 wvA4 = *(const f4*)&wvm[0][r4];   // a1-scaled
            f4 wvB4 = *(const f4*)&wvm[1][r4];
            f4 wvC4 = *(const f4*)&wvm[2][r4];
            f4 wvD4 = *(const f4*)&wvm[3][r4];
            float tr0 = 0.f, tr1 = 0.f, tr2 = 0.f, tr3 = 0.f;
            {   // n = 0
                float c0 = Am0[0] * vv4[0], c1 = Am0[1] * vv4[1];
                float c2 = Am0[2] * vv4[2], c3 = Am0[3] * vv4[3];
#pragma unroll
                for (int j = 0; j < 4; ++j)
                    mrs0[j] += a1brel4[j] + c0 * wvA4[j] + c1 * wvB4[j] + c2 * wvC4[j] + c3 * wvD4[j];
                tr0 += w3r[0] * mrs0[0]; tr1 += w3r[0] * mrs0[1];
                tr2 += w3r[0] * mrs0[2]; tr3 += w3r[0] * mrs0[3];
            }
            {   // n = 1
                float c0 = Am1[0] * vv4[0], c1 = Am1[1] * vv4[1];
                float c2 = Am1[2] * vv4[2], c3 = Am1[3] * vv4[3];
#pragma unroll
                for (int j = 0; j < 4; ++j)
                    mrs1[j] += a1brel4[j] + c0 * wvA4[j] + c1 * wvB4[j] + c2 * wvC4[j] + c3 * wvD4[j];
                tr0 += w3r[1] * mrs1[0]; tr1 += w3r[1] * mrs1[1];
                tr2 += w3r[1] * mrs1[2]; tr3 += w3r[1] * mrs1[3];
            }
            {   // n = 2
                float c0 = Am2[0] * vv4[0], c1 = Am2[1] * vv4[1];
                float c2 = Am2[2] * vv4[2], c3 = Am2[3] * vv4[3];
#pragma unroll
                for (int j = 0; j < 4; ++j)
                    mrs2[j] += a1brel4[j] + c0 * wvA4[j] + c1 * wvB4[j] + c2 * wvC4[j] + c3 * wvD4[j];
                tr0 += w3r[2] * mrs2[0]; tr1 += w3r[2] * mrs2[1];
                tr2 += w3r[2] * mrs2[2]; tr3 += w3r[2] * mrs2[3];
            }
            {   // n = 3
                float c0 = Am3[0] * vv4[0], c1 = Am3[1] * vv4[1];
                float c2 = Am3[2] * vv4[2], c3 = Am3[3] * vv4[3];
#pragma unroll
                for (int j = 0; j < 4; ++j)
                    mrs3[j] += a1brel4[j] + c0 * wvA4[j] + c1 * wvB4[j] + c2 * wvC4[j] + c3 * wvD4[j];
                tr0 += w3r[3] * mrs3[0]; tr1 += w3r[3] * mrs3[1];
                tr2 += w3r[3] * mrs3[2]; tr3 += w3r[3] * mrs3[3];
            }
            h4 trh;
            trh[0] = (_Float16)tr0; trh[1] = (_Float16)tr1;
            trh[2] = (_Float16)tr2; trh[3] = (_Float16)tr3;
            *(h4*)&AsX[sidx(s, r4)] = trh;
            const float vts = vt[s];
            float tp0 = vts * tr0, tp1 = vts * tr1, tp2 = vts * tr2, tp3 = vts * tr3;
            tp0 += __shfl_xor(tp0, 16); tp0 += __shfl_xor(tp0, 32);
            tp1 += __shfl_xor(tp1, 16); tp1 += __shfl_xor(tp1, 32);
            tp2 += __shfl_xor(tp2, 16); tp2 += __shfl_xor(tp2, 32);
            tp3 += __shfl_xor(tp3, 16); tp3 += __shfl_xor(tp3, 32);
            if (ln < 16) {
                f4 w = {tp0, tp1, tp2, tp3};
                *(f4*)&wavepart[wv][rq << 2] = w;
            }
        }
        __syncthreads();   // (4)

        // ===== P5: Wvb MFMA (w0-7) + Mi/AsT; tvec->global (w15); stage ====
        if (wv < 8) {
            const int rowbase = (wv & 3) << 4;
            const int arow = rowbase + li;
            const int tc0 = (wv >> 2) << 1;
            h8 af0 = *(const h8*)&AsX[fidx(arow, 0, g)];
            h8 af1 = *(const h8*)&AsX[fidx(arow, 1, g)];
#pragma unroll
            for (int tt = 0; tt < 2; ++tt) {
                const int col = ((tc0 + tt) << 4) + li;
                const float bv = b_vb_s[col];
                f4 acc = {bv, bv, bv, bv};
                acc = __builtin_amdgcn_mfma_f32_16x16x32_f16(af0, *(const h8*)&WvbT[fidx(col, 0, g)], acc, 0, 0, 0);
                acc = __builtin_amdgcn_mfma_f32_16x16x32_f16(af1, *(const h8*)&WvbT[fidx(col, 1, g)], acc, 0, 0, 0);
#pragma unroll
                for (int r = 0; r < 4; ++r) {
                    const int row = rowbase + (g << 2) + r;
                    const float mn = MI(row, col) + a2v * ftanh(acc[r]);
                    MI(row, col) = mn;
                    AsT[sidx(row, col)] = (_Float16)ftanh(mn);
                }
            }
        } else if (wv == 15) {
            float tv = 0.f;
#pragma unroll
            for (int w = 0; w < 16; ++w) tv += wavepart[w][ln];
            tvec_all[f * S_ + ln] = tv;
        } else {
            if (tid >= 512 && tid < 576) vt[tid - 512] = pf;
            else if (tid >= 576 && tid < 580) w3s4[tid - 576] = pf;
            else if (tid >= 640 && tid < 768) bmgin[tid - 640] = b_mg_s[tid - 640] + pf;
        }
        __syncthreads();   // (5)
    }
    #undef MI
}

// ---------------------------------------------------------------------------
// K3: o = tvec@Wrel3 + b_rel3 + xo, then MLP + final head
// ---------------------------------------------------------------------------
__global__ __launch_bounds__(256)
void k3_post(const float* __restrict__ tvec_all, const float* __restrict__ xo_all,
             const float* __restrict__ Wrel3, const float* __restrict__ b_rel3,
             const float* __restrict__ Wm1, const float* __restrict__ b_m1,
             const float* __restrict__ Wm2, const float* __restrict__ b_m2,
             const float* __restrict__ Wout, const float* __restrict__ b_out,
             const float* __restrict__ fc_g, const float* __restrict__ fc_b,
             const float* __restrict__ Wfc, const float* __restrict__ b_fc,
             float* __restrict__ out)
{
    __shared__ float os[8][O_];
    __shared__ float tv_s[8][O_];
    __shared__ float w3l[S_ * O_];
    __shared__ float h1[8][D_];
    __shared__ float h2[8][D_];
    __shared__ float mus[8], rst[8];
    const int tid = threadIdx.x;
    const int f0 = blockIdx.x * 8;

    for (int i = tid; i < S_ * O_; i += 256) w3l[i] = Wrel3[i];
    for (int i = tid; i < 8 * O_; i += 256) tv_s[i >> 6][i & 63] = tvec_all[f0 * O_ + i];
    __syncthreads();

    { // os = tv @ Wrel3 + b_rel3 + xo
        const int j = tid & 63, r0 = tid >> 6;
#pragma unroll
        for (int ri = 0; ri < 2; ++ri) {
            const int r = r0 + 4 * ri;
            float a = b_rel3[j] + xo_all[(f0 + r) * O_ + j];
            for (int k = 0; k < S_; ++k) a = fmaf(tv_s[r][k], w3l[k * O_ + j], a);
            os[r][j] = a;
        }
    }
    __syncthreads();

    const int d0 = tid, d1 = tid + 256;
    {
        float a0[8], a1[8];
        float b0 = b_m1[d0], b1 = b_m1[d1];
#pragma unroll
        for (int r = 0; r < 8; ++r) { a0[r] = b0; a1[r] = b1; }
        for (int k = 0; k < O_; ++k) {
            float w0 = Wm1[k * D_ + d0], w1 = Wm1[k * D_ + d1];
#pragma unroll
            for (int r = 0; r < 8; ++r) {
                float e = os[r][k];
                a0[r] = fmaf(e, w0, a0[r]); a1[r] = fmaf(e, w1, a1[r]);
            }
        }
#pragma unroll
        for (int r = 0; r < 8; ++r) { h1[r][d0] = fmaxf(a0[r], 0.f); h1[r][d1] = fmaxf(a1[r], 0.f); }
    }
    __syncthreads();
    {
        float a0[8], a1[8];
        float b0 = b_m2[d0], b1 = b_m2[d1];
#pragma unroll
        for (int r = 0; r < 8; ++r) { a0[r] = b0; a1[r] = b1; }
        for (int k = 0; k < D_; ++k) {
            float w0 = Wm2[k * D_ + d0], w1 = Wm2[k * D_ + d1];
#pragma unroll
            for (int r = 0; r < 8; ++r) {
                float e = h1[r][k];
                a0[r] = fmaf(e, w0, a0[r]); a1[r] = fmaf(e, w1, a1[r]);
            }
        }
#pragma unroll
        for (int r = 0; r < 8; ++r) { h2[r][d0] = fmaxf(a0[r], 0.f); h2[r][d1] = fmaxf(a1[r], 0.f); }
    }
    __syncthreads();
    {
        float a0[8], a1[8];
        float b0 = b_out[d0], b1 = b_out[d1];
#pragma unroll
        for (int r = 0; r < 8; ++r) { a0[r] = b0; a1[r] = b1; }
        for (int k = 0; k < D_; ++k) {
            float w0 = Wout[k * D_ + d0], w1 = Wout[k * D_ + d1];
#pragma unroll
            for (int r = 0; r < 8; ++r) {
                float e = h2[r][k];
                a0[r] = fmaf(e, w0, a0[r]); a1[r] = fmaf(e, w1, a1[r]);
            }
        }
#pragma unroll
        for (int r = 0; r < 8; ++r) { h1[r][d0] = a0[r]; h1[r][d1] = a1[r]; }
    }
    __syncthreads();
    {
        const int r = tid >> 5, l = tid & 31;
        float s1 = 0.f, s2 = 0.f;
        for (int k = l; k < D_; k += 32) { float y = h1[r][k]; s1 += y; s2 += y * y; }
#pragma unroll
        for (int off = 16; off; off >>= 1) { s1 += __shfl_down(s1, off, 32); s2 += __shfl_down(s2, off, 32); }
        if (l == 0) {
            float mu = s1 / (float)D_;
            float var = s2 / (float)D_ - mu * mu;
            mus[r] = mu; rst[r] = rsqrtf(var + 1e-5f);
        }
    }
    __syncthreads();
    for (int i = tid; i < 8 * D_; i += 256) {
        int r = i >> 9, d = i & (D_ - 1);
        float y = (h1[r][d] - mus[r]) * rst[r] * fc_g[d] + fc_b[d];
        h1[r][d] = fmaxf(y, 0.f);
    }
    __syncthreads();
    {
        const int v = tid & 127, r0 = tid >> 7;
#pragma unroll
        for (int ri = 0; ri < 4; ++ri) {
            int r = r0 + 2 * ri;
            float a = b_fc[v];
            for (int k = 0; k < D_; ++k) a = fmaf(h1[r][k], Wfc[k * V_ + v], a);
            int f = f0 + r, t = f >> 5, b = f & 31;
            out[b * (V_ * T_) + v * T_ + t] = a;
        }
    }
}

// ---------------------------------------------------------------------------
extern "C" void kernel_launch(void* const* d_in, const int* in_sizes, int n_in,
                              void* d_out, int out_size, void* d_ws, size_t ws_size,
                              hipStream_t stream)
{
    (void)in_sizes; (void)n_in; (void)out_size; (void)ws_size;
    const int*   ids   = (const int*)  d_in[0];
    const float* emb   = (const float*)d_in[1];
    const float* We    = (const float*)d_in[2];
    const float* be    = (const float*)d_in[3];
    const float* Win   = (const float*)d_in[4];
    const float* b_in  = (const float*)d_in[5];
    const float* Win2  = (const float*)d_in[6];
    const float* b_in2 = (const float*)d_in[7];
    const float* Win3  = (const float*)d_in[8];
    const float* b_in3 = (const float*)d_in[9];
    const float* Wig   = (const float*)d_in[10];
    const float* b_ig  = (const float*)d_in[11];
    const float* Wmg   = (const float*)d_in[12];
    const float* b_mg  = (const float*)d_in[13];
    const float* ibp   = (const float*)d_in[14];
    const float* fbp   = (const float*)d_in[15];
    const float* Wqkv  = (const float*)d_in[16];
    const float* b_qkv = (const float*)d_in[17];
    const float* ln_g  = (const float*)d_in[18];
    const float* ln_b  = (const float*)d_in[19];
    const float* a1p   = (const float*)d_in[20];
    const float* a2p   = (const float*)d_in[21];
    const float* Wrel  = (const float*)d_in[22];
    const float* b_rel = (const float*)d_in[23];
    const float* Wvb   = (const float*)d_in[24];
    const float* b_vb  = (const float*)d_in[25];
    const float* Wrel3 = (const float*)d_in[26];
    const float* b_rel3= (const float*)d_in[27];
    const float* Wm1   = (const float*)d_in[28];
    const float* b_m1  = (const float*)d_in[29];
    const float* Wm2   = (const float*)d_in[30];
    const float* b_m2  = (const float*)d_in[31];
    const float* Wout  = (const float*)d_in[32];
    const float* b_out = (const float*)d_in[33];
    const float* Mi0   = (const float*)d_in[34];
    const float* Mr0   = (const float*)d_in[35];
    const float* fc_g  = (const float*)d_in[36];
    const float* fc_b  = (const float*)d_in[37];
    const float* Wfc   = (const float*)d_in[38];
    const float* b_fc  = (const float*)d_in[39];

    float* ws = (float*)d_ws;
    float* v_all    = ws;
    float* gIn_all  = v_all    + T_ * B_ * S_;
    float* w3_all   = gIn_all  + T_ * B_ * 2 * S_;
    float* xo_all   = w3_all   + T_ * B_ * N_;
    float* tvec_all = xo_all   + T_ * B_ * O_;

    k1_pre<<<dim3((T_ * B_) / 8), dim3(256), 0, stream>>>(
        ids, emb, We, be, Win, b_in, Win2, b_in2, Win3, b_in3, Wig, b_ig,
        v_all, gIn_all, w3_all, xo_all);

    k2_scan<<<dim3(B_), dim3(1024), 0, stream>>>(
        v_all, gIn_all, w3_all,
        Wmg, b_mg, Wqkv, b_qkv, ln_g, ln_b,
        Wrel, b_rel, Wvb, b_vb,
        Mi0, Mr0, ibp, fbp, a1p, a2p, tvec_all);

    k3_post<<<dim3((T_ * B_) / 8), dim3(256), 0, stream>>>(
        tvec_all, xo_all, Wrel3, b_rel3,
        Wm1, b_m1, Wm2, b_m2, Wout, b_out, fc_g, fc_b, Wfc, b_fc,
        (float*)d_out);
}

// Round 7
// 899.761 us; speedup vs baseline: 5.1029x; 1.1224x over previous
//
#include <hip/hip_runtime.h>
#include <hip/hip_fp16.h>
#include <math.h>

#define T_ 128
#define B_ 32
#define D_ 512
#define V_ 128
#define S_ 64
#define N_ 4
#define R_ 64
#define O_ 64

typedef _Float16 h4 __attribute__((ext_vector_type(4)));
typedef _Float16 h8 __attribute__((ext_vector_type(8)));
typedef float f4 __attribute__((ext_vector_type(4)));

__device__ __forceinline__ float fsigm(float x) {
    return __fdividef(1.0f, 1.0f + __expf(-x));
}
__device__ __forceinline__ float ftanh(float x) {
    float e = __expf(2.f * x);
    return 1.f - __fdividef(2.f, e + 1.f);
}

// ---- h8-contiguous fragment layout for [rows][64] f16 operand tiles ----
__device__ __forceinline__ int fidx(int row, int ks, int g) {
    return row * 64 + ((((ks << 2) | g) ^ (row & 7)) << 3);
}
__device__ __forceinline__ int sidx(int row, int k) {
    int ks = k >> 5, u = (k >> 4) & 1, gg = (k >> 2) & 3, e = k & 3;
    return row * 64 + ((((ks << 2) | gg) ^ (row & 7)) << 3) + (u << 2) + e;
}

// ---------------------------------------------------------------------------
// K1: precompute (all t,b in parallel) — unchanged
// ---------------------------------------------------------------------------
__global__ __launch_bounds__(256)
void k1_pre(const int* __restrict__ ids, const float* __restrict__ emb,
            const float* __restrict__ We, const float* __restrict__ be,
            const float* __restrict__ Win, const float* __restrict__ b_in,
            const float* __restrict__ Win2, const float* __restrict__ b_in2,
            const float* __restrict__ Win3, const float* __restrict__ b_in3,
            const float* __restrict__ Wig, const float* __restrict__ b_ig,
            float* __restrict__ v_all, float* __restrict__ gIn_all,
            float* __restrict__ w3_all, float* __restrict__ xo_all)
{
    __shared__ float E[8][D_];
    __shared__ float X[8][D_];
    __shared__ float vs[8][S_];
    __shared__ float sc[8][N_];
    const int tid = threadIdx.x;
    const int f0 = blockIdx.x * 8;

    for (int i = tid; i < 8 * D_; i += 256) {
        int r = i >> 9, d = i & (D_ - 1);
        int f = f0 + r;
        int t = f >> 5, b = f & 31;
        E[r][d] = emb[ids[b * T_ + t] * D_ + d];
    }
    __syncthreads();

    { // src = E @ We + be
        const int d0 = tid, d1 = tid + 256;
        float a0[8], a1[8];
        float b0 = be[d0], b1 = be[d1];
#pragma unroll
        for (int r = 0; r < 8; ++r) { a0[r] = b0; a1[r] = b1; }
        for (int k = 0; k < D_; ++k) {
            float w0 = We[k * D_ + d0], w1 = We[k * D_ + d1];
#pragma unroll
            for (int r = 0; r < 8; ++r) {
                float e = E[r][k];
                a0[r] = fmaf(e, w0, a0[r]);
                a1[r] = fmaf(e, w1, a1[r]);
            }
        }
#pragma unroll
        for (int r = 0; r < 8; ++r) { X[r][d0] = a0[r]; X[r][d1] = a1[r]; }
    }
    __syncthreads();

    { // v and xo
        const int j = tid & 63, r0 = tid >> 6;
#pragma unroll
        for (int ri = 0; ri < 2; ++ri) {
            int r = r0 + 4 * ri;
            float a = b_in[j], a2 = b_in2[j];
            for (int k = 0; k < D_; ++k) {
                float x = X[r][k];
                a  = fmaf(x, Win [k * S_ + j], a);
                a2 = fmaf(x, Win2[k * O_ + j], a2);
            }
            vs[r][j] = a;
            v_all [(f0 + r) * S_ + j] = a;
            xo_all[(f0 + r) * O_ + j] = a2;
        }
    }
    if (tid < 32) {
        int r = tid >> 2, n = tid & 3;
        float a = b_in3[n];
        for (int k = 0; k < D_; ++k) a = fmaf(X[r][k], Win3[k * N_ + n], a);
        sc[r][n] = a;
    }
    __syncthreads();
    if (tid < 8) {
        float x0 = sc[tid][0], x1 = sc[tid][1], x2 = sc[tid][2], x3 = sc[tid][3];
        float m = fmaxf(fmaxf(x0, x1), fmaxf(x2, x3));
        float e0 = expf(x0 - m), e1 = expf(x1 - m), e2 = expf(x2 - m), e3 = expf(x3 - m);
        float inv = 1.0f / (e0 + e1 + e2 + e3);
        float* w = &w3_all[(f0 + tid) * N_];
        w[0] = e0 * inv; w[1] = e1 * inv; w[2] = e2 * inv; w[3] = e3 * inv;
    }
    {
        const int c = tid & 127, r0 = tid >> 7;
#pragma unroll
        for (int ri = 0; ri < 4; ++ri) {
            int r = r0 + 2 * ri;
            float a = b_ig[c];
            for (int k = 0; k < S_; ++k) a = fmaf(vs[r][k], Wig[k * 2 * S_ + c], a);
            gIn_all[(f0 + r) * 2 * S_ + c] = a;
        }
    }
}

// ---------------------------------------------------------------------------
// K2: sequential scan, packed-VALU + balanced-waves edition.
//   P1: gates MFMA (16w, 2 tiles each) + prefetch
//   P2: qkv MFMA (w0-3) + LN 16-partials + vgT/P_op
//   P3: wvm MFMA (w0-3); A-scores (w4-7); vvsT (w8-11)
//   P4: in-register Mrs update (packed f4) + transfer + tvec partials
//   P5: Wvb MFMA (16w, 1 tile each) + Mi/AsT; tvec (w15); stage (w8-11)
// ---------------------------------------------------------------------------
__global__ __launch_bounds__(1024, 4)
void k2_scan(const float* __restrict__ v_all, const float* __restrict__ gIn_all,
             const float* __restrict__ w3_all,
             const float* __restrict__ Wmg, const float* __restrict__ b_mg,
             const float* __restrict__ Wqkv, const float* __restrict__ b_qkv,
             const float* __restrict__ ln_g, const float* __restrict__ ln_b,
             const float* __restrict__ Wrel, const float* __restrict__ b_rel,
             const float* __restrict__ Wvb, const float* __restrict__ b_vb,
             const float* __restrict__ Mi0, const float* __restrict__ Mr0,
             const float* __restrict__ p_ib, const float* __restrict__ p_fb,
             const float* __restrict__ p_a1, const float* __restrict__ p_a2,
             float* __restrict__ tvec_all)
{
    const int tid = threadIdx.x;
    const int b = blockIdx.x;
    const int wv = tid >> 6;        // wave id 0..15
    const int ln = tid & 63;        // lane
    const int g  = ln >> 4;         // 4-lane-group
    const int li = ln & 15;

    __shared__ __align__(16) float Mi_s[S_ * 68];           // 17408
    __shared__ __align__(16) _Float16 AsT[S_ * S_];         // tanh(Mi): gates A-op
    __shared__ __align__(16) _Float16 AsX[S_ * S_];         // transfer: Wvb A-op
    __shared__ __align__(16) _Float16 Mif16[S_ * S_];       // Mi after gates: qkv A-op
    __shared__ __align__(16) _Float16 P_op[16 * S_];        // qkv_v*ln_g (rows 4-15 zero)
    __shared__ __align__(16) _Float16 WmgT[2 * S_ * S_];
    __shared__ __align__(16) _Float16 WvbT[S_ * S_];
    __shared__ __align__(16) _Float16 WrelT[S_ * S_];
    __shared__ __align__(16) _Float16 WqkvT[16 * S_];
    __shared__ __align__(16) float vgT[12 * 68];            // qkv_raw*g, transposed
    __shared__ __align__(16) float gT[12 * 68];             // ln_g transposed
    __shared__ __align__(16) float lbT[12 * 68];            // ln_b transposed
    __shared__ __align__(16) float vvsT[S_ * 4];            // [s][m] post-LN vv
    __shared__ __align__(16) float wvm[N_][S_];             // a1-scaled
    __shared__ __align__(16) float G2s[N_][S_];
    __shared__ __align__(16) float B2s[N_][S_];
    __shared__ __align__(16) float wavepart[16][S_];
    __shared__ float bmgin[128];
    __shared__ float b_mg_s[128];
    __shared__ __align__(16) float b_vb_s[64];
    __shared__ float b_qkv_s[16];
    __shared__ float vt[S_];
    __shared__ __align__(16) float w3s4[4];
    __shared__ __align__(16) float Amat[N_][N_];
    __shared__ __align__(16) float red1[16], red2[16];

    const float ib = p_ib[0], fb = p_fb[0], a1 = p_a1[0], a2v = p_a2[0];

    #define MI(r, c) Mi_s[(r) * 68 + (c)]

    // ---- init ----
    for (int i = tid; i < 2 * S_ * S_; i += 1024) {        // Wmg (64,128)
        int k = i >> 7, j = i & 127;
        WmgT[sidx(j, k)] = (_Float16)Wmg[i];
    }
    for (int i = tid; i < S_ * S_; i += 1024) {            // Wvb (64,64)
        int r = i >> 6, j = i & 63;
        WvbT[sidx(j, r)] = (_Float16)Wvb[i];
    }
    for (int i = tid; i < S_ * S_; i += 1024) {            // Wrel (64s,64r)
        int s = i >> 6, r = i & 63;
        WrelT[sidx(r, s)] = (_Float16)Wrel[i];
    }
    if (tid < 16 * S_) {                                    // Wqkv (64,12)
        int c = tid >> 6, k = tid & 63;
        float w = (c < 12) ? Wqkv[k * 12 + c] : 0.f;
        WqkvT[sidx(c, k)] = (_Float16)w;
    }
    if (tid < 768) {                                        // gT/lbT transposed
        int s = tid / 12, c = tid - s * 12;
        gT[c * 68 + s]  = ln_g[tid];
        lbT[c * 68 + s] = ln_b[tid];
    }
    if (tid < 128) b_mg_s[tid] = b_mg[tid];
    else if (tid < 192) b_vb_s[tid - 128] = b_vb[tid - 128];
    else if (tid < 208) b_qkv_s[tid - 192] = (tid - 192 < 12) ? b_qkv[tid - 192] : 0.f;
    if (tid < 1024) P_op[tid] = (_Float16)0.f;
    if (tid < 256) {   // G2/B2 correction tables
        const int m = tid >> 6, r = tid & 63;
        float g2 = 0.f, b2 = 0.f;
        for (int s = 0; s < S_; ++s) {
            float w = Wrel[s * R_ + r];
            g2 = fmaf(ln_g[s * 12 + 8 + m], w, g2);
            b2 = fmaf(ln_b[s * 12 + 8 + m], w, b2);
        }
        G2s[m][r] = g2;
        B2s[m][r] = a1 * b2;
    }
    for (int i = tid; i < S_ * S_; i += 1024) MI(i >> 6, i & 63) = Mi0[i];
    {   // AsT = tanh(Mi0)
        const int row = tid >> 4, k0 = (tid & 15) << 2;
        const float* mp = Mi0 + (tid << 2);
        h4 t4;
        t4[0] = (_Float16)ftanh(mp[0]); t4[1] = (_Float16)ftanh(mp[1]);
        t4[2] = (_Float16)ftanh(mp[2]); t4[3] = (_Float16)ftanh(mp[3]);
        *(h4*)&AsT[sidx(row, k0)] = t4;
    }
    // Mrs -> registers: thread owns (s = tid>>4, r4 = (tid&15)*4), n = 0..3
    f4 mrs0, mrs1, mrs2, mrs3, a1brel4;
    {
        const int s0i = tid >> 4, r4i = (tid & 15) << 2;
        const float* mrp = Mr0 + s0i * 64 + r4i;
        mrs0 = *(const f4*)&mrp[0];
        mrs1 = *(const f4*)&mrp[4096];
        mrs2 = *(const f4*)&mrp[8192];
        mrs3 = *(const f4*)&mrp[12288];
        f4 br = *(const f4*)&b_rel[r4i];
        a1brel4 = a1 * br;
    }
    // t=0 step inputs
    if (tid < 64) vt[tid] = v_all[b * S_ + tid];
    else if (tid < 68) w3s4[tid - 64] = w3_all[b * N_ + (tid - 64)];
    if (tid >= 128 && tid < 256)
        bmgin[tid - 128] = b_mg[tid - 128] + gIn_all[b * 2 * S_ + (tid - 128)];
    __syncthreads();

    for (int t = 0; t < T_; ++t) {
        const int f = t * B_ + b;

        // ===== P1: gates MFMA (16 waves); prefetch t+1 inputs =============
        float pf = 0.f;
        {
            const int fn = ((t + 1 < T_) ? t + 1 : t) * B_ + b;
            if (tid >= 512 && tid < 576) pf = v_all[fn * S_ + (tid - 512)];
            else if (tid >= 576 && tid < 580) pf = w3_all[fn * N_ + (tid - 576)];
            else if (tid >= 640 && tid < 768) pf = gIn_all[fn * 2 * S_ + (tid - 640)];
        }
        {
            const int rowbase = (wv & 3) << 4;
            const int arow = rowbase + li;
            const int colI = ((wv >> 2) << 4) + li;
            const int colF = colI + 64;
            h8 af0 = *(const h8*)&AsT[fidx(arow, 0, g)];
            h8 af1 = *(const h8*)&AsT[fidx(arow, 1, g)];
            const float bi = bmgin[colI], bfv = bmgin[colF];
            f4 accI = {bi, bi, bi, bi};
            f4 accF = {bfv, bfv, bfv, bfv};
            accI = __builtin_amdgcn_mfma_f32_16x16x32_f16(af0, *(const h8*)&WmgT[fidx(colI, 0, g)], accI, 0, 0, 0);
            accI = __builtin_amdgcn_mfma_f32_16x16x32_f16(af1, *(const h8*)&WmgT[fidx(colI, 1, g)], accI, 0, 0, 0);
            accF = __builtin_amdgcn_mfma_f32_16x16x32_f16(af0, *(const h8*)&WmgT[fidx(colF, 0, g)], accF, 0, 0, 0);
            accF = __builtin_amdgcn_mfma_f32_16x16x32_f16(af1, *(const h8*)&WmgT[fidx(colF, 1, g)], accF, 0, 0, 0);
            const float vc = vt[colI];
#pragma unroll
            for (int r = 0; r < 4; ++r) {
                const int row = rowbase + (g << 2) + r;
                const float gi = fsigm(accI[r] + ib);
                const float gf = fsigm(accF[r] + fb);
                const float mo = MI(row, colI);
                const float mn = gf * mo + gi * ftanh(vt[row] * vc);
                MI(row, colI) = mn;
                Mif16[sidx(row, colI)] = (_Float16)mn;
            }
        }
        __syncthreads();   // (1)

        // ===== P2: qkv MFMA (w0-3) + LN 16-partials + vgT/P_op ============
        if (wv < 4) {
            const int rowbase = wv << 4;
            const int arow = rowbase + li;
            h8 af0 = *(const h8*)&Mif16[fidx(arow, 0, g)];
            h8 af1 = *(const h8*)&Mif16[fidx(arow, 1, g)];
            const float bq = b_qkv_s[li];
            f4 qacc = {bq, bq, bq, bq};
            qacc = __builtin_amdgcn_mfma_f32_16x16x32_f16(af0, *(const h8*)&WqkvT[fidx(li, 0, g)], qacc, 0, 0, 0);
            qacc = __builtin_amdgcn_mfma_f32_16x16x32_f16(af1, *(const h8*)&WqkvT[fidx(li, 1, g)], qacc, 0, 0, 0);
            float s1 = 0.f, s2 = 0.f;
            if (li < 12) {
                const int srow = rowbase + (g << 2);
                f4 g4 = *(const f4*)&gT[li * 68 + srow];
                f4 vg = qacc * g4;
                *(f4*)&vgT[li * 68 + srow] = vg;
                s1 = (qacc[0] + qacc[1]) + (qacc[2] + qacc[3]);
                f4 sq = qacc * qacc;
                s2 = (sq[0] + sq[1]) + (sq[2] + sq[3]);
                if (li >= 8) {   // P-operand rows m = li-8
                    h4 p4 = __builtin_convertvector(vg, h4);
                    *(h4*)&P_op[sidx(li - 8, srow)] = p4;
                }
            }
#pragma unroll
            for (int off = 8; off; off >>= 1) {
                s1 += __shfl_down(s1, off); s2 += __shfl_down(s2, off);
            }
            if (li == 0) { red1[(wv << 2) + g] = s1; red2[(wv << 2) + g] = s2; }
        }
        __syncthreads();   // (2)

        // ===== P3: wvm MFMA (w0-3); A-scores (w4-7); vvsT (w8-11) =========
        {
            f4 rA = *(const f4*)&red1[0];
            rA += *(const f4*)&red1[4];
            rA += *(const f4*)&red1[8];
            rA += *(const f4*)&red1[12];
            f4 rB = *(const f4*)&red2[0];
            rB += *(const f4*)&red2[4];
            rB += *(const f4*)&red2[8];
            rB += *(const f4*)&red2[12];
            const float sA = (rA[0] + rA[1]) + (rA[2] + rA[3]);
            const float sB = (rB[0] + rB[1]) + (rB[2] + rB[3]);
            const float mu = sA * (1.f / 768.f);
            const float var = sB * (1.f / 768.f) - mu * mu;
            const float rstd = rsqrtf(var + 1e-5f);
            const float murstd = mu * rstd;
            if (wv < 4) {
                h8 af0 = *(const h8*)&P_op[fidx(li, 0, g)];
                h8 af1 = *(const h8*)&P_op[fidx(li, 1, g)];
                const int col = (wv << 4) + li;
                f4 acc = {0.f, 0.f, 0.f, 0.f};
                acc = __builtin_amdgcn_mfma_f32_16x16x32_f16(af0, *(const h8*)&WrelT[fidx(col, 0, g)], acc, 0, 0, 0);
                acc = __builtin_amdgcn_mfma_f32_16x16x32_f16(af1, *(const h8*)&WrelT[fidx(col, 1, g)], acc, 0, 0, 0);
                if (ln < 16) {
                    const float sa = a1 * rstd;
                    const float sb = -a1 * murstd;
#pragma unroll
                    for (int r = 0; r < 4; ++r)
                        wvm[r][col] = sa * acc[r] + sb * G2s[r][col] + B2s[r][col];
                }
            } else if (wv < 8) {
                // A-scores: n = wv-4, m = g, s-chunk = li*4
                const int n = wv - 4;
                const int s0 = li << 2;
                f4 vgq = *(const f4*)&vgT[n * 68 + s0];
                f4 gq  = *(const f4*)&gT [n * 68 + s0];
                f4 lbq = *(const f4*)&lbT[n * 68 + s0];
                f4 qv  = rstd * vgq - murstd * gq + lbq;
                const int kr = 4 + g;
                f4 vgk = *(const f4*)&vgT[kr * 68 + s0];
                f4 gk  = *(const f4*)&gT [kr * 68 + s0];
                f4 lbk = *(const f4*)&lbT[kr * 68 + s0];
                f4 kv  = rstd * vgk - murstd * gk + lbk;
                f4 pr = qv * kv;
                float a = (pr[0] + pr[1]) + (pr[2] + pr[3]);
                a += __shfl_down(a, 8);
                a += __shfl_down(a, 4);
                a += __shfl_down(a, 2);
                a += __shfl_down(a, 1);
                a *= 0.125f;
                float s0v = __shfl(a, 0), s1v = __shfl(a, 16);
                float s2v = __shfl(a, 32), s3v = __shfl(a, 48);
                if (li == 0) {
                    float mx = fmaxf(fmaxf(s0v, s1v), fmaxf(s2v, s3v));
                    float e0 = __expf(s0v - mx), e1 = __expf(s1v - mx);
                    float e2 = __expf(s2v - mx), e3 = __expf(s3v - mx);
                    float inv = __fdividef(1.f, e0 + e1 + e2 + e3);
                    float ev = (g == 0) ? e0 : (g == 1) ? e1 : (g == 2) ? e2 : e3;
                    Amat[n][g] = ev * inv;
                }
            } else if (wv < 12) {
                // vvsT: m = wv-8, s = ln
                const int m = wv - 8;
                const int c = (8 + m) * 68 + ln;
                vvsT[(ln << 2) + m] = rstd * vgT[c] - murstd * gT[c] + lbT[c];
            }
        }
        __syncthreads();   // (3)

        // ===== P4: in-register Mrs update (packed) + transfer + tvec ======
        {
            const int s = tid >> 4, rq = tid & 15, r4 = rq << 2;
            f4 Am0 = *(const f4*)&Amat[0][0];
            f4 Am1 = *(const f4*)&Amat[1][0];
            f4 Am2 = *(const f4*)&Amat[2][0];
            f4 Am3 = *(const f4*)&Amat[3][0];
            f4 w3r = *(const f4*)&w3s4[0];
            f4 vv4 = *(const f4*)&vvsT[s << 2];
            f4 wvA4 = *(const f4*)&wvm[0][r4];   // a1-scaled
            f4 wvB4 = *(const f4*)&wvm[1][r4];
            f4 wvC4 = *(const f4*)&wvm[2][r4];
            f4 wvD4 = *(const f4*)&wvm[3][r4];
            {   // n = 0
                const float c0 = Am0[0] * vv4[0], c1 = Am0[1] * vv4[1];
                const float c2 = Am0[2] * vv4[2], c3 = Am0[3] * vv4[3];
                mrs0 += a1brel4 + c0 * wvA4 + c1 * wvB4 + c2 * wvC4 + c3 * wvD4;
            }
            {   // n = 1
                const float c0 = Am1[0] * vv4[0], c1 = Am1[1] * vv4[1];
                const float c2 = Am1[2] * vv4[2], c3 = Am1[3] * vv4[3];
                mrs1 += a1brel4 + c0 * wvA4 + c1 * wvB4 + c2 * wvC4 + c3 * wvD4;
            }
            {   // n = 2
                const float c0 = Am2[0] * vv4[0], c1 = Am2[1] * vv4[1];
                const float c2 = Am2[2] * vv4[2], c3 = Am2[3] * vv4[3];
                mrs2 += a1brel4 + c0 * wvA4 + c1 * wvB4 + c2 * wvC4 + c3 * wvD4;
            }
            {   // n = 3
                const float c0 = Am3[0] * vv4[0], c1 = Am3[1] * vv4[1];
                const float c2 = Am3[2] * vv4[2], c3 = Am3[3] * vv4[3];
                mrs3 += a1brel4 + c0 * wvA4 + c1 * wvB4 + c2 * wvC4 + c3 * wvD4;
            }
            f4 trv = w3r[0] * mrs0 + w3r[1] * mrs1 + w3r[2] * mrs2 + w3r[3] * mrs3;
            h4 trh = __builtin_convertvector(trv, h4);
            *(h4*)&AsX[sidx(s, r4)] = trh;
            f4 tp = vt[s] * trv;
            {
                f4 o;
                o[0] = __shfl_xor(tp[0], 16); o[1] = __shfl_xor(tp[1], 16);
                o[2] = __shfl_xor(tp[2], 16); o[3] = __shfl_xor(tp[3], 16);
                tp += o;
                o[0] = __shfl_xor(tp[0], 32); o[1] = __shfl_xor(tp[1], 32);
                o[2] = __shfl_xor(tp[2], 32); o[3] = __shfl_xor(tp[3], 32);
                tp += o;
            }
            if (ln < 16) *(f4*)&wavepart[wv][r4] = tp;
        }
        __syncthreads();   // (4)

        // ===== P5: Wvb MFMA (16 waves, 1 tile) + Mi/AsT; tvec; stage ======
        {
            const int rowbase = (wv & 3) << 4;
            const int arow = rowbase + li;
            const int col = ((wv >> 2) << 4) + li;
            h8 af0 = *(const h8*)&AsX[fidx(arow, 0, g)];
            h8 af1 = *(const h8*)&AsX[fidx(arow, 1, g)];
            const float bv = b_vb_s[col];
            f4 acc = {bv, bv, bv, bv};
            acc = __builtin_amdgcn_mfma_f32_16x16x32_f16(af0, *(const h8*)&WvbT[fidx(col, 0, g)], acc, 0, 0, 0);
            acc = __builtin_amdgcn_mfma_f32_16x16x32_f16(af1, *(const h8*)&WvbT[fidx(col, 1, g)], acc, 0, 0, 0);
#pragma unroll
            for (int r = 0; r < 4; ++r) {
                const int row = rowbase + (g << 2) + r;
                const float mn = MI(row, col) + a2v * ftanh(acc[r]);
                MI(row, col) = mn;
                AsT[sidx(row, col)] = (_Float16)ftanh(mn);
            }
        }
        if (wv == 15) {
            float tv = 0.f;
#pragma unroll
            for (int w = 0; w < 16; ++w) tv += wavepart[w][ln];
            tvec_all[f * S_ + ln] = tv;
        } else if (tid >= 512 && tid < 768) {
            if (tid < 576) vt[tid - 512] = pf;
            else if (tid < 580) w3s4[tid - 576] = pf;
            else if (tid >= 640) bmgin[tid - 640] = b_mg_s[tid - 640] + pf;
        }
        __syncthreads();   // (5)
    }
    #undef MI
}

// ---------------------------------------------------------------------------
// K3: o = tvec@Wrel3 + b_rel3 + xo, then MLP + final head — unchanged
// ---------------------------------------------------------------------------
__global__ __launch_bounds__(256)
void k3_post(const float* __restrict__ tvec_all, const float* __restrict__ xo_all,
             const float* __restrict__ Wrel3, const float* __restrict__ b_rel3,
             const float* __restrict__ Wm1, const float* __restrict__ b_m1,
             const float* __restrict__ Wm2, const float* __restrict__ b_m2,
             const float* __restrict__ Wout, const float* __restrict__ b_out,
             const float* __restrict__ fc_g, const float* __restrict__ fc_b,
             const float* __restrict__ Wfc, const float* __restrict__ b_fc,
             float* __restrict__ out)
{
    __shared__ float os[8][O_];
    __shared__ float tv_s[8][O_];
    __shared__ float w3l[S_ * O_];
    __shared__ float h1[8][D_];
    __shared__ float h2[8][D_];
    __shared__ float mus[8], rst[8];
    const int tid = threadIdx.x;
    const int f0 = blockIdx.x * 8;

    for (int i = tid; i < S_ * O_; i += 256) w3l[i] = Wrel3[i];
    for (int i = tid; i < 8 * O_; i += 256) tv_s[i >> 6][i & 63] = tvec_all[f0 * O_ + i];
    __syncthreads();

    { // os = tv @ Wrel3 + b_rel3 + xo
        const int j = tid & 63, r0 = tid >> 6;
#pragma unroll
        for (int ri = 0; ri < 2; ++ri) {
            const int r = r0 + 4 * ri;
            float a = b_rel3[j] + xo_all[(f0 + r) * O_ + j];
            for (int k = 0; k < S_; ++k) a = fmaf(tv_s[r][k], w3l[k * O_ + j], a);
            os[r][j] = a;
        }
    }
    __syncthreads();

    const int d0 = tid, d1 = tid + 256;
    {
        float a0[8], a1[8];
        float b0 = b_m1[d0], b1 = b_m1[d1];
#pragma unroll
        for (int r = 0; r < 8; ++r) { a0[r] = b0; a1[r] = b1; }
        for (int k = 0; k < O_; ++k) {
            float w0 = Wm1[k * D_ + d0], w1 = Wm1[k * D_ + d1];
#pragma unroll
            for (int r = 0; r < 8; ++r) {
                float e = os[r][k];
                a0[r] = fmaf(e, w0, a0[r]); a1[r] = fmaf(e, w1, a1[r]);
            }
        }
#pragma unroll
        for (int r = 0; r < 8; ++r) { h1[r][d0] = fmaxf(a0[r], 0.f); h1[r][d1] = fmaxf(a1[r], 0.f); }
    }
    __syncthreads();
    {
        float a0[8], a1[8];
        float b0 = b_m2[d0], b1 = b_m2[d1];
#pragma unroll
        for (int r = 0; r < 8; ++r) { a0[r] = b0; a1[r] = b1; }
        for (int k = 0; k < D_; ++k) {
            float w0 = Wm2[k * D_ + d0], w1 = Wm2[k * D_ + d1];
#pragma unroll
            for (int r = 0; r < 8; ++r) {
                float e = h1[r][k];
                a0[r] = fmaf(e, w0, a0[r]); a1[r] = fmaf(e, w1, a1[r]);
            }
        }
#pragma unroll
        for (int r = 0; r < 8; ++r) { h2[r][d0] = fmaxf(a0[r], 0.f); h2[r][d1] = fmaxf(a1[r], 0.f); }
    }
    __syncthreads();
    {
        float a0[8], a1[8];
        float b0 = b_out[d0], b1 = b_out[d1];
#pragma unroll
        for (int r = 0; r < 8; ++r) { a0[r] = b0; a1[r] = b1; }
        for (int k = 0; k < D_; ++k) {
            float w0 = Wout[k * D_ + d0], w1 = Wout[k * D_ + d1];
#pragma unroll
            for (int r = 0; r < 8; ++r) {
                float e = h2[r][k];
                a0[r] = fmaf(e, w0, a0[r]); a1[r] = fmaf(e, w1, a1[r]);
            }
        }
#pragma unroll
        for (int r = 0; r < 8; ++r) { h1[r][d0] = a0[r]; h1[r][d1] = a1[r]; }
    }
    __syncthreads();
    {
        const int r = tid >> 5, l = tid & 31;
        float s1 = 0.f, s2 = 0.f;
        for (int k = l; k < D_; k += 32) { float y = h1[r][k]; s1 += y; s2 += y * y; }
#pragma unroll
        for (int off = 16; off; off >>= 1) { s1 += __shfl_down(s1, off, 32); s2 += __shfl_down(s2, off, 32); }
        if (l == 0) {
            float mu = s1 / (float)D_;
            float var = s2 / (float)D_ - mu * mu;
            mus[r] = mu; rst[r] = rsqrtf(var + 1e-5f);
        }
    }
    __syncthreads();
    for (int i = tid; i < 8 * D_; i += 256) {
        int r = i >> 9, d = i & (D_ - 1);
        float y = (h1[r][d] - mus[r]) * rst[r] * fc_g[d] + fc_b[d];
        h1[r][d] = fmaxf(y, 0.f);
    }
    __syncthreads();
    {
        const int v = tid & 127, r0 = tid >> 7;
#pragma unroll
        for (int ri = 0; ri < 4; ++ri) {
            int r = r0 + 2 * ri;
            float a = b_fc[v];
            for (int k = 0; k < D_; ++k) a = fmaf(h1[r][k], Wfc[k * V_ + v], a);
            int f = f0 + r, t = f >> 5, b = f & 31;
            out[b * (V_ * T_) + v * T_ + t] = a;
        }
    }
}

// ---------------------------------------------------------------------------
extern "C" void kernel_launch(void* const* d_in, const int* in_sizes, int n_in,
                              void* d_out, int out_size, void* d_ws, size_t ws_size,
                              hipStream_t stream)
{
    (void)in_sizes; (void)n_in; (void)out_size; (void)ws_size;
    const int*   ids   = (const int*)  d_in[0];
    const float* emb   = (const float*)d_in[1];
    const float* We    = (const float*)d_in[2];
    const float* be    = (const float*)d_in[3];
    const float* Win   = (const float*)d_in[4];
    const float* b_in  = (const float*)d_in[5];
    const float* Win2  = (const float*)d_in[6];
    const float* b_in2 = (const float*)d_in[7];
    const float* Win3  = (const float*)d_in[8];
    const float* b_in3 = (const float*)d_in[9];
    const float* Wig   = (const float*)d_in[10];
    const float* b_ig  = (const float*)d_in[11];
    const float* Wmg   = (const float*)d_in[12];
    const float* b_mg  = (const float*)d_in[13];
    const float* ibp   = (const float*)d_in[14];
    const float* fbp   = (const float*)d_in[15];
    const float* Wqkv  = (const float*)d_in[16];
    const float* b_qkv = (const float*)d_in[17];
    const float* ln_g  = (const float*)d_in[18];
    const float* ln_b  = (const float*)d_in[19];
    const float* a1p   = (const float*)d_in[20];
    const float* a2p   = (const float*)d_in[21];
    const float* Wrel  = (const float*)d_in[22];
    const float* b_rel = (const float*)d_in[23];
    const float* Wvb   = (const float*)d_in[24];
    const float* b_vb  = (const float*)d_in[25];
    const float* Wrel3 = (const float*)d_in[26];
    const float* b_rel3= (const float*)d_in[27];
    const float* Wm1   = (const float*)d_in[28];
    const float* b_m1  = (const float*)d_in[29];
    const float* Wm2   = (const float*)d_in[30];
    const float* b_m2  = (const float*)d_in[31];
    const float* Wout  = (const float*)d_in[32];
    const float* b_out = (const float*)d_in[33];
    const float* Mi0   = (const float*)d_in[34];
    const float* Mr0   = (const float*)d_in[35];
    const float* fc_g  = (const float*)d_in[36];
    const float* fc_b  = (const float*)d_in[37];
    const float* Wfc   = (const float*)d_in[38];
    const float* b_fc  = (const float*)d_in[39];

    float* ws = (float*)d_ws;
    float* v_all    = ws;
    float* gIn_all  = v_all    + T_ * B_ * S_;
    float* w3_all   = gIn_all  + T_ * B_ * 2 * S_;
    float* xo_all   = w3_all   + T_ * B_ * N_;
    float* tvec_all = xo_all   + T_ * B_ * O_;

    k1_pre<<<dim3((T_ * B_) / 8), dim3(256), 0, stream>>>(
        ids, emb, We, be, Win, b_in, Win2, b_in2, Win3, b_in3, Wig, b_ig,
        v_all, gIn_all, w3_all, xo_all);

    k2_scan<<<dim3(B_), dim3(1024), 0, stream>>>(
        v_all, gIn_all, w3_all,
        Wmg, b_mg, Wqkv, b_qkv, ln_g, ln_b,
        Wrel, b_rel, Wvb, b_vb,
        Mi0, Mr0, ibp, fbp, a1p, a2p, tvec_all);

    k3_post<<<dim3((T_ * B_) / 8), dim3(256), 0, stream>>>(
        tvec_all, xo_all, Wrel3, b_rel3,
        Wm1, b_m1, Wm2, b_m2, Wout, b_out, fc_g, fc_b, Wfc, b_fc,
        (float*)d_out);
}

// Round 8
// 697.371 us; speedup vs baseline: 6.5839x; 1.2902x over previous
//
#include <hip/hip_runtime.h>
#include <hip/hip_fp16.h>
#include <math.h>

#define T_ 128
#define B_ 32
#define D_ 512
#define V_ 128
#define S_ 64
#define N_ 4
#define R_ 64
#define O_ 64

typedef _Float16 h4 __attribute__((ext_vector_type(4)));
typedef _Float16 h8 __attribute__((ext_vector_type(8)));
typedef float f4 __attribute__((ext_vector_type(4)));

__device__ __forceinline__ float fsigm(float x) {
    return __fdividef(1.0f, 1.0f + __expf(-x));
}
__device__ __forceinline__ float ftanh(float x) {
    float e = __expf(2.f * x);
    return 1.f - __fdividef(2.f, e + 1.f);
}

// ---- h8-contiguous fragment layout for [rows][64] f16 operand tiles (k2) ----
__device__ __forceinline__ int fidx(int row, int ks, int g) {
    return row * 64 + ((((ks << 2) | g) ^ (row & 7)) << 3);
}
__device__ __forceinline__ int sidx(int row, int k) {
    int ks = k >> 5, u = (k >> 4) & 1, gg = (k >> 2) & 3, e = k & 3;
    return row * 64 + ((((ks << 2) | gg) ^ (row & 7)) << 3) + (u << 2) + e;
}

// ---- A-fragment LDS layouts for K=512 / K=64 (k1/k3) ----
__device__ __forceinline__ int afi512(int row, int ks, int g) {
    return row * 512 + ((((ks << 2) | g) ^ (row & 7)) << 3);
}
__device__ __forceinline__ int afw512(int row, int k) {
    return row * 512 + (((((k >> 5) << 2) | ((k >> 2) & 3)) ^ (row & 7)) << 3)
         + (((k >> 4) & 1) << 2) + (k & 3);
}
__device__ __forceinline__ int afi64(int row, int ks, int g) {
    return row * 64 + ((((ks << 2) | g) ^ (row & 7)) << 3);
}
__device__ __forceinline__ int afw64(int row, int k) {
    return row * 64 + (((((k >> 5) << 2) | ((k >> 2) & 3)) ^ (row & 7)) << 3)
         + (((k >> 4) & 1) << 2) + (k & 3);
}

// fragment-layout weight segment offsets (halves) within hW
#define OFF_WE    0
#define OFF_WIN   262144
#define OFF_WIN2  294912
#define OFF_WIN3  327680
#define OFF_WIG   335872
#define OFF_WREL3 344064
#define OFF_WM1   348160
#define OFF_WM2   380928
#define OFF_WOUT  643072
#define OFF_WFC   905216
#define HW_TOTAL  970752

// ---------------------------------------------------------------------------
// K0: convert 10 weight matrices to fragment-interleaved fp16.
// Layout per GEMM (W is KxN row-major, Npad mult of 16, NT=Npad/16):
//   flat = ((ks*NT + ct)*64 + lane)*8 + e
//   col = ct*16 + (lane&15); k = ks*32 + (e>>2)*16 + (lane>>4)*4 + (e&3)
// ---------------------------------------------------------------------------
__global__ __launch_bounds__(256)
void k0_conv(const float* __restrict__ We, const float* __restrict__ Win,
             const float* __restrict__ Win2, const float* __restrict__ Win3,
             const float* __restrict__ Wig, const float* __restrict__ Wrel3,
             const float* __restrict__ Wm1, const float* __restrict__ Wm2,
             const float* __restrict__ Wout, const float* __restrict__ Wfc,
             _Float16* __restrict__ outh)
{
    int idx = blockIdx.x * 256 + threadIdx.x;
    if (idx >= HW_TOTAL) return;
    const float* W; int base, Nn, NT;
    if (idx < OFF_WIN)        { W = We;    base = OFF_WE;    Nn = 512; NT = 32; }
    else if (idx < OFF_WIN2)  { W = Win;   base = OFF_WIN;   Nn = 64;  NT = 4;  }
    else if (idx < OFF_WIN3)  { W = Win2;  base = OFF_WIN2;  Nn = 64;  NT = 4;  }
    else if (idx < OFF_WIG)   { W = Win3;  base = OFF_WIN3;  Nn = 4;   NT = 1;  }
    else if (idx < OFF_WREL3) { W = Wig;   base = OFF_WIG;   Nn = 128; NT = 8;  }
    else if (idx < OFF_WM1)   { W = Wrel3; base = OFF_WREL3; Nn = 64;  NT = 4;  }
    else if (idx < OFF_WM2)   { W = Wm1;   base = OFF_WM1;   Nn = 512; NT = 32; }
    else if (idx < OFF_WOUT)  { W = Wm2;   base = OFF_WM2;   Nn = 512; NT = 32; }
    else if (idx < OFF_WFC)   { W = Wout;  base = OFF_WOUT;  Nn = 512; NT = 32; }
    else                      { W = Wfc;   base = OFF_WFC;   Nn = 128; NT = 8;  }
    int local = idx - base;
    int e = local & 7, fr = local >> 3;
    int l = fr & 63, ctks = fr >> 6;
    int ks = ctks / NT, ct = ctks - ks * NT;
    int col = ct * 16 + (l & 15);
    int k = ks * 32 + ((e >> 2) << 4) + ((l >> 4) << 2) + (e & 3);
    outh[idx] = (col < Nn) ? (_Float16)W[k * Nn + col] : (_Float16)0.f;
}

// ---------------------------------------------------------------------------
// K1: MFMA precompute. 16 rows/block, 512 thr (8 waves), grid 256.
//   emb->afE ; src = emb@We + be (MFMA) -> afS ;
//   v = src@Win + b_in -> v_all + afV ; xo = src@Win2 + b_in2 -> xo_all ;
//   w3 = softmax(src@Win3 + b_in3) -> w3_all ; gIn = v@Wig + b_ig -> gIn_all
// ---------------------------------------------------------------------------
__global__ __launch_bounds__(512)
void k1_pre(const int* __restrict__ ids, const float* __restrict__ emb,
            const _Float16* __restrict__ hW,
            const float* __restrict__ be, const float* __restrict__ b_in,
            const float* __restrict__ b_in2, const float* __restrict__ b_in3,
            const float* __restrict__ b_ig,
            float* __restrict__ v_all, float* __restrict__ gIn_all,
            float* __restrict__ w3_all, float* __restrict__ xo_all)
{
    __shared__ __align__(16) _Float16 afE[16 * 512];
    __shared__ __align__(16) _Float16 afS[16 * 512];
    __shared__ __align__(16) _Float16 afV[16 * 64];
    const int tid = threadIdx.x;
    const int wv = tid >> 6, l = tid & 63, li = l & 15, g = l >> 4;
    const int f0 = blockIdx.x * 16;

    const _Float16* WeF   = hW + OFF_WE;
    const _Float16* WinF  = hW + OFF_WIN;
    const _Float16* Win2F = hW + OFF_WIN2;
    const _Float16* Win3F = hW + OFF_WIN3;
    const _Float16* WigF  = hW + OFF_WIG;

    // ---- stage 1: emb rows -> afE (fp16 frags) ----
#pragma unroll
    for (int row = 0; row < 16; ++row) {
        const int f = f0 + row, t = f >> 5, bb = f & 31;
        const int id = ids[bb * T_ + t];
        afE[afw512(row, tid)] = (_Float16)emb[id * D_ + tid];
    }
    __syncthreads();

    // ---- stage 2: src = emb@We + be -> afS ----
    {
        h8 a[16];
#pragma unroll
        for (int ks = 0; ks < 16; ++ks) a[ks] = *(const h8*)&afE[afi512(li, ks, g)];
#pragma unroll
        for (int c4 = 0; c4 < 4; ++c4) {
            const int ct = (wv << 2) + c4;
            const int col = (ct << 4) + li;
            const float bb = be[col];
            f4 acc = {bb, bb, bb, bb};
#pragma unroll
            for (int ks = 0; ks < 16; ++ks)
                acc = __builtin_amdgcn_mfma_f32_16x16x32_f16(
                    a[ks], *(const h8*)&WeF[((ks * 32 + ct) * 64 + l) * 8], acc, 0, 0, 0);
#pragma unroll
            for (int r = 0; r < 4; ++r)
                afS[afw512((g << 2) + r, col)] = (_Float16)acc[r];
        }
    }
    __syncthreads();

    // ---- stage 3: v (waves 0-3) / xo (waves 4-7) ----
    h8 s[16];
#pragma unroll
    for (int ks = 0; ks < 16; ++ks) s[ks] = *(const h8*)&afS[afi512(li, ks, g)];
    if (wv < 4) {
        const int col = (wv << 4) + li;
        const float bb = b_in[col];
        f4 acc = {bb, bb, bb, bb};
#pragma unroll
        for (int ks = 0; ks < 16; ++ks)
            acc = __builtin_amdgcn_mfma_f32_16x16x32_f16(
                s[ks], *(const h8*)&WinF[((ks * 4 + wv) * 64 + l) * 8], acc, 0, 0, 0);
#pragma unroll
        for (int r = 0; r < 4; ++r) {
            const int row = (g << 2) + r;
            v_all[(f0 + row) * S_ + col] = acc[r];
            afV[afw64(row, col)] = (_Float16)acc[r];
        }
    } else {
        const int ct = wv - 4;
        const int col = (ct << 4) + li;
        const float bb = b_in2[col];
        f4 acc = {bb, bb, bb, bb};
#pragma unroll
        for (int ks = 0; ks < 16; ++ks)
            acc = __builtin_amdgcn_mfma_f32_16x16x32_f16(
                s[ks], *(const h8*)&Win2F[((ks * 4 + ct) * 64 + l) * 8], acc, 0, 0, 0);
#pragma unroll
        for (int r = 0; r < 4; ++r)
            xo_all[(f0 + (g << 2) + r) * O_ + col] = acc[r];
    }
    __syncthreads();

    // ---- stage 4: w3 (wave 0) + gIn (all 8 waves) ----
    if (wv == 0) {
        f4 acc = {0.f, 0.f, 0.f, 0.f};
#pragma unroll
        for (int ks = 0; ks < 16; ++ks)
            acc = __builtin_amdgcn_mfma_f32_16x16x32_f16(
                s[ks], *(const h8*)&Win3F[(ks * 64 + l) * 8], acc, 0, 0, 0);
        if (li < 4) {
            const float bc = b_in3[li];
#pragma unroll
            for (int r = 0; r < 4; ++r) {
                float a0 = acc[r] + bc;
                float mx = fmaxf(a0, __shfl_xor(a0, 1));
                mx = fmaxf(mx, __shfl_xor(mx, 2));
                float ee = __expf(a0 - mx);
                float sm = ee + __shfl_xor(ee, 1);
                sm += __shfl_xor(sm, 2);
                w3_all[(f0 + (g << 2) + r) * N_ + li] = __fdividef(ee, sm);
            }
        }
    }
    {
        const int ct = (wv == 0) ? 7 : wv - 1;
        h8 v0 = *(const h8*)&afV[afi64(li, 0, g)];
        h8 v1 = *(const h8*)&afV[afi64(li, 1, g)];
        const int col = (ct << 4) + li;
        const float bb = b_ig[col];
        f4 acc = {bb, bb, bb, bb};
        acc = __builtin_amdgcn_mfma_f32_16x16x32_f16(
            v0, *(const h8*)&WigF[((0 * 8 + ct) * 64 + l) * 8], acc, 0, 0, 0);
        acc = __builtin_amdgcn_mfma_f32_16x16x32_f16(
            v1, *(const h8*)&WigF[((1 * 8 + ct) * 64 + l) * 8], acc, 0, 0, 0);
#pragma unroll
        for (int r = 0; r < 4; ++r)
            gIn_all[(f0 + (g << 2) + r) * 2 * S_ + col] = acc[r];
    }
}

// ---------------------------------------------------------------------------
// K2: sequential scan — UNCHANGED from round 7.
// ---------------------------------------------------------------------------
__global__ __launch_bounds__(1024, 4)
void k2_scan(const float* __restrict__ v_all, const float* __restrict__ gIn_all,
             const float* __restrict__ w3_all,
             const float* __restrict__ Wmg, const float* __restrict__ b_mg,
             const float* __restrict__ Wqkv, const float* __restrict__ b_qkv,
             const float* __restrict__ ln_g, const float* __restrict__ ln_b,
             const float* __restrict__ Wrel, const float* __restrict__ b_rel,
             const float* __restrict__ Wvb, const float* __restrict__ b_vb,
             const float* __restrict__ Mi0, const float* __restrict__ Mr0,
             const float* __restrict__ p_ib, const float* __restrict__ p_fb,
             const float* __restrict__ p_a1, const float* __restrict__ p_a2,
             float* __restrict__ tvec_all)
{
    const int tid = threadIdx.x;
    const int b = blockIdx.x;
    const int wv = tid >> 6;
    const int ln = tid & 63;
    const int g  = ln >> 4;
    const int li = ln & 15;

    __shared__ __align__(16) float Mi_s[S_ * 68];
    __shared__ __align__(16) _Float16 AsT[S_ * S_];
    __shared__ __align__(16) _Float16 AsX[S_ * S_];
    __shared__ __align__(16) _Float16 Mif16[S_ * S_];
    __shared__ __align__(16) _Float16 P_op[16 * S_];
    __shared__ __align__(16) _Float16 WmgT[2 * S_ * S_];
    __shared__ __align__(16) _Float16 WvbT[S_ * S_];
    __shared__ __align__(16) _Float16 WrelT[S_ * S_];
    __shared__ __align__(16) _Float16 WqkvT[16 * S_];
    __shared__ __align__(16) float vgT[12 * 68];
    __shared__ __align__(16) float gT[12 * 68];
    __shared__ __align__(16) float lbT[12 * 68];
    __shared__ __align__(16) float vvsT[S_ * 4];
    __shared__ __align__(16) float wvm[N_][S_];
    __shared__ __align__(16) float G2s[N_][S_];
    __shared__ __align__(16) float B2s[N_][S_];
    __shared__ __align__(16) float wavepart[16][S_];
    __shared__ float bmgin[128];
    __shared__ float b_mg_s[128];
    __shared__ __align__(16) float b_vb_s[64];
    __shared__ float b_qkv_s[16];
    __shared__ float vt[S_];
    __shared__ __align__(16) float w3s4[4];
    __shared__ __align__(16) float Amat[N_][N_];
    __shared__ __align__(16) float red1[16], red2[16];

    const float ib = p_ib[0], fb = p_fb[0], a1 = p_a1[0], a2v = p_a2[0];

    #define MI(r, c) Mi_s[(r) * 68 + (c)]

    for (int i = tid; i < 2 * S_ * S_; i += 1024) {
        int k = i >> 7, j = i & 127;
        WmgT[sidx(j, k)] = (_Float16)Wmg[i];
    }
    for (int i = tid; i < S_ * S_; i += 1024) {
        int r = i >> 6, j = i & 63;
        WvbT[sidx(j, r)] = (_Float16)Wvb[i];
    }
    for (int i = tid; i < S_ * S_; i += 1024) {
        int s = i >> 6, r = i & 63;
        WrelT[sidx(r, s)] = (_Float16)Wrel[i];
    }
    if (tid < 16 * S_) {
        int c = tid >> 6, k = tid & 63;
        float w = (c < 12) ? Wqkv[k * 12 + c] : 0.f;
        WqkvT[sidx(c, k)] = (_Float16)w;
    }
    if (tid < 768) {
        int s = tid / 12, c = tid - s * 12;
        gT[c * 68 + s]  = ln_g[tid];
        lbT[c * 68 + s] = ln_b[tid];
    }
    if (tid < 128) b_mg_s[tid] = b_mg[tid];
    else if (tid < 192) b_vb_s[tid - 128] = b_vb[tid - 128];
    else if (tid < 208) b_qkv_s[tid - 192] = (tid - 192 < 12) ? b_qkv[tid - 192] : 0.f;
    if (tid < 1024) P_op[tid] = (_Float16)0.f;
    if (tid < 256) {
        const int m = tid >> 6, r = tid & 63;
        float g2 = 0.f, b2 = 0.f;
        for (int s = 0; s < S_; ++s) {
            float w = Wrel[s * R_ + r];
            g2 = fmaf(ln_g[s * 12 + 8 + m], w, g2);
            b2 = fmaf(ln_b[s * 12 + 8 + m], w, b2);
        }
        G2s[m][r] = g2;
        B2s[m][r] = a1 * b2;
    }
    for (int i = tid; i < S_ * S_; i += 1024) MI(i >> 6, i & 63) = Mi0[i];
    {
        const int row = tid >> 4, k0 = (tid & 15) << 2;
        const float* mp = Mi0 + (tid << 2);
        h4 t4;
        t4[0] = (_Float16)ftanh(mp[0]); t4[1] = (_Float16)ftanh(mp[1]);
        t4[2] = (_Float16)ftanh(mp[2]); t4[3] = (_Float16)ftanh(mp[3]);
        *(h4*)&AsT[sidx(row, k0)] = t4;
    }
    f4 mrs0, mrs1, mrs2, mrs3, a1brel4;
    {
        const int s0i = tid >> 4, r4i = (tid & 15) << 2;
        const float* mrp = Mr0 + s0i * 64 + r4i;
        mrs0 = *(const f4*)&mrp[0];
        mrs1 = *(const f4*)&mrp[4096];
        mrs2 = *(const f4*)&mrp[8192];
        mrs3 = *(const f4*)&mrp[12288];
        f4 br = *(const f4*)&b_rel[r4i];
        a1brel4 = a1 * br;
    }
    if (tid < 64) vt[tid] = v_all[b * S_ + tid];
    else if (tid < 68) w3s4[tid - 64] = w3_all[b * N_ + (tid - 64)];
    if (tid >= 128 && tid < 256)
        bmgin[tid - 128] = b_mg[tid - 128] + gIn_all[b * 2 * S_ + (tid - 128)];
    __syncthreads();

    for (int t = 0; t < T_; ++t) {
        const int f = t * B_ + b;

        float pf = 0.f;
        {
            const int fn = ((t + 1 < T_) ? t + 1 : t) * B_ + b;
            if (tid >= 512 && tid < 576) pf = v_all[fn * S_ + (tid - 512)];
            else if (tid >= 576 && tid < 580) pf = w3_all[fn * N_ + (tid - 576)];
            else if (tid >= 640 && tid < 768) pf = gIn_all[fn * 2 * S_ + (tid - 640)];
        }
        {
            const int rowbase = (wv & 3) << 4;
            const int arow = rowbase + li;
            const int colI = ((wv >> 2) << 4) + li;
            const int colF = colI + 64;
            h8 af0 = *(const h8*)&AsT[fidx(arow, 0, g)];
            h8 af1 = *(const h8*)&AsT[fidx(arow, 1, g)];
            const float bi = bmgin[colI], bfv = bmgin[colF];
            f4 accI = {bi, bi, bi, bi};
            f4 accF = {bfv, bfv, bfv, bfv};
            accI = __builtin_amdgcn_mfma_f32_16x16x32_f16(af0, *(const h8*)&WmgT[fidx(colI, 0, g)], accI, 0, 0, 0);
            accI = __builtin_amdgcn_mfma_f32_16x16x32_f16(af1, *(const h8*)&WmgT[fidx(colI, 1, g)], accI, 0, 0, 0);
            accF = __builtin_amdgcn_mfma_f32_16x16x32_f16(af0, *(const h8*)&WmgT[fidx(colF, 0, g)], accF, 0, 0, 0);
            accF = __builtin_amdgcn_mfma_f32_16x16x32_f16(af1, *(const h8*)&WmgT[fidx(colF, 1, g)], accF, 0, 0, 0);
            const float vc = vt[colI];
#pragma unroll
            for (int r = 0; r < 4; ++r) {
                const int row = rowbase + (g << 2) + r;
                const float gi = fsigm(accI[r] + ib);
                const float gf = fsigm(accF[r] + fb);
                const float mo = MI(row, colI);
                const float mn = gf * mo + gi * ftanh(vt[row] * vc);
                MI(row, colI) = mn;
                Mif16[sidx(row, colI)] = (_Float16)mn;
            }
        }
        __syncthreads();

        if (wv < 4) {
            const int rowbase = wv << 4;
            const int arow = rowbase + li;
            h8 af0 = *(const h8*)&Mif16[fidx(arow, 0, g)];
            h8 af1 = *(const h8*)&Mif16[fidx(arow, 1, g)];
            const float bq = b_qkv_s[li];
            f4 qacc = {bq, bq, bq, bq};
            qacc = __builtin_amdgcn_mfma_f32_16x16x32_f16(af0, *(const h8*)&WqkvT[fidx(li, 0, g)], qacc, 0, 0, 0);
            qacc = __builtin_amdgcn_mfma_f32_16x16x32_f16(af1, *(const h8*)&WqkvT[fidx(li, 1, g)], qacc, 0, 0, 0);
            float s1 = 0.f, s2 = 0.f;
            if (li < 12) {
                const int srow = rowbase + (g << 2);
                f4 g4 = *(const f4*)&gT[li * 68 + srow];
                f4 vg = qacc * g4;
                *(f4*)&vgT[li * 68 + srow] = vg;
                s1 = (qacc[0] + qacc[1]) + (qacc[2] + qacc[3]);
                f4 sq = qacc * qacc;
                s2 = (sq[0] + sq[1]) + (sq[2] + sq[3]);
                if (li >= 8) {
                    h4 p4 = __builtin_convertvector(vg, h4);
                    *(h4*)&P_op[sidx(li - 8, srow)] = p4;
                }
            }
#pragma unroll
            for (int off = 8; off; off >>= 1) {
                s1 += __shfl_down(s1, off); s2 += __shfl_down(s2, off);
            }
            if (li == 0) { red1[(wv << 2) + g] = s1; red2[(wv << 2) + g] = s2; }
        }
        __syncthreads();

        {
            f4 rA = *(const f4*)&red1[0];
            rA += *(const f4*)&red1[4];
            rA += *(const f4*)&red1[8];
            rA += *(const f4*)&red1[12];
            f4 rB = *(const f4*)&red2[0];
            rB += *(const f4*)&red2[4];
            rB += *(const f4*)&red2[8];
            rB += *(const f4*)&red2[12];
            const float sA = (rA[0] + rA[1]) + (rA[2] + rA[3]);
            const float sB = (rB[0] + rB[1]) + (rB[2] + rB[3]);
            const float mu = sA * (1.f / 768.f);
            const float var = sB * (1.f / 768.f) - mu * mu;
            const float rstd = rsqrtf(var + 1e-5f);
            const float murstd = mu * rstd;
            if (wv < 4) {
                h8 af0 = *(const h8*)&P_op[fidx(li, 0, g)];
                h8 af1 = *(const h8*)&P_op[fidx(li, 1, g)];
                const int col = (wv << 4) + li;
                f4 acc = {0.f, 0.f, 0.f, 0.f};
                acc = __builtin_amdgcn_mfma_f32_16x16x32_f16(af0, *(const h8*)&WrelT[fidx(col, 0, g)], acc, 0, 0, 0);
                acc = __builtin_amdgcn_mfma_f32_16x16x32_f16(af1, *(const h8*)&WrelT[fidx(col, 1, g)], acc, 0, 0, 0);
                if (ln < 16) {
                    const float sa = a1 * rstd;
                    const float sb = -a1 * murstd;
#pragma unroll
                    for (int r = 0; r < 4; ++r)
                        wvm[r][col] = sa * acc[r] + sb * G2s[r][col] + B2s[r][col];
                }
            } else if (wv < 8) {
                const int n = wv - 4;
                const int s0 = li << 2;
                f4 vgq = *(const f4*)&vgT[n * 68 + s0];
                f4 gq  = *(const f4*)&gT [n * 68 + s0];
                f4 lbq = *(const f4*)&lbT[n * 68 + s0];
                f4 qv  = rstd * vgq - murstd * gq + lbq;
                const int kr = 4 + g;
                f4 vgk = *(const f4*)&vgT[kr * 68 + s0];
                f4 gk  = *(const f4*)&gT [kr * 68 + s0];
                f4 lbk = *(const f4*)&lbT[kr * 68 + s0];
                f4 kv  = rstd * vgk - murstd * gk + lbk;
                f4 pr = qv * kv;
                float a = (pr[0] + pr[1]) + (pr[2] + pr[3]);
                a += __shfl_down(a, 8);
                a += __shfl_down(a, 4);
                a += __shfl_down(a, 2);
                a += __shfl_down(a, 1);
                a *= 0.125f;
                float s0v = __shfl(a, 0), s1v = __shfl(a, 16);
                float s2v = __shfl(a, 32), s3v = __shfl(a, 48);
                if (li == 0) {
                    float mx = fmaxf(fmaxf(s0v, s1v), fmaxf(s2v, s3v));
                    float e0 = __expf(s0v - mx), e1 = __expf(s1v - mx);
                    float e2 = __expf(s2v - mx), e3 = __expf(s3v - mx);
                    float inv = __fdividef(1.f, e0 + e1 + e2 + e3);
                    float ev = (g == 0) ? e0 : (g == 1) ? e1 : (g == 2) ? e2 : e3;
                    Amat[n][g] = ev * inv;
                }
            } else if (wv < 12) {
                const int m = wv - 8;
                const int c = (8 + m) * 68 + ln;
                vvsT[(ln << 2) + m] = rstd * vgT[c] - murstd * gT[c] + lbT[c];
            }
        }
        __syncthreads();

        {
            const int s = tid >> 4, rq = tid & 15, r4 = rq << 2;
            f4 Am0 = *(const f4*)&Amat[0][0];
            f4 Am1 = *(const f4*)&Amat[1][0];
            f4 Am2 = *(const f4*)&Amat[2][0];
            f4 Am3 = *(const f4*)&Amat[3][0];
            f4 w3r = *(const f4*)&w3s4[0];
            f4 vv4 = *(const f4*)&vvsT[s << 2];
            f4 wvA4 = *(const f4*)&wvm[0][r4];
            f4 wvB4 = *(const f4*)&wvm[1][r4];
            f4 wvC4 = *(const f4*)&wvm[2][r4];
            f4 wvD4 = *(const f4*)&wvm[3][r4];
            {
                const float c0 = Am0[0] * vv4[0], c1 = Am0[1] * vv4[1];
                const float c2 = Am0[2] * vv4[2], c3 = Am0[3] * vv4[3];
                mrs0 += a1brel4 + c0 * wvA4 + c1 * wvB4 + c2 * wvC4 + c3 * wvD4;
            }
            {
                const float c0 = Am1[0] * vv4[0], c1 = Am1[1] * vv4[1];
                const float c2 = Am1[2] * vv4[2], c3 = Am1[3] * vv4[3];
                mrs1 += a1brel4 + c0 * wvA4 + c1 * wvB4 + c2 * wvC4 + c3 * wvD4;
            }
            {
                const float c0 = Am2[0] * vv4[0], c1 = Am2[1] * vv4[1];
                const float c2 = Am2[2] * vv4[2], c3 = Am2[3] * vv4[3];
                mrs2 += a1brel4 + c0 * wvA4 + c1 * wvB4 + c2 * wvC4 + c3 * wvD4;
            }
            {
                const float c0 = Am3[0] * vv4[0], c1 = Am3[1] * vv4[1];
                const float c2 = Am3[2] * vv4[2], c3 = Am3[3] * vv4[3];
                mrs3 += a1brel4 + c0 * wvA4 + c1 * wvB4 + c2 * wvC4 + c3 * wvD4;
            }
            f4 trv = w3r[0] * mrs0 + w3r[1] * mrs1 + w3r[2] * mrs2 + w3r[3] * mrs3;
            h4 trh = __builtin_convertvector(trv, h4);
            *(h4*)&AsX[sidx(s, r4)] = trh;
            f4 tp = vt[s] * trv;
            {
                f4 o;
                o[0] = __shfl_xor(tp[0], 16); o[1] = __shfl_xor(tp[1], 16);
                o[2] = __shfl_xor(tp[2], 16); o[3] = __shfl_xor(tp[3], 16);
                tp += o;
                o[0] = __shfl_xor(tp[0], 32); o[1] = __shfl_xor(tp[1], 32);
                o[2] = __shfl_xor(tp[2], 32); o[3] = __shfl_xor(tp[3], 32);
                tp += o;
            }
            if (ln < 16) *(f4*)&wavepart[wv][r4] = tp;
        }
        __syncthreads();

        {
            const int rowbase = (wv & 3) << 4;
            const int arow = rowbase + li;
            const int col = ((wv >> 2) << 4) + li;
            h8 af0 = *(const h8*)&AsX[fidx(arow, 0, g)];
            h8 af1 = *(const h8*)&AsX[fidx(arow, 1, g)];
            const float bv = b_vb_s[col];
            f4 acc = {bv, bv, bv, bv};
            acc = __builtin_amdgcn_mfma_f32_16x16x32_f16(af0, *(const h8*)&WvbT[fidx(col, 0, g)], acc, 0, 0, 0);
            acc = __builtin_amdgcn_mfma_f32_16x16x32_f16(af1, *(const h8*)&WvbT[fidx(col, 1, g)], acc, 0, 0, 0);
#pragma unroll
            for (int r = 0; r < 4; ++r) {
                const int row = rowbase + (g << 2) + r;
                const float mn = MI(row, col) + a2v * ftanh(acc[r]);
                MI(row, col) = mn;
                AsT[sidx(row, col)] = (_Float16)ftanh(mn);
            }
        }
        if (wv == 15) {
            float tv = 0.f;
#pragma unroll
            for (int w = 0; w < 16; ++w) tv += wavepart[w][ln];
            tvec_all[f * S_ + ln] = tv;
        } else if (tid >= 512 && tid < 768) {
            if (tid < 576) vt[tid - 512] = pf;
            else if (tid < 580) w3s4[tid - 576] = pf;
            else if (tid >= 640) bmgin[tid - 640] = b_mg_s[tid - 640] + pf;
        }
        __syncthreads();
    }
    #undef MI
}

// ---------------------------------------------------------------------------
// K3: MFMA post-pass. 16 rows/block, 512 thr, grid 256.
//   o = tvec@Wrel3 + b_rel3 + xo -> h1 = relu(o@Wm1+b) -> h2 = relu(h1@Wm2+b)
//   -> y = h2@Wout+b -> LN -> relu -> logits = yn@Wfc + b_fc -> out[b][v][t]
// ---------------------------------------------------------------------------
__global__ __launch_bounds__(512)
void k3_post(const float* __restrict__ tvec_all, const float* __restrict__ xo_all,
             const _Float16* __restrict__ hW,
             const float* __restrict__ b_rel3, const float* __restrict__ b_m1,
             const float* __restrict__ b_m2, const float* __restrict__ b_out,
             const float* __restrict__ fc_g, const float* __restrict__ fc_b,
             const float* __restrict__ b_fc, float* __restrict__ out)
{
    __shared__ __align__(16) _Float16 afA[16 * 512];   // h1, later yn
    __shared__ __align__(16) _Float16 afB[16 * 512];   // h2
    __shared__ __align__(16) _Float16 afT[16 * 64];
    __shared__ __align__(16) _Float16 afO[16 * 64];
    __shared__ __align__(16) float ybuf[16 * 512];
    __shared__ float mus[16], rsts[16];
    const int tid = threadIdx.x;
    const int wv = tid >> 6, l = tid & 63, li = l & 15, g = l >> 4;
    const int f0 = blockIdx.x * 16;

    const _Float16* Wrel3F = hW + OFF_WREL3;
    const _Float16* Wm1F   = hW + OFF_WM1;
    const _Float16* Wm2F   = hW + OFF_WM2;
    const _Float16* WoutF  = hW + OFF_WOUT;
    const _Float16* WfcF   = hW + OFF_WFC;

    // ---- stage 0: tvec -> afT ----
    for (int i = tid; i < 16 * 64; i += 512) {
        int row = i >> 6, k = i & 63;
        afT[afw64(row, k)] = (_Float16)tvec_all[(f0 + row) * O_ + k];
    }
    __syncthreads();

    // ---- stage A: o = tvec@Wrel3 + b_rel3 + xo -> afO ----
    if (wv < 4) {
        h8 t0 = *(const h8*)&afT[afi64(li, 0, g)];
        h8 t1 = *(const h8*)&afT[afi64(li, 1, g)];
        const int col = (wv << 4) + li;
        const float bb = b_rel3[col];
        f4 acc = {bb, bb, bb, bb};
        acc = __builtin_amdgcn_mfma_f32_16x16x32_f16(
            t0, *(const h8*)&Wrel3F[((0 * 4 + wv) * 64 + l) * 8], acc, 0, 0, 0);
        acc = __builtin_amdgcn_mfma_f32_16x16x32_f16(
            t1, *(const h8*)&Wrel3F[((1 * 4 + wv) * 64 + l) * 8], acc, 0, 0, 0);
#pragma unroll
        for (int r = 0; r < 4; ++r) {
            const int row = (g << 2) + r;
            const float o = acc[r] + xo_all[(f0 + row) * O_ + col];
            afO[afw64(row, col)] = (_Float16)o;
        }
    }
    __syncthreads();

    // ---- stage B: h1 = relu(o@Wm1 + b_m1) -> afA ----
    {
        h8 o0 = *(const h8*)&afO[afi64(li, 0, g)];
        h8 o1 = *(const h8*)&afO[afi64(li, 1, g)];
#pragma unroll
        for (int c4 = 0; c4 < 4; ++c4) {
            const int ct = (wv << 2) + c4;
            const int col = (ct << 4) + li;
            const float bb = b_m1[col];
            f4 acc = {bb, bb, bb, bb};
            acc = __builtin_amdgcn_mfma_f32_16x16x32_f16(
                o0, *(const h8*)&Wm1F[((0 * 32 + ct) * 64 + l) * 8], acc, 0, 0, 0);
            acc = __builtin_amdgcn_mfma_f32_16x16x32_f16(
                o1, *(const h8*)&Wm1F[((1 * 32 + ct) * 64 + l) * 8], acc, 0, 0, 0);
#pragma unroll
            for (int r = 0; r < 4; ++r)
                afA[afw512((g << 2) + r, col)] = (_Float16)fmaxf(acc[r], 0.f);
        }
    }
    __syncthreads();

    // ---- stage C: h2 = relu(h1@Wm2 + b_m2) -> afB ----
    {
        h8 a[16];
#pragma unroll
        for (int ks = 0; ks < 16; ++ks) a[ks] = *(const h8*)&afA[afi512(li, ks, g)];
#pragma unroll
        for (int c4 = 0; c4 < 4; ++c4) {
            const int ct = (wv << 2) + c4;
            const int col = (ct << 4) + li;
            const float bb = b_m2[col];
            f4 acc = {bb, bb, bb, bb};
#pragma unroll
            for (int ks = 0; ks < 16; ++ks)
                acc = __builtin_amdgcn_mfma_f32_16x16x32_f16(
                    a[ks], *(const h8*)&Wm2F[((ks * 32 + ct) * 64 + l) * 8], acc, 0, 0, 0);
#pragma unroll
            for (int r = 0; r < 4; ++r)
                afB[afw512((g << 2) + r, col)] = (_Float16)fmaxf(acc[r], 0.f);
        }
    }
    __syncthreads();

    // ---- stage D: y = h2@Wout + b_out -> ybuf (f32) ----
    {
        h8 a[16];
#pragma unroll
        for (int ks = 0; ks < 16; ++ks) a[ks] = *(const h8*)&afB[afi512(li, ks, g)];
#pragma unroll
        for (int c4 = 0; c4 < 4; ++c4) {
            const int ct = (wv << 2) + c4;
            const int col = (ct << 4) + li;
            const float bb = b_out[col];
            f4 acc = {bb, bb, bb, bb};
#pragma unroll
            for (int ks = 0; ks < 16; ++ks)
                acc = __builtin_amdgcn_mfma_f32_16x16x32_f16(
                    a[ks], *(const h8*)&WoutF[((ks * 32 + ct) * 64 + l) * 8], acc, 0, 0, 0);
#pragma unroll
            for (int r = 0; r < 4; ++r)
                ybuf[((g << 2) + r) * 512 + col] = acc[r];
        }
    }
    __syncthreads();

    // ---- stage E: LN + relu -> afA (yn frags) ----
    {
        const int r = tid >> 5, l32 = tid & 31;
        float s1 = 0.f, s2 = 0.f;
        for (int k = l32; k < 512; k += 32) {
            float y = ybuf[r * 512 + k];
            s1 += y; s2 += y * y;
        }
#pragma unroll
        for (int off = 16; off; off >>= 1) {
            s1 += __shfl_down(s1, off, 32);
            s2 += __shfl_down(s2, off, 32);
        }
        if (l32 == 0) {
            float mu = s1 * (1.f / 512.f);
            float var = s2 * (1.f / 512.f) - mu * mu;
            mus[r] = mu; rsts[r] = rsqrtf(var + 1e-5f);
        }
    }
    __syncthreads();
    for (int i = tid; i < 16 * 512; i += 512) {
        int row = i >> 9, col = i & 511;
        float yn = (ybuf[row * 512 + col] - mus[row]) * rsts[row] * fc_g[col] + fc_b[col];
        afA[afw512(row, col)] = (_Float16)fmaxf(yn, 0.f);
    }
    __syncthreads();

    // ---- stage F: logits = yn@Wfc + b_fc -> out[b][v][t] ----
    {
        h8 a[16];
#pragma unroll
        for (int ks = 0; ks < 16; ++ks) a[ks] = *(const h8*)&afA[afi512(li, ks, g)];
        const int col = (wv << 4) + li;
        const float bb = b_fc[col];
        f4 acc = {bb, bb, bb, bb};
#pragma unroll
        for (int ks = 0; ks < 16; ++ks)
            acc = __builtin_amdgcn_mfma_f32_16x16x32_f16(
                a[ks], *(const h8*)&WfcF[((ks * 8 + wv) * 64 + l) * 8], acc, 0, 0, 0);
#pragma unroll
        for (int r = 0; r < 4; ++r) {
            const int row = (g << 2) + r;
            const int f = f0 + row, t = f >> 5, bo = f & 31;
            out[bo * (V_ * T_) + col * T_ + t] = acc[r];
        }
    }
}

// ---------------------------------------------------------------------------
extern "C" void kernel_launch(void* const* d_in, const int* in_sizes, int n_in,
                              void* d_out, int out_size, void* d_ws, size_t ws_size,
                              hipStream_t stream)
{
    (void)in_sizes; (void)n_in; (void)out_size; (void)ws_size;
    const int*   ids   = (const int*)  d_in[0];
    const float* emb   = (const float*)d_in[1];
    const float* We    = (const float*)d_in[2];
    const float* be    = (const float*)d_in[3];
    const float* Win   = (const float*)d_in[4];
    const float* b_in  = (const float*)d_in[5];
    const float* Win2  = (const float*)d_in[6];
    const float* b_in2 = (const float*)d_in[7];
    const float* Win3  = (const float*)d_in[8];
    const float* b_in3 = (const float*)d_in[9];
    const float* Wig   = (const float*)d_in[10];
    const float* b_ig  = (const float*)d_in[11];
    const float* Wmg   = (const float*)d_in[12];
    const float* b_mg  = (const float*)d_in[13];
    const float* ibp   = (const float*)d_in[14];
    const float* fbp   = (const float*)d_in[15];
    const float* Wqkv  = (const float*)d_in[16];
    const float* b_qkv = (const float*)d_in[17];
    const float* ln_g  = (const float*)d_in[18];
    const float* ln_b  = (const float*)d_in[19];
    const float* a1p   = (const float*)d_in[20];
    const float* a2p   = (const float*)d_in[21];
    const float* Wrel  = (const float*)d_in[22];
    const float* b_rel = (const float*)d_in[23];
    const float* Wvb   = (const float*)d_in[24];
    const float* b_vb  = (const float*)d_in[25];
    const float* Wrel3 = (const float*)d_in[26];
    const float* b_rel3= (const float*)d_in[27];
    const float* Wm1   = (const float*)d_in[28];
    const float* b_m1  = (const float*)d_in[29];
    const float* Wm2   = (const float*)d_in[30];
    const float* b_m2  = (const float*)d_in[31];
    const float* Wout  = (const float*)d_in[32];
    const float* b_out = (const float*)d_in[33];
    const float* Mi0   = (const float*)d_in[34];
    const float* Mr0   = (const float*)d_in[35];
    const float* fc_g  = (const float*)d_in[36];
    const float* fc_b  = (const float*)d_in[37];
    const float* Wfc   = (const float*)d_in[38];
    const float* b_fc  = (const float*)d_in[39];

    float* ws = (float*)d_ws;
    float* v_all    = ws;                          // 262144
    float* gIn_all  = v_all    + T_ * B_ * S_;     // 524288
    float* w3_all   = gIn_all  + T_ * B_ * 2 * S_; // 16384
    float* xo_all   = w3_all   + T_ * B_ * N_;     // 262144
    float* tvec_all = xo_all   + T_ * B_ * O_;     // 262144
    _Float16* hW    = (_Float16*)(tvec_all + T_ * B_ * O_);  // 970752 halves

    k0_conv<<<dim3((HW_TOTAL + 255) / 256), dim3(256), 0, stream>>>(
        We, Win, Win2, Win3, Wig, Wrel3, Wm1, Wm2, Wout, Wfc, hW);

    k1_pre<<<dim3((T_ * B_) / 16), dim3(512), 0, stream>>>(
        ids, emb, hW, be, b_in, b_in2, b_in3, b_ig,
        v_all, gIn_all, w3_all, xo_all);

    k2_scan<<<dim3(B_), dim3(1024), 0, stream>>>(
        v_all, gIn_all, w3_all,
        Wmg, b_mg, Wqkv, b_qkv, ln_g, ln_b,
        Wrel, b_rel, Wvb, b_vb,
        Mi0, Mr0, ibp, fbp, a1p, a2p, tvec_all);

    k3_post<<<dim3((T_ * B_) / 16), dim3(512), 0, stream>>>(
        tvec_all, xo_all, hW, b_rel3, b_m1, b_m2, b_out, fc_g, fc_b, b_fc,
        (float*)d_out);
}